// Round 4
// baseline (1532.282 us; speedup 1.0000x reference)
//
#include <hip/hip_runtime.h>

typedef unsigned short u16;
typedef unsigned int u32;
typedef __bf16 bf16x8 __attribute__((ext_vector_type(8)));
typedef float f32x4 __attribute__((ext_vector_type(4)));

#define LN_EPS 1e-5f
#define L2E 1.44269504f

__device__ __forceinline__ u16 f2bf(float f) {
    u32 u = __float_as_uint(f);
    u += 0x7fffu + ((u >> 16) & 1u);
    return (u16)(u >> 16);
}
__device__ __forceinline__ float bf2f(u32 v) {
    return __uint_as_float(v << 16);
}
__device__ __forceinline__ void unp8(uint4 u, float* v) {
    v[0] = bf2f(u.x & 0xffff); v[1] = bf2f(u.x >> 16);
    v[2] = bf2f(u.y & 0xffff); v[3] = bf2f(u.y >> 16);
    v[4] = bf2f(u.z & 0xffff); v[5] = bf2f(u.z >> 16);
    v[6] = bf2f(u.w & 0xffff); v[7] = bf2f(u.w >> 16);
}
__device__ __forceinline__ u32 pk2(float a, float b) {
    return (u32)f2bf(a) | ((u32)f2bf(b) << 16);
}

// async global->LDS, 16B per lane; lds base must be wave-uniform (HW: base + lane*16)
#define ASYNC_CP16(g, l)                                                      \
    __builtin_amdgcn_global_load_lds(                                         \
        (const __attribute__((address_space(1))) u32*)(g),                    \
        (__attribute__((address_space(3))) u32*)(l), 16, 0, 0)

// ---------------- one-shot prep: all weight transposes (f32->bf16) + bias concat ----
__global__ __launch_bounds__(256) void k_prep(
    const float* __restrict__ wq, const float* __restrict__ wk,
    const float* __restrict__ wv, const float* __restrict__ wo,
    const float* __restrict__ w1, const float* __restrict__ w2,
    const float* __restrict__ bq, const float* __restrict__ bk,
    const float* __restrict__ bv, float* __restrict__ qkvb,
    u16* __restrict__ wqkvT, u16* __restrict__ woT,
    u16* __restrict__ w1T, u16* __restrict__ w2T)
{
    int b = blockIdx.x;
    if (b >= 12288) {
        int i = (b - 12288) * 256 + threadIdx.x;
        qkvb[i] = (i < 1024) ? bq[i] : (i < 2048 ? bk[i - 1024] : bv[i - 2048]);
        return;
    }
    const float* in; u16* out; int C; long ldo; int gx; int l;
    if (b < 4096) {
        int j = b >> 10; l = b & 1023;
        in = (j == 0) ? wq : (j == 1) ? wk : (j == 2) ? wv : wo;
        out = (j == 3) ? woT : wqkvT + (long)j * 1024 * 1024;
        C = 1024; ldo = 1024; gx = 32;
    } else if (b < 8192) {
        l = b - 4096; in = w1; out = w1T; C = 4096; ldo = 1024; gx = 128;
    } else {
        l = b - 8192; in = w2; out = w2T; C = 1024; ldo = 4096; gx = 32;
    }
    int bx = l % gx, by = l / gx;
    __shared__ float tile[32][33];
    int c0 = bx * 32, r0 = by * 32;
    int tx = threadIdx.x & 31, ty = threadIdx.x >> 5;
#pragma unroll
    for (int i = 0; i < 4; i++)
        tile[ty + 8 * i][tx] = in[(long)(r0 + ty + 8 * i) * C + c0 + tx];
    __syncthreads();
#pragma unroll
    for (int i = 0; i < 4; i++)
        out[(long)(c0 + ty + 8 * i) * ldo + r0 + tx] = f2bf(tile[tx][ty + 8 * i]);
}

// ---------------- embedding: xb = bf16(emb[id]*32 + pe) ----------------
__global__ __launch_bounds__(256) void k_embed(
    const int* __restrict__ ids, const float* __restrict__ emb,
    const float* __restrict__ pe, u16* __restrict__ xb)
{
    int row = blockIdx.x;          // b*512 + l
    int l = row & 511;
    long id = (long)ids[row];
    const float* e = emb + id * 1024;
    const float* p = pe + (long)l * 1024;
    u16* xbo = xb + (long)row * 1024;
    int d0 = threadIdx.x * 4;
    float4 ev = *(const float4*)&e[d0];
    float4 pv = *(const float4*)&p[d0];
    ushort4 o;
    o.x = f2bf(ev.x * 32.0f + pv.x);
    o.y = f2bf(ev.y * 32.0f + pv.y);
    o.z = f2bf(ev.z * 32.0f + pv.z);
    o.w = f2bf(ev.w * 32.0f + pv.w);
    *(ushort4*)&xbo[d0] = o;
}

// ---------------- bf16 MFMA GEMM, NT form (small shapes: QKV / WO) -----------------
template <int TM, int TN, bool VT_EPI>
__global__ __launch_bounds__(256) void k_gemm_nt(
    const u16* __restrict__ A, long lda,
    const u16* __restrict__ B, long ldb,
    u16* __restrict__ Cm, long ldc,
    int M, int N, int K,
    const float* __restrict__ bias,
    u16* __restrict__ vTout)
{
    constexpr int FM = TM / 32;     // m-frags per wave
    constexpr int FN = TN / 32;     // n-frags per wave
    constexpr int CPA = TM / 64;    // A chunks per wave per K-plane
    constexpr int CPB = TN / 64;
    __shared__ u16 As[2 * TM * 32];
    __shared__ u16 Bs[2 * TN * 32];
    int m0 = blockIdx.y * TM, n0 = blockIdx.x * TN;
    int tid = threadIdx.x;
    int lane = tid & 63, wid = tid >> 6;
    int wr = wid >> 1, wc = wid & 1;
    int quad = lane >> 4, l16 = lane & 15;

    f32x4 acc[FM][FN];
#pragma unroll
    for (int i = 0; i < FM; i++)
#pragma unroll
        for (int j = 0; j < FN; j++) acc[i][j] = {0.f, 0.f, 0.f, 0.f};

    // staging: chunk = 16 rows x 32 k (1KB); lane l -> row c*16 + l/4, k-seg (l%4)*8
    int seg = (lane & 3) * 8;
    const u16* pA[CPA]; u16* lA[2][CPA];
    const u16* pB[CPB]; u16* lB[2][CPB];
#pragma unroll
    for (int i = 0; i < CPA; i++) {
        int c = wid * CPA + i;
        int gm = min(m0 + c * 16 + (lane >> 2), M - 1);
        pA[i] = A + (long)gm * lda + seg;
        lA[0][i] = &As[c * 512];
        lA[1][i] = &As[TM * 32 + c * 512];
    }
#pragma unroll
    for (int i = 0; i < CPB; i++) {
        int c = wid * CPB + i;
        int gn = min(n0 + c * 16 + (lane >> 2), N - 1);
        pB[i] = B + (long)gn * ldb + seg;
        lB[0][i] = &Bs[c * 512];
        lB[1][i] = &Bs[TN * 32 + c * 512];
    }

    for (int kb = 0; kb < K; kb += 64) {
#pragma unroll
        for (int kh = 0; kh < 2; kh++) {
#pragma unroll
            for (int i = 0; i < CPA; i++) ASYNC_CP16(pA[i] + kb + kh * 32, lA[kh][i]);
#pragma unroll
            for (int i = 0; i < CPB; i++) ASYNC_CP16(pB[i] + kb + kh * 32, lB[kh][i]);
        }
        __syncthreads();
        bf16x8 af[2][FM], bg[2][FN];
#pragma unroll
        for (int kh = 0; kh < 2; kh++)
#pragma unroll
            for (int t = 0; t < FM; t++)
                af[kh][t] = *(const bf16x8*)&As[kh * TM * 32 + (wr * (TM / 2) + t * 16 + l16) * 32 + quad * 8];
#pragma unroll
        for (int kh = 0; kh < 2; kh++)
#pragma unroll
            for (int t = 0; t < FN; t++)
                bg[kh][t] = *(const bf16x8*)&Bs[kh * TN * 32 + (wc * (TN / 2) + t * 16 + l16) * 32 + quad * 8];
#pragma unroll
        for (int kh = 0; kh < 2; kh++)
#pragma unroll
            for (int i = 0; i < FM; i++)
#pragma unroll
                for (int j = 0; j < FN; j++)
                    acc[i][j] = __builtin_amdgcn_mfma_f32_16x16x32_bf16(af[kh][i], bg[kh][j], acc[i][j], 0, 0, 0);
        __syncthreads();
    }

    // epilogue: C/D layout col=lane&15, row=quad*4+r (verified m89/m91)
#pragma unroll
    for (int i = 0; i < FM; i++) {
        int gm0 = m0 + wr * (TM / 2) + i * 16 + quad * 4;
#pragma unroll
        for (int j = 0; j < FN; j++) {
            int gn = n0 + wc * (TN / 2) + j * 16 + l16;
            if (gn >= N) continue;
            float bn = bias[gn];
            if (VT_EPI && gn >= 2048) {
                // V columns -> vT[d][l]: r maps to contiguous l -> ushort4 store
                ushort4 o;
                o.x = f2bf(acc[i][j][0] + bn);
                o.y = f2bf(acc[i][j][1] + bn);
                o.z = f2bf(acc[i][j][2] + bn);
                o.w = f2bf(acc[i][j][3] + bn);
                *(ushort4*)&vTout[(long)(gn - 2048) * 512 + gm0] = o;
                continue;
            }
#pragma unroll
            for (int r = 0; r < 4; r++) {
                int gm = gm0 + r;
                if (gm >= M) continue;
                Cm[(long)gm * ldc + gn] = f2bf(acc[i][j][r] + bn);
            }
        }
    }
}

// ---------------- full-prefetch counted-waitcnt MFMA GEMM, 256x256 (FFN) ------------
// 512 thr = 8 waves (2m x 4n); per-wave C = 128x64. K in 32-wide subtiles, 4 LDS slots.
// Per iter j: issue ALL 12 ds_reads for subtile j+1 (slot resident via prev vmcnt(4)),
// stage subtile j+3; lgkmcnt(12) waits only for LAST iter's reads (long done); then the
// FULL 32-MFMA burst runs from regs while this iter's 12 reads service underneath.
// vmcnt(4) end-of-iter gates slot j+2 residency; ONE barrier/iter. Overwrite safety:
// stage(j+3) hits slot (j-1)&3 whose reads (iter j-2) completed before iter j-1's
// lgkm(12)+barrier. XCD-swizzled blockIdx; 2-way-free LDS bank swizzle via
// inverse-swizzled global src + swizzled ds_read addr.
// SPLITK: blockIdx.z selects K-half; f32 partials at z*M*ldc; bias only z==0.
// Requires M%256==0, N%256==0, K%64==0, K>=256, (gridDim.x*gridDim.y)%8==0.
template <bool SPLITK>
__global__ __launch_bounds__(512, 2) void k_gemm8(
    const u16* __restrict__ A, long lda,
    const u16* __restrict__ B, long ldb,
    u16* __restrict__ Cm, long ldc,
    int K, const float* __restrict__ bias)
{
    constexpr int BM = 256, BN = 256;
    constexpr int MF = 8;
    constexpr int ASLOT = BM * 32;
    constexpr int BSLOT = BN * 32;
    __shared__ u16 As[4 * ASLOT];
    __shared__ u16 Bs[4 * BSLOT];

    // XCD-aware chunked swizzle (bijective since nwg % 8 == 0)
    int lin = blockIdx.y * gridDim.x + blockIdx.x;
    int cpx = (gridDim.x * gridDim.y) >> 3;
    int sw = (lin & 7) * cpx + (lin >> 3);
    int bx = sw % gridDim.x, by = sw / gridDim.x;

    const int m0 = by * BM, n0 = bx * BN;
    const long kbase = SPLITK ? (long)blockIdx.z * K : 0;
    const int tid = threadIdx.x;
    const int lane = tid & 63, wid = tid >> 6;
    const int wm = wid >> 2, wn = wid & 3;
    const int wrow = wm * 128, wcol = wn * 64;
    const int quad = lane >> 4, l16 = lane & 15;

    f32x4 acc[MF][4];
#pragma unroll
    for (int f = 0; f < MF; f++)
#pragma unroll
        for (int g = 0; g < 4; g++) acc[f][g] = {0.f, 0.f, 0.f, 0.f};

    // staging source: lane covers row = i*128 + wid*16 + (lane>>2),
    // k-granule pre-inverse-swizzled: (lane&3) ^ ((lane>>3)&3)
    const int srow = wid * 16 + (lane >> 2);
    const int skoff = (((lane & 3) ^ ((lane >> 3) & 3)) << 3);
    const u16* aSrc = A + (long)(m0 + srow) * lda + kbase + skoff;
    const u16* bSrc = B + (long)(n0 + srow) * ldb + kbase + skoff;

    // swizzled ds_read offsets (u16 units): r*32 + ((quad ^ ((r>>1)&3)) * 8)
    int aoff[MF], boff[4];
#pragma unroll
    for (int f = 0; f < MF; f++) {
        int r = wrow + f * 16 + l16;
        aoff[f] = r * 32 + ((quad ^ ((r >> 1) & 3)) << 3);
    }
#pragma unroll
    for (int g = 0; g < 4; g++) {
        int r = wcol + g * 16 + l16;
        boff[g] = r * 32 + ((quad ^ ((r >> 1) & 3)) << 3);
    }

    auto stageA = [&](int j) {
        u16* d = &As[(j & 3) * ASLOT + wid * 512];
#pragma unroll
        for (int i = 0; i < 2; i++)
            ASYNC_CP16(aSrc + (long)i * 128 * lda + j * 32, d + i * 4096);
    };
    auto stageB = [&](int j) {
        u16* d = &Bs[(j & 3) * BSLOT + wid * 512];
#pragma unroll
        for (int i = 0; i < 2; i++)
            ASYNC_CP16(bSrc + (long)i * 128 * ldb + j * 32, d + i * 4096);
    };

    // prologue: 3 subtiles in flight; slots 0 AND 1 resident (iter 0 reads slot 1)
    stageA(0); stageB(0); stageA(1); stageB(1); stageA(2); stageB(2);
    asm volatile("s_waitcnt vmcnt(4)" ::: "memory");
    __builtin_amdgcn_s_barrier();

    bf16x8 ra[2][MF], rb[2][4];
#pragma unroll
    for (int f = 0; f < MF; f++) ra[0][f] = *(const bf16x8*)&As[aoff[f]];
#pragma unroll
    for (int g = 0; g < 4; g++)  rb[0][g] = *(const bf16x8*)&Bs[boff[g]];

    const int NK = K >> 5;   // NK even, >= 8
    for (int j0 = 0; j0 < NK - 2; j0 += 2) {
#pragma unroll
        for (int u = 0; u < 2; u++) {
            const int j = j0 + u;
            const u16* Abn = &As[((j + 1) & 3) * ASLOT];
            const u16* Bbn = &Bs[((j + 1) & 3) * BSLOT];
            // prefetch ALL of subtile j+1 into the alternate reg set (12 reads)
#pragma unroll
            for (int f = 0; f < MF; f++) ra[u ^ 1][f] = *(const bf16x8*)&Abn[aoff[f]];
#pragma unroll
            for (int g = 0; g < 4; g++)  rb[u ^ 1][g] = *(const bf16x8*)&Bbn[boff[g]];
            if (j + 3 < NK) { stageA(j + 3); stageB(j + 3); }
            __builtin_amdgcn_sched_barrier(0);
            // wait only for LAST iter's 12 reads (set u) -- long since serviced
            asm volatile("s_waitcnt lgkmcnt(12)" ::: "memory");
            __builtin_amdgcn_sched_barrier(0);
            __builtin_amdgcn_s_setprio(1);
#pragma unroll
            for (int f = 0; f < MF; f++)
#pragma unroll
                for (int g = 0; g < 4; g++)
                    acc[f][g] = __builtin_amdgcn_mfma_f32_16x16x32_bf16(ra[u][f], rb[u][g], acc[f][g], 0, 0, 0);
            __builtin_amdgcn_s_setprio(0);
            // residency gate for slot j+2 (read at iter j+1); drain once stages end
            if (j < NK - 3) asm volatile("s_waitcnt vmcnt(4)" ::: "memory");
            else            asm volatile("s_waitcnt vmcnt(0)" ::: "memory");
            __builtin_amdgcn_s_barrier();
        }
    }
    // peel j = NK-2 (set 0): prefetch subtile NK-1, no stage/gate
    {
        const u16* Abn = &As[((NK - 1) & 3) * ASLOT];
        const u16* Bbn = &Bs[((NK - 1) & 3) * BSLOT];
#pragma unroll
        for (int f = 0; f < MF; f++) ra[1][f] = *(const bf16x8*)&Abn[aoff[f]];
#pragma unroll
        for (int g = 0; g < 4; g++)  rb[1][g] = *(const bf16x8*)&Bbn[boff[g]];
        __builtin_amdgcn_sched_barrier(0);
        asm volatile("s_waitcnt lgkmcnt(12)" ::: "memory");
        __builtin_amdgcn_sched_barrier(0);
        __builtin_amdgcn_s_setprio(1);
#pragma unroll
        for (int f = 0; f < MF; f++)
#pragma unroll
            for (int g = 0; g < 4; g++)
                acc[f][g] = __builtin_amdgcn_mfma_f32_16x16x32_bf16(ra[0][f], rb[0][g], acc[f][g], 0, 0, 0);
        __builtin_amdgcn_s_setprio(0);
    }
    // peel j = NK-1 (set 1)
    {
        asm volatile("s_waitcnt lgkmcnt(0)" ::: "memory");
        __builtin_amdgcn_sched_barrier(0);
        __builtin_amdgcn_s_setprio(1);
#pragma unroll
        for (int f = 0; f < MF; f++)
#pragma unroll
            for (int g = 0; g < 4; g++)
                acc[f][g] = __builtin_amdgcn_mfma_f32_16x16x32_bf16(ra[1][f], rb[1][g], acc[f][g], 0, 0, 0);
        __builtin_amdgcn_s_setprio(0);
    }

    // epilogue: C/D layout col=lane&15, row=quad*4+r
    if (SPLITK) {
        float* Co = (float*)Cm + (long)blockIdx.z * (long)gridDim.y * BM * ldc;
        const bool zb = (blockIdx.z == 0);
#pragma unroll
        for (int f = 0; f < MF; f++) {
            int gm0 = m0 + wrow + f * 16 + quad * 4;
#pragma unroll
            for (int g = 0; g < 4; g++) {
                int gn = n0 + wcol + g * 16 + l16;
                float bn = zb ? bias[gn] : 0.f;
#pragma unroll
                for (int r = 0; r < 4; r++)
                    Co[(long)(gm0 + r) * ldc + gn] = acc[f][g][r] + bn;
            }
        }
    } else {
#pragma unroll
        for (int f = 0; f < MF; f++) {
            int gm0 = m0 + wrow + f * 16 + quad * 4;
#pragma unroll
            for (int g = 0; g < 4; g++) {
                int gn = n0 + wcol + g * 16 + l16;
                float bn = bias[gn];
#pragma unroll
                for (int r = 0; r < 4; r++)
                    Cm[(long)(gm0 + r) * ldc + gn] = f2bf(acc[f][g][r] + bn);
            }
        }
    }
}

// ---------------- fused attention: scores+softmax+PV for one (head, 32-q-row) block ---
__global__ __launch_bounds__(128) void k_attn(
    const u16* __restrict__ qkv, const u16* __restrict__ vT, u16* __restrict__ Ob)
{
    __shared__ u16 Ks[2][4096];   // plane layout: idx(key,d) = (d>>5)*2048 + key*32 + (d&31)
    __shared__ u16 Vs[2][4096];   // idx(d,key)   = (key>>5)*2048 + d*32 + (key&31)
    __shared__ u16 Pl[32 * 72];   // [q_local][72]; 144B rows -> 16B-aligned
    int qb = blockIdx.x, h = blockIdx.y;
    int tid = threadIdx.x;
    int w = tid >> 6, lane = tid & 63;
    int quad = lane >> 4, l16 = lane & 15;

    int qrow = qb * 32 + w * 16 + l16;
    bf16x8 aq[2];
#pragma unroll
    for (int c = 0; c < 2; c++)
        aq[c] = *(const bf16x8*)&qkv[(long)qrow * 3072 + h * 64 + c * 32 + quad * 8];

    f32x4 acc_o[4];
#pragma unroll
    for (int j = 0; j < 4; j++) acc_o[j] = {0.f, 0.f, 0.f, 0.f};
    float mrow[4], lrow[4];
#pragma unroll
    for (int r = 0; r < 4; r++) { mrow[r] = -1e30f; lrow[r] = 0.f; }

    {
        int kt = 0;
#pragma unroll
        for (int rr = 0; rr < 4; rr++) {
            int c = rr * 2 + w;
            int loc = (c & 3) * 16 + (lane >> 2);
            int off8 = ((c >> 2) << 5) + (lane & 3) * 8;
            ASYNC_CP16(&qkv[(long)(kt * 64 + loc) * 3072 + 1024 + h * 64 + off8], &Ks[0][c * 512]);
            ASYNC_CP16(&vT[(long)(h * 64 + loc) * 512 + kt * 64 + off8], &Vs[0][c * 512]);
        }
    }
    __syncthreads();

    for (int kt = 0; kt < 8; kt++) {
        int buf = kt & 1;
        if (kt < 7) {
            int nb = buf ^ 1, ktn = kt + 1;
#pragma unroll
            for (int rr = 0; rr < 4; rr++) {
                int c = rr * 2 + w;
                int loc = (c & 3) * 16 + (lane >> 2);
                int off8 = ((c >> 2) << 5) + (lane & 3) * 8;
                ASYNC_CP16(&qkv[(long)(ktn * 64 + loc) * 3072 + 1024 + h * 64 + off8], &Ks[nb][c * 512]);
                ASYNC_CP16(&vT[(long)(h * 64 + loc) * 512 + ktn * 64 + off8], &Vs[nb][c * 512]);
            }
        }
        f32x4 s[4];
#pragma unroll
        for (int ss = 0; ss < 4; ss++) {
            s[ss] = {0.f, 0.f, 0.f, 0.f};
#pragma unroll
            for (int c = 0; c < 2; c++) {
                bf16x8 bk = *(const bf16x8*)&Ks[buf][c * 2048 + (ss * 16 + l16) * 32 + quad * 8];
                s[ss] = __builtin_amdgcn_mfma_f32_16x16x32_bf16(aq[c], bk, s[ss], 0, 0, 0);
            }
        }
        float mt[4];
#pragma unroll
        for (int r = 0; r < 4; r++) {
#pragma unroll
            for (int ss = 0; ss < 4; ss++) s[ss][r] *= 0.125f;
            mt[r] = fmaxf(fmaxf(s[0][r], s[1][r]), fmaxf(s[2][r], s[3][r]));
        }
#pragma unroll
        for (int mask = 1; mask < 16; mask <<= 1)
#pragma unroll
            for (int r = 0; r < 4; r++) mt[r] = fmaxf(mt[r], __shfl_xor(mt[r], mask));
        float al[4], rsum[4];
#pragma unroll
        for (int r = 0; r < 4; r++) {
            float mn = fmaxf(mrow[r], mt[r]);
            al[r] = exp2f((mrow[r] - mn) * L2E);
            mrow[r] = mn;
            rsum[r] = 0.f;
#pragma unroll
            for (int ss = 0; ss < 4; ss++) {
                float p = exp2f((s[ss][r] - mn) * L2E);
                s[ss][r] = p;
                rsum[r] += p;
            }
        }
#pragma unroll
        for (int mask = 1; mask < 16; mask <<= 1)
#pragma unroll
            for (int r = 0; r < 4; r++) rsum[r] += __shfl_xor(rsum[r], mask);
#pragma unroll
        for (int r = 0; r < 4; r++) lrow[r] = lrow[r] * al[r] + rsum[r];
#pragma unroll
        for (int j = 0; j < 4; j++)
#pragma unroll
            for (int r = 0; r < 4; r++) acc_o[j][r] *= al[r];
#pragma unroll
        for (int ss = 0; ss < 4; ss++)
#pragma unroll
            for (int r = 0; r < 4; r++)
                Pl[(w * 16 + quad * 4 + r) * 72 + ss * 16 + l16] = f2bf(s[ss][r]);
#pragma unroll
        for (int kc = 0; kc < 2; kc++) {
            bf16x8 ap = *(const bf16x8*)&Pl[(w * 16 + l16) * 72 + kc * 32 + quad * 8];
#pragma unroll
            for (int j = 0; j < 4; j++) {
                bf16x8 bv = *(const bf16x8*)&Vs[buf][kc * 2048 + (j * 16 + l16) * 32 + quad * 8];
                acc_o[j] = __builtin_amdgcn_mfma_f32_16x16x32_bf16(ap, bv, acc_o[j], 0, 0, 0);
            }
        }
        __syncthreads();
    }

#pragma unroll
    for (int r = 0; r < 4; r++) {
        float inv = 1.0f / lrow[r];
        int gq = qb * 32 + w * 16 + quad * 4 + r;
#pragma unroll
        for (int j = 0; j < 4; j++)
            Ob[(long)gq * 1024 + h * 64 + j * 16 + l16] = f2bf(acc_o[j][r] * inv);
    }
}

// ---------------- xb = bf16(LN(xb + s) * g + beta), wave-per-row, no barrier -----------
__global__ __launch_bounds__(256) void k_add_ln(
    u16* __restrict__ xb, const u16* __restrict__ s, int sBroadcast,
    const float* __restrict__ g, const float* __restrict__ beta)
{
    int row = blockIdx.x * 4 + (threadIdx.x >> 6);   // b*512 + l
    int lane = threadIdx.x & 63;
    int srow = sBroadcast ? (row & 511) : row;
    u16* x = xb + (long)row * 1024;
    const u16* sp = s + (long)srow * 1024;
    int d0 = lane * 16;
    uint4 xa = *(const uint4*)&x[d0];
    uint4 xc = *(const uint4*)&x[d0 + 8];
    uint4 sa = *(const uint4*)&sp[d0];
    uint4 sc = *(const uint4*)&sp[d0 + 8];
    float v[16], t[8];
    unp8(xa, v); unp8(xc, v + 8);
    unp8(sa, t);
#pragma unroll
    for (int i = 0; i < 8; i++) v[i] += t[i];
    unp8(sc, t);
#pragma unroll
    for (int i = 0; i < 8; i++) v[8 + i] += t[i];
    float sum = 0.f, sq = 0.f;
#pragma unroll
    for (int i = 0; i < 16; i++) { sum += v[i]; sq += v[i] * v[i]; }
#pragma unroll
    for (int off = 32; off; off >>= 1) {
        sum += __shfl_xor(sum, off);
        sq += __shfl_xor(sq, off);
    }
    float mean = sum * (1.f / 1024.f);
    float var = sq * (1.f / 1024.f) - mean * mean;
    float rstd = rsqrtf(var + LN_EPS);
    float4 g0 = *(const float4*)&g[d0],      g1 = *(const float4*)&g[d0 + 4];
    float4 g2 = *(const float4*)&g[d0 + 8],  g3 = *(const float4*)&g[d0 + 12];
    float4 b0 = *(const float4*)&beta[d0],     b1 = *(const float4*)&beta[d0 + 4];
    float4 b2 = *(const float4*)&beta[d0 + 8], b3 = *(const float4*)&beta[d0 + 12];
    float gg[16] = {g0.x,g0.y,g0.z,g0.w, g1.x,g1.y,g1.z,g1.w, g2.x,g2.y,g2.z,g2.w, g3.x,g3.y,g3.z,g3.w};
    float bb[16] = {b0.x,b0.y,b0.z,b0.w, b1.x,b1.y,b1.z,b1.w, b2.x,b2.y,b2.z,b2.w, b3.x,b3.y,b3.z,b3.w};
    float y[16];
#pragma unroll
    for (int i = 0; i < 16; i++) y[i] = (v[i] - mean) * rstd * gg[i] + bb[i];
    uint4 oa, oc;
    oa.x = pk2(y[0], y[1]);  oa.y = pk2(y[2], y[3]);
    oa.z = pk2(y[4], y[5]);  oa.w = pk2(y[6], y[7]);
    oc.x = pk2(y[8], y[9]);  oc.y = pk2(y[10], y[11]);
    oc.z = pk2(y[12], y[13]); oc.w = pk2(y[14], y[15]);
    *(uint4*)&x[d0] = oa;
    *(uint4*)&x[d0 + 8] = oc;
}

// ---------------- xb = bf16(LN(xb + p0 + p1) * g + beta) -- f32 split-K partials ------
__global__ __launch_bounds__(256) void k_add_ln2(
    u16* __restrict__ xb, const float* __restrict__ p0, const float* __restrict__ p1,
    const float* __restrict__ g, const float* __restrict__ beta)
{
    int row = blockIdx.x * 4 + (threadIdx.x >> 6);   // b*512 + l
    int lane = threadIdx.x & 63;
    u16* x = xb + (long)row * 1024;
    const float* a0 = p0 + (long)row * 1024;
    const float* a1 = p1 + (long)row * 1024;
    int d0 = lane * 16;
    uint4 xa = *(const uint4*)&x[d0];
    uint4 xc = *(const uint4*)&x[d0 + 8];
    float v[16];
    unp8(xa, v); unp8(xc, v + 8);
#pragma unroll
    for (int i = 0; i < 16; i += 4) {
        float4 q0 = *(const float4*)&a0[d0 + i];
        float4 q1 = *(const float4*)&a1[d0 + i];
        v[i]     += q0.x + q1.x;
        v[i + 1] += q0.y + q1.y;
        v[i + 2] += q0.z + q1.z;
        v[i + 3] += q0.w + q1.w;
    }
    float sum = 0.f, sq = 0.f;
#pragma unroll
    for (int i = 0; i < 16; i++) { sum += v[i]; sq += v[i] * v[i]; }
#pragma unroll
    for (int off = 32; off; off >>= 1) {
        sum += __shfl_xor(sum, off);
        sq += __shfl_xor(sq, off);
    }
    float mean = sum * (1.f / 1024.f);
    float var = sq * (1.f / 1024.f) - mean * mean;
    float rstd = rsqrtf(var + LN_EPS);
    float4 g0 = *(const float4*)&g[d0],      g1 = *(const float4*)&g[d0 + 4];
    float4 g2 = *(const float4*)&g[d0 + 8],  g3 = *(const float4*)&g[d0 + 12];
    float4 b0 = *(const float4*)&beta[d0],     b1 = *(const float4*)&beta[d0 + 4];
    float4 b2 = *(const float4*)&beta[d0 + 8], b3 = *(const float4*)&beta[d0 + 12];
    float gg[16] = {g0.x,g0.y,g0.z,g0.w, g1.x,g1.y,g1.z,g1.w, g2.x,g2.y,g2.z,g2.w, g3.x,g3.y,g3.z,g3.w};
    float bb[16] = {b0.x,b0.y,b0.z,b0.w, b1.x,b1.y,b1.z,b1.w, b2.x,b2.y,b2.z,b2.w, b3.x,b3.y,b3.z,b3.w};
    float y[16];
#pragma unroll
    for (int i = 0; i < 16; i++) y[i] = (v[i] - mean) * rstd * gg[i] + bb[i];
    uint4 oa, oc;
    oa.x = pk2(y[0], y[1]);  oa.y = pk2(y[2], y[3]);
    oa.z = pk2(y[4], y[5]);  oa.w = pk2(y[6], y[7]);
    oc.x = pk2(y[8], y[9]);  oc.y = pk2(y[10], y[11]);
    oc.z = pk2(y[12], y[13]); oc.w = pk2(y[14], y[15]);
    *(uint4*)&x[d0] = oa;
    *(uint4*)&x[d0 + 8] = oc;
}

// ---------------- fused pool+head: out[b][c] = (mean_l x[b][l])·wf[:,c] + bf[c] -----
__global__ __launch_bounds__(256) void k_pool_head(
    const u16* __restrict__ xb, const float* __restrict__ wf,
    const float* __restrict__ bfin, float* __restrict__ out)
{
    int b = blockIdx.x;
    int tid = threadIdx.x;
    __shared__ float pl[1024];
    int d0 = tid * 4;
    const u16* x = xb + (long)b * 512 * 1024;
    float s0 = 0.f, s1 = 0.f, s2 = 0.f, s3 = 0.f;
    for (int l = 0; l < 512; l++) {
        ushort4 v = *(const ushort4*)&x[(long)l * 1024 + d0];
        s0 += bf2f(v.x); s1 += bf2f(v.y); s2 += bf2f(v.z); s3 += bf2f(v.w);
    }
    pl[d0] = s0 * (1.f / 512.f);
    pl[d0 + 1] = s1 * (1.f / 512.f);
    pl[d0 + 2] = s2 * (1.f / 512.f);
    pl[d0 + 3] = s3 * (1.f / 512.f);
    __syncthreads();
    __shared__ float red[4];
    for (int c = 0; c < 10; c++) {
        float t = 0.f;
        for (int d = tid; d < 1024; d += 256) t += pl[d] * wf[(long)d * 10 + c];
        for (int off = 32; off; off >>= 1) t += __shfl_down(t, off);
        if ((tid & 63) == 0) red[tid >> 6] = t;
        __syncthreads();
        if (tid == 0) out[b * 10 + c] = red[0] + red[1] + red[2] + red[3] + bfin[c];
        __syncthreads();
    }
}

// ---------------- host side ----------------
template <int TM, int TN, bool VT_EPI>
static void gemm(const u16* A, long lda, const u16* B, long ldb,
                 u16* C, long ldc,
                 int M, int N, int K, const float* bias,
                 hipStream_t st, u16* vTout = nullptr)
{
    dim3 g((N + TN - 1) / TN, (M + TM - 1) / TM);
    k_gemm_nt<TM, TN, VT_EPI><<<g, 256, 0, st>>>(A, lda, B, ldb, C, ldc, M, N, K, bias, vTout);
}

extern "C" void kernel_launch(void* const* d_in, const int* in_sizes, int n_in,
                              void* d_out, int out_size, void* d_ws, size_t ws_size,
                              hipStream_t stream)
{
    const int* ids   = (const int*)d_in[0];
    const float* emb = (const float*)d_in[1];
    const float* pe  = (const float*)d_in[2];
    const float* wq  = (const float*)d_in[3];
    const float* bq  = (const float*)d_in[4];
    const float* wk  = (const float*)d_in[5];
    const float* bk  = (const float*)d_in[6];
    const float* wv  = (const float*)d_in[7];
    const float* bv  = (const float*)d_in[8];
    const float* wo  = (const float*)d_in[9];
    const float* bo  = (const float*)d_in[10];
    const float* w1  = (const float*)d_in[11];
    const float* b1  = (const float*)d_in[12];
    const float* w2  = (const float*)d_in[13];
    const float* b2  = (const float*)d_in[14];
    const float* g1  = (const float*)d_in[15];
    const float* be1 = (const float*)d_in[16];
    const float* g2  = (const float*)d_in[17];
    const float* be2 = (const float*)d_in[18];
    const float* wf  = (const float*)d_in[19];
    const float* bfi = (const float*)d_in[20];
    float* out = (float*)d_out;

    char* base = (char*)d_ws;
    size_t off = 0;
    auto alloc = [&](size_t bytes) {
        char* p = base + off;
        off = (off + bytes + 255) & ~(size_t)255;
        return p;
    };
    u16*   xb    = (u16*)  alloc(16UL * 512 * 1024 * 2);   // bf16 residual stream [B,L,D]
    u16*   wqkvT = (u16*)  alloc(3072UL * 1024 * 2);       // [3072,1024] = wqT;wkT;wvT
    u16*   woT   = (u16*)  alloc(1024UL * 1024 * 2);
    u16*   w1T   = (u16*)  alloc(4096UL * 1024 * 2);       // [F,D]
    u16*   w2T   = (u16*)  alloc(1024UL * 4096 * 2);       // [D,F]
    float* qkvb  = (float*)alloc(3072UL * 4);              // concat(bq,bk,bv)
    u16*   qkv   = (u16*)  alloc(512UL * 3072 * 2);        // [L, 3*D]; v-part unused (goes to vT)
    u16*   vT    = (u16*)  alloc(1024UL * 512 * 2);        // v transposed [D,L]
    u16*   Ob    = (u16*)  alloc(512UL * 1024 * 2);        // attn context bf16 [L,D]
    u16*   src2  = (u16*)  alloc(512UL * 1024 * 2);        // bf16
    u16*   Hb    = (u16*)  alloc(8192UL * 4096 * 2);       // FFN hidden bf16
    float* ffp   = (float*)alloc(2UL * 8192 * 1024 * 4);   // FFN split-K f32 partials

    k_prep<<<12300, 256, 0, stream>>>(wq, wk, wv, wo, w1, w2, bq, bk, bv, qkvb,
                                      wqkvT, woT, w1T, w2T);
    k_embed<<<8192, 256, 0, stream>>>(ids, emb, pe, xb);

    for (int layer = 0; layer < 6; layer++) {
        // fused q|k|v for batch 0: [512,3072]; V cols written transposed into vT
        gemm<64, 64, true>(xb, 1024, wqkvT, 1024, qkv, 3072, 512, 3072, 1024, qkvb, stream, vT);
        // fused scores+softmax+PV
        k_attn<<<dim3(16, 16), 128, 0, stream>>>(qkv, vT, Ob);
        // src2 = O . wo + bo
        gemm<64, 64, false>(Ob, 1024, woT, 1024, src2, 1024, 512, 1024, 1024, bo, stream);
        k_add_ln<<<2048, 256, 0, stream>>>(xb, src2, 1, g1, be1);
        // FFN GEMM1: [8192,1024]x[4096,1024]^T -> Hb, grid (16,32)=512 blocks
        k_gemm8<false><<<dim3(16, 32), 512, 0, stream>>>(xb, 1024, w1T, 1024, Hb, 4096, 1024, b1);
        // FFN GEMM2: [8192,4096]x[1024,4096]^T, split-K z=2 -> f32 partials (256 blocks)
        k_gemm8<true><<<dim3(4, 32, 2), 512, 0, stream>>>(Hb, 4096, w2T, 4096, (u16*)ffp, 1024, 2048, b2);
        k_add_ln2<<<2048, 256, 0, stream>>>(xb, ffp, ffp + 8192UL * 1024, g2, be2);
    }

    k_pool_head<<<16, 256, 0, stream>>>(xb, wf, bfi, out);
}

// Round 5
// 1170.388 us; speedup vs baseline: 1.3092x; 1.3092x over previous
//
#include <hip/hip_runtime.h>

typedef unsigned short u16;
typedef unsigned int u32;
typedef __bf16 bf16x8 __attribute__((ext_vector_type(8)));
typedef float f32x4 __attribute__((ext_vector_type(4)));

#define LN_EPS 1e-5f
#define L2E 1.44269504f

__device__ __forceinline__ u16 f2bf(float f) {
    u32 u = __float_as_uint(f);
    u += 0x7fffu + ((u >> 16) & 1u);
    return (u16)(u >> 16);
}
__device__ __forceinline__ float bf2f(u32 v) {
    return __uint_as_float(v << 16);
}
__device__ __forceinline__ void unp8(uint4 u, float* v) {
    v[0] = bf2f(u.x & 0xffff); v[1] = bf2f(u.x >> 16);
    v[2] = bf2f(u.y & 0xffff); v[3] = bf2f(u.y >> 16);
    v[4] = bf2f(u.z & 0xffff); v[5] = bf2f(u.z >> 16);
    v[6] = bf2f(u.w & 0xffff); v[7] = bf2f(u.w >> 16);
}
__device__ __forceinline__ u32 pk2(float a, float b) {
    return (u32)f2bf(a) | ((u32)f2bf(b) << 16);
}

// async global->LDS, 16B per lane; lds base must be wave-uniform (HW: base + lane*16)
#define ASYNC_CP16(g, l)                                                      \
    __builtin_amdgcn_global_load_lds(                                         \
        (const __attribute__((address_space(1))) u32*)(g),                    \
        (__attribute__((address_space(3))) u32*)(l), 16, 0, 0)

// ---------------- one-shot prep: weight transposes (f32->bf16), w1 cast, bias concat --
__global__ __launch_bounds__(256) void k_prep(
    const float* __restrict__ wq, const float* __restrict__ wk,
    const float* __restrict__ wv, const float* __restrict__ wo,
    const float* __restrict__ w1, const float* __restrict__ w2,
    const float* __restrict__ bq, const float* __restrict__ bk,
    const float* __restrict__ bv, float* __restrict__ qkvb,
    u16* __restrict__ wqkvT, u16* __restrict__ woT,
    u16* __restrict__ w1b, u16* __restrict__ w2T)
{
    int b = blockIdx.x;
    if (b >= 12288) {
        int i = (b - 12288) * 256 + threadIdx.x;
        qkvb[i] = (i < 1024) ? bq[i] : (i < 2048 ? bk[i - 1024] : bv[i - 2048]);
        return;
    }
    if (b >= 4096 && b < 8192) {
        // straight f32->bf16 cast of w1 [1024][4096] (K-major already; no transpose)
        int i = (b - 4096) * 1024 + threadIdx.x * 4;
        float4 v = *(const float4*)&w1[i];
        ushort4 o;
        o.x = f2bf(v.x); o.y = f2bf(v.y); o.z = f2bf(v.z); o.w = f2bf(v.w);
        *(ushort4*)&w1b[i] = o;
        return;
    }
    const float* in; u16* out; int C; long ldo; int gx; int l;
    if (b < 4096) {
        int j = b >> 10; l = b & 1023;
        in = (j == 0) ? wq : (j == 1) ? wk : (j == 2) ? wv : wo;
        out = (j == 3) ? woT : wqkvT + (long)j * 1024 * 1024;
        C = 1024; ldo = 1024; gx = 32;
    } else {
        l = b - 8192; in = w2; out = w2T; C = 1024; ldo = 4096; gx = 32;
    }
    int bx = l % gx, by = l / gx;
    __shared__ float tile[32][33];
    int c0 = bx * 32, r0 = by * 32;
    int tx = threadIdx.x & 31, ty = threadIdx.x >> 5;
#pragma unroll
    for (int i = 0; i < 4; i++)
        tile[ty + 8 * i][tx] = in[(long)(r0 + ty + 8 * i) * C + c0 + tx];
    __syncthreads();
#pragma unroll
    for (int i = 0; i < 4; i++)
        out[(long)(c0 + ty + 8 * i) * ldo + r0 + tx] = f2bf(tile[tx][ty + 8 * i]);
}

// ---------------- folded FFN bias: b12[e] = sum_f b1[f]*w2[f][e] + b2[e] --------------
__global__ __launch_bounds__(512) void k_bias12(
    const float* __restrict__ b1, const float* __restrict__ w2,
    const float* __restrict__ b2, float* __restrict__ b12)
{
    __shared__ float sh[512];
    int e = blockIdx.x * 128 + (threadIdx.x & 127);
    int fp = threadIdx.x >> 7;           // 0..3, 1024 f's each
    float s = 0.f;
    for (int f = fp * 1024; f < fp * 1024 + 1024; f++)
        s += b1[f] * w2[(long)f * 1024 + e];
    sh[threadIdx.x] = s;
    __syncthreads();
    if (threadIdx.x < 128)
        b12[e] = sh[threadIdx.x] + sh[threadIdx.x + 128] + sh[threadIdx.x + 256]
               + sh[threadIdx.x + 384] + b2[e];
}

// ---------------- embedding: xb = bf16(emb[id]*32 + pe) ----------------
__global__ __launch_bounds__(256) void k_embed(
    const int* __restrict__ ids, const float* __restrict__ emb,
    const float* __restrict__ pe, u16* __restrict__ xb)
{
    int row = blockIdx.x;          // b*512 + l
    int l = row & 511;
    long id = (long)ids[row];
    const float* e = emb + id * 1024;
    const float* p = pe + (long)l * 1024;
    u16* xbo = xb + (long)row * 1024;
    int d0 = threadIdx.x * 4;
    float4 ev = *(const float4*)&e[d0];
    float4 pv = *(const float4*)&p[d0];
    ushort4 o;
    o.x = f2bf(ev.x * 32.0f + pv.x);
    o.y = f2bf(ev.y * 32.0f + pv.y);
    o.z = f2bf(ev.z * 32.0f + pv.z);
    o.w = f2bf(ev.w * 32.0f + pv.w);
    *(ushort4*)&xbo[d0] = o;
}

// ---------------- bf16 MFMA GEMM, NT form (small shapes: QKV / WO / W12 build) -------
template <int TM, int TN, bool VT_EPI>
__global__ __launch_bounds__(256) void k_gemm_nt(
    const u16* __restrict__ A, long lda,
    const u16* __restrict__ B, long ldb,
    u16* __restrict__ Cm, long ldc,
    int M, int N, int K,
    const float* __restrict__ bias,
    u16* __restrict__ vTout)
{
    constexpr int FM = TM / 32;     // m-frags per wave
    constexpr int FN = TN / 32;     // n-frags per wave
    constexpr int CPA = TM / 64;    // A chunks per wave per K-plane
    constexpr int CPB = TN / 64;
    __shared__ u16 As[2 * TM * 32];
    __shared__ u16 Bs[2 * TN * 32];
    int m0 = blockIdx.y * TM, n0 = blockIdx.x * TN;
    int tid = threadIdx.x;
    int lane = tid & 63, wid = tid >> 6;
    int wr = wid >> 1, wc = wid & 1;
    int quad = lane >> 4, l16 = lane & 15;

    f32x4 acc[FM][FN];
#pragma unroll
    for (int i = 0; i < FM; i++)
#pragma unroll
        for (int j = 0; j < FN; j++) acc[i][j] = {0.f, 0.f, 0.f, 0.f};

    // staging: chunk = 16 rows x 32 k (1KB); lane l -> row c*16 + l/4, k-seg (l%4)*8
    int seg = (lane & 3) * 8;
    const u16* pA[CPA]; u16* lA[2][CPA];
    const u16* pB[CPB]; u16* lB[2][CPB];
#pragma unroll
    for (int i = 0; i < CPA; i++) {
        int c = wid * CPA + i;
        int gm = min(m0 + c * 16 + (lane >> 2), M - 1);
        pA[i] = A + (long)gm * lda + seg;
        lA[0][i] = &As[c * 512];
        lA[1][i] = &As[TM * 32 + c * 512];
    }
#pragma unroll
    for (int i = 0; i < CPB; i++) {
        int c = wid * CPB + i;
        int gn = min(n0 + c * 16 + (lane >> 2), N - 1);
        pB[i] = B + (long)gn * ldb + seg;
        lB[0][i] = &Bs[c * 512];
        lB[1][i] = &Bs[TN * 32 + c * 512];
    }

    for (int kb = 0; kb < K; kb += 64) {
#pragma unroll
        for (int kh = 0; kh < 2; kh++) {
#pragma unroll
            for (int i = 0; i < CPA; i++) ASYNC_CP16(pA[i] + kb + kh * 32, lA[kh][i]);
#pragma unroll
            for (int i = 0; i < CPB; i++) ASYNC_CP16(pB[i] + kb + kh * 32, lB[kh][i]);
        }
        __syncthreads();
        bf16x8 af[2][FM], bg[2][FN];
#pragma unroll
        for (int kh = 0; kh < 2; kh++)
#pragma unroll
            for (int t = 0; t < FM; t++)
                af[kh][t] = *(const bf16x8*)&As[kh * TM * 32 + (wr * (TM / 2) + t * 16 + l16) * 32 + quad * 8];
#pragma unroll
        for (int kh = 0; kh < 2; kh++)
#pragma unroll
            for (int t = 0; t < FN; t++)
                bg[kh][t] = *(const bf16x8*)&Bs[kh * TN * 32 + (wc * (TN / 2) + t * 16 + l16) * 32 + quad * 8];
#pragma unroll
        for (int kh = 0; kh < 2; kh++)
#pragma unroll
            for (int i = 0; i < FM; i++)
#pragma unroll
                for (int j = 0; j < FN; j++)
                    acc[i][j] = __builtin_amdgcn_mfma_f32_16x16x32_bf16(af[kh][i], bg[kh][j], acc[i][j], 0, 0, 0);
        __syncthreads();
    }

    // epilogue: C/D layout col=lane&15, row=quad*4+r (verified m89/m91)
#pragma unroll
    for (int i = 0; i < FM; i++) {
        int gm0 = m0 + wr * (TM / 2) + i * 16 + quad * 4;
#pragma unroll
        for (int j = 0; j < FN; j++) {
            int gn = n0 + wc * (TN / 2) + j * 16 + l16;
            if (gn >= N) continue;
            float bn = bias ? bias[gn] : 0.f;
            if (VT_EPI && gn >= 2048) {
                // V columns -> vT[d][l]: r maps to contiguous l -> ushort4 store
                ushort4 o;
                o.x = f2bf(acc[i][j][0] + bn);
                o.y = f2bf(acc[i][j][1] + bn);
                o.z = f2bf(acc[i][j][2] + bn);
                o.w = f2bf(acc[i][j][3] + bn);
                *(ushort4*)&vTout[(long)(gn - 2048) * 512 + gm0] = o;
                continue;
            }
#pragma unroll
            for (int r = 0; r < 4; r++) {
                int gm = gm0 + r;
                if (gm >= M) continue;
                Cm[(long)gm * ldc + gn] = f2bf(acc[i][j][r] + bn);
            }
        }
    }
}

// ---------------- full-prefetch counted-waitcnt MFMA GEMM, 256x256 (FFN) ------------
// 512 thr = 8 waves (2m x 4n); per-wave C = 128x64. K in 32-wide subtiles, 4 LDS slots.
// Per iter j: issue ALL 12 ds_reads for subtile j+1 (slot resident via prev vmcnt(4)),
// stage subtile j+3; lgkmcnt(12) waits only for LAST iter's reads (long done); then the
// FULL 32-MFMA burst runs from regs while this iter's 12 reads service underneath.
// vmcnt(4) end-of-iter gates slot j+2 residency; ONE barrier/iter. XCD-swizzled
// blockIdx; 2-way-free LDS bank swizzle via inverse-swizzled global src + swizzled
// ds_read addr. SPLITK: blockIdx.z selects K-slice; f32 partials at z*M*ldc; bias z==0.
// Requires M%256==0, N%256==0, K%64==0, K>=128, (gridDim.x*gridDim.y)%8==0.
template <bool SPLITK>
__global__ __launch_bounds__(512, 2) void k_gemm8(
    const u16* __restrict__ A, long lda,
    const u16* __restrict__ B, long ldb,
    u16* __restrict__ Cm, long ldc,
    int K, const float* __restrict__ bias)
{
    constexpr int BM = 256, BN = 256;
    constexpr int MF = 8;
    constexpr int ASLOT = BM * 32;
    constexpr int BSLOT = BN * 32;
    __shared__ u16 As[4 * ASLOT];
    __shared__ u16 Bs[4 * BSLOT];

    // XCD-aware chunked swizzle (bijective since nwg % 8 == 0)
    int lin = blockIdx.y * gridDim.x + blockIdx.x;
    int cpx = (gridDim.x * gridDim.y) >> 3;
    int sw = (lin & 7) * cpx + (lin >> 3);
    int bx = sw % gridDim.x, by = sw / gridDim.x;

    const int m0 = by * BM, n0 = bx * BN;
    const long kbase = SPLITK ? (long)blockIdx.z * K : 0;
    const int tid = threadIdx.x;
    const int lane = tid & 63, wid = tid >> 6;
    const int wm = wid >> 2, wn = wid & 3;
    const int wrow = wm * 128, wcol = wn * 64;
    const int quad = lane >> 4, l16 = lane & 15;

    f32x4 acc[MF][4];
#pragma unroll
    for (int f = 0; f < MF; f++)
#pragma unroll
        for (int g = 0; g < 4; g++) acc[f][g] = {0.f, 0.f, 0.f, 0.f};

    // staging source: lane covers row = i*128 + wid*16 + (lane>>2),
    // k-granule pre-inverse-swizzled: (lane&3) ^ ((lane>>3)&3)
    const int srow = wid * 16 + (lane >> 2);
    const int skoff = (((lane & 3) ^ ((lane >> 3) & 3)) << 3);
    const u16* aSrc = A + (long)(m0 + srow) * lda + kbase + skoff;
    const u16* bSrc = B + (long)(n0 + srow) * ldb + kbase + skoff;

    // swizzled ds_read offsets (u16 units): r*32 + ((quad ^ ((r>>1)&3)) * 8)
    int aoff[MF], boff[4];
#pragma unroll
    for (int f = 0; f < MF; f++) {
        int r = wrow + f * 16 + l16;
        aoff[f] = r * 32 + ((quad ^ ((r >> 1) & 3)) << 3);
    }
#pragma unroll
    for (int g = 0; g < 4; g++) {
        int r = wcol + g * 16 + l16;
        boff[g] = r * 32 + ((quad ^ ((r >> 1) & 3)) << 3);
    }

    auto stageA = [&](int j) {
        u16* d = &As[(j & 3) * ASLOT + wid * 512];
#pragma unroll
        for (int i = 0; i < 2; i++)
            ASYNC_CP16(aSrc + (long)i * 128 * lda + j * 32, d + i * 4096);
    };
    auto stageB = [&](int j) {
        u16* d = &Bs[(j & 3) * BSLOT + wid * 512];
#pragma unroll
        for (int i = 0; i < 2; i++)
            ASYNC_CP16(bSrc + (long)i * 128 * ldb + j * 32, d + i * 4096);
    };

    // prologue: 3 subtiles in flight; slots 0 AND 1 resident (iter 0 reads slot 1)
    stageA(0); stageB(0); stageA(1); stageB(1); stageA(2); stageB(2);
    asm volatile("s_waitcnt vmcnt(4)" ::: "memory");
    __builtin_amdgcn_s_barrier();

    bf16x8 ra[2][MF], rb[2][4];
#pragma unroll
    for (int f = 0; f < MF; f++) ra[0][f] = *(const bf16x8*)&As[aoff[f]];
#pragma unroll
    for (int g = 0; g < 4; g++)  rb[0][g] = *(const bf16x8*)&Bs[boff[g]];

    const int NK = K >> 5;   // NK even, >= 4
    for (int j0 = 0; j0 < NK - 2; j0 += 2) {
#pragma unroll
        for (int u = 0; u < 2; u++) {
            const int j = j0 + u;
            const u16* Abn = &As[((j + 1) & 3) * ASLOT];
            const u16* Bbn = &Bs[((j + 1) & 3) * BSLOT];
            // prefetch ALL of subtile j+1 into the alternate reg set (12 reads)
#pragma unroll
            for (int f = 0; f < MF; f++) ra[u ^ 1][f] = *(const bf16x8*)&Abn[aoff[f]];
#pragma unroll
            for (int g = 0; g < 4; g++)  rb[u ^ 1][g] = *(const bf16x8*)&Bbn[boff[g]];
            if (j + 3 < NK) { stageA(j + 3); stageB(j + 3); }
            __builtin_amdgcn_sched_barrier(0);
            // wait only for LAST iter's 12 reads (set u) -- long since serviced
            asm volatile("s_waitcnt lgkmcnt(12)" ::: "memory");
            __builtin_amdgcn_sched_barrier(0);
            __builtin_amdgcn_s_setprio(1);
#pragma unroll
            for (int f = 0; f < MF; f++)
#pragma unroll
                for (int g = 0; g < 4; g++)
                    acc[f][g] = __builtin_amdgcn_mfma_f32_16x16x32_bf16(ra[u][f], rb[u][g], acc[f][g], 0, 0, 0);
            __builtin_amdgcn_s_setprio(0);
            // residency gate for slot j+2 (read at iter j+1); drain once stages end
            if (j < NK - 3) asm volatile("s_waitcnt vmcnt(4)" ::: "memory");
            else            asm volatile("s_waitcnt vmcnt(0)" ::: "memory");
            __builtin_amdgcn_s_barrier();
        }
    }
    // peel j = NK-2 (set 0): prefetch subtile NK-1, no stage/gate
    {
        const u16* Abn = &As[((NK - 1) & 3) * ASLOT];
        const u16* Bbn = &Bs[((NK - 1) & 3) * BSLOT];
#pragma unroll
        for (int f = 0; f < MF; f++) ra[1][f] = *(const bf16x8*)&Abn[aoff[f]];
#pragma unroll
        for (int g = 0; g < 4; g++)  rb[1][g] = *(const bf16x8*)&Bbn[boff[g]];
        __builtin_amdgcn_sched_barrier(0);
        asm volatile("s_waitcnt lgkmcnt(12)" ::: "memory");
        __builtin_amdgcn_sched_barrier(0);
        __builtin_amdgcn_s_setprio(1);
#pragma unroll
        for (int f = 0; f < MF; f++)
#pragma unroll
            for (int g = 0; g < 4; g++)
                acc[f][g] = __builtin_amdgcn_mfma_f32_16x16x32_bf16(ra[0][f], rb[0][g], acc[f][g], 0, 0, 0);
        __builtin_amdgcn_s_setprio(0);
    }
    // peel j = NK-1 (set 1)
    {
        asm volatile("s_waitcnt lgkmcnt(0)" ::: "memory");
        __builtin_amdgcn_sched_barrier(0);
        __builtin_amdgcn_s_setprio(1);
#pragma unroll
        for (int f = 0; f < MF; f++)
#pragma unroll
            for (int g = 0; g < 4; g++)
                acc[f][g] = __builtin_amdgcn_mfma_f32_16x16x32_bf16(ra[1][f], rb[1][g], acc[f][g], 0, 0, 0);
        __builtin_amdgcn_s_setprio(0);
    }

    // epilogue: C/D layout col=lane&15, row=quad*4+r
    if (SPLITK) {
        float* Co = (float*)Cm + (long)blockIdx.z * (long)gridDim.y * BM * ldc;
        const bool zb = (blockIdx.z == 0);
#pragma unroll
        for (int f = 0; f < MF; f++) {
            int gm0 = m0 + wrow + f * 16 + quad * 4;
#pragma unroll
            for (int g = 0; g < 4; g++) {
                int gn = n0 + wcol + g * 16 + l16;
                float bn = zb ? bias[gn] : 0.f;
#pragma unroll
                for (int r = 0; r < 4; r++)
                    Co[(long)(gm0 + r) * ldc + gn] = acc[f][g][r] + bn;
            }
        }
    } else {
#pragma unroll
        for (int f = 0; f < MF; f++) {
            int gm0 = m0 + wrow + f * 16 + quad * 4;
#pragma unroll
            for (int g = 0; g < 4; g++) {
                int gn = n0 + wcol + g * 16 + l16;
                float bn = bias[gn];
#pragma unroll
                for (int r = 0; r < 4; r++)
                    Cm[(long)(gm0 + r) * ldc + gn] = f2bf(acc[f][g][r] + bn);
            }
        }
    }
}

// ---------------- fused attention: scores+softmax+PV for one (head, 32-q-row) block ---
__global__ __launch_bounds__(128) void k_attn(
    const u16* __restrict__ qkv, const u16* __restrict__ vT, u16* __restrict__ Ob)
{
    __shared__ u16 Ks[2][4096];   // plane layout: idx(key,d) = (d>>5)*2048 + key*32 + (d&31)
    __shared__ u16 Vs[2][4096];   // idx(d,key)   = (key>>5)*2048 + d*32 + (key&31)
    __shared__ u16 Pl[32 * 72];   // [q_local][72]; 144B rows -> 16B-aligned
    int qb = blockIdx.x, h = blockIdx.y;
    int tid = threadIdx.x;
    int w = tid >> 6, lane = tid & 63;
    int quad = lane >> 4, l16 = lane & 15;

    int qrow = qb * 32 + w * 16 + l16;
    bf16x8 aq[2];
#pragma unroll
    for (int c = 0; c < 2; c++)
        aq[c] = *(const bf16x8*)&qkv[(long)qrow * 3072 + h * 64 + c * 32 + quad * 8];

    f32x4 acc_o[4];
#pragma unroll
    for (int j = 0; j < 4; j++) acc_o[j] = {0.f, 0.f, 0.f, 0.f};
    float mrow[4], lrow[4];
#pragma unroll
    for (int r = 0; r < 4; r++) { mrow[r] = -1e30f; lrow[r] = 0.f; }

    {
        int kt = 0;
#pragma unroll
        for (int rr = 0; rr < 4; rr++) {
            int c = rr * 2 + w;
            int loc = (c & 3) * 16 + (lane >> 2);
            int off8 = ((c >> 2) << 5) + (lane & 3) * 8;
            ASYNC_CP16(&qkv[(long)(kt * 64 + loc) * 3072 + 1024 + h * 64 + off8], &Ks[0][c * 512]);
            ASYNC_CP16(&vT[(long)(h * 64 + loc) * 512 + kt * 64 + off8], &Vs[0][c * 512]);
        }
    }
    __syncthreads();

    for (int kt = 0; kt < 8; kt++) {
        int buf = kt & 1;
        if (kt < 7) {
            int nb = buf ^ 1, ktn = kt + 1;
#pragma unroll
            for (int rr = 0; rr < 4; rr++) {
                int c = rr * 2 + w;
                int loc = (c & 3) * 16 + (lane >> 2);
                int off8 = ((c >> 2) << 5) + (lane & 3) * 8;
                ASYNC_CP16(&qkv[(long)(ktn * 64 + loc) * 3072 + 1024 + h * 64 + off8], &Ks[nb][c * 512]);
                ASYNC_CP16(&vT[(long)(h * 64 + loc) * 512 + ktn * 64 + off8], &Vs[nb][c * 512]);
            }
        }
        f32x4 s[4];
#pragma unroll
        for (int ss = 0; ss < 4; ss++) {
            s[ss] = {0.f, 0.f, 0.f, 0.f};
#pragma unroll
            for (int c = 0; c < 2; c++) {
                bf16x8 bk = *(const bf16x8*)&Ks[buf][c * 2048 + (ss * 16 + l16) * 32 + quad * 8];
                s[ss] = __builtin_amdgcn_mfma_f32_16x16x32_bf16(aq[c], bk, s[ss], 0, 0, 0);
            }
        }
        float mt[4];
#pragma unroll
        for (int r = 0; r < 4; r++) {
#pragma unroll
            for (int ss = 0; ss < 4; ss++) s[ss][r] *= 0.125f;
            mt[r] = fmaxf(fmaxf(s[0][r], s[1][r]), fmaxf(s[2][r], s[3][r]));
        }
#pragma unroll
        for (int mask = 1; mask < 16; mask <<= 1)
#pragma unroll
            for (int r = 0; r < 4; r++) mt[r] = fmaxf(mt[r], __shfl_xor(mt[r], mask));
        float al[4], rsum[4];
#pragma unroll
        for (int r = 0; r < 4; r++) {
            float mn = fmaxf(mrow[r], mt[r]);
            al[r] = exp2f((mrow[r] - mn) * L2E);
            mrow[r] = mn;
            rsum[r] = 0.f;
#pragma unroll
            for (int ss = 0; ss < 4; ss++) {
                float p = exp2f((s[ss][r] - mn) * L2E);
                s[ss][r] = p;
                rsum[r] += p;
            }
        }
#pragma unroll
        for (int mask = 1; mask < 16; mask <<= 1)
#pragma unroll
            for (int r = 0; r < 4; r++) rsum[r] += __shfl_xor(rsum[r], mask);
#pragma unroll
        for (int r = 0; r < 4; r++) lrow[r] = lrow[r] * al[r] + rsum[r];
#pragma unroll
        for (int j = 0; j < 4; j++)
#pragma unroll
            for (int r = 0; r < 4; r++) acc_o[j][r] *= al[r];
#pragma unroll
        for (int ss = 0; ss < 4; ss++)
#pragma unroll
            for (int r = 0; r < 4; r++)
                Pl[(w * 16 + quad * 4 + r) * 72 + ss * 16 + l16] = f2bf(s[ss][r]);
#pragma unroll
        for (int kc = 0; kc < 2; kc++) {
            bf16x8 ap = *(const bf16x8*)&Pl[(w * 16 + l16) * 72 + kc * 32 + quad * 8];
#pragma unroll
            for (int j = 0; j < 4; j++) {
                bf16x8 bv = *(const bf16x8*)&Vs[buf][kc * 2048 + (j * 16 + l16) * 32 + quad * 8];
                acc_o[j] = __builtin_amdgcn_mfma_f32_16x16x32_bf16(ap, bv, acc_o[j], 0, 0, 0);
            }
        }
        __syncthreads();
    }

#pragma unroll
    for (int r = 0; r < 4; r++) {
        float inv = 1.0f / lrow[r];
        int gq = qb * 32 + w * 16 + quad * 4 + r;
#pragma unroll
        for (int j = 0; j < 4; j++)
            Ob[(long)gq * 1024 + h * 64 + j * 16 + l16] = f2bf(acc_o[j][r] * inv);
    }
}

// ---------------- xb = bf16(LN(xb + s) * g + beta), wave-per-row, no barrier -----------
__global__ __launch_bounds__(256) void k_add_ln(
    u16* __restrict__ xb, const u16* __restrict__ s, int sBroadcast,
    const float* __restrict__ g, const float* __restrict__ beta)
{
    int row = blockIdx.x * 4 + (threadIdx.x >> 6);   // b*512 + l
    int lane = threadIdx.x & 63;
    int srow = sBroadcast ? (row & 511) : row;
    u16* x = xb + (long)row * 1024;
    const u16* sp = s + (long)srow * 1024;
    int d0 = lane * 16;
    uint4 xa = *(const uint4*)&x[d0];
    uint4 xc = *(const uint4*)&x[d0 + 8];
    uint4 sa = *(const uint4*)&sp[d0];
    uint4 sc = *(const uint4*)&sp[d0 + 8];
    float v[16], t[8];
    unp8(xa, v); unp8(xc, v + 8);
    unp8(sa, t);
#pragma unroll
    for (int i = 0; i < 8; i++) v[i] += t[i];
    unp8(sc, t);
#pragma unroll
    for (int i = 0; i < 8; i++) v[8 + i] += t[i];
    float sum = 0.f, sq = 0.f;
#pragma unroll
    for (int i = 0; i < 16; i++) { sum += v[i]; sq += v[i] * v[i]; }
#pragma unroll
    for (int off = 32; off; off >>= 1) {
        sum += __shfl_xor(sum, off);
        sq += __shfl_xor(sq, off);
    }
    float mean = sum * (1.f / 1024.f);
    float var = sq * (1.f / 1024.f) - mean * mean;
    float rstd = rsqrtf(var + LN_EPS);
    float4 g0 = *(const float4*)&g[d0],      g1 = *(const float4*)&g[d0 + 4];
    float4 g2 = *(const float4*)&g[d0 + 8],  g3 = *(const float4*)&g[d0 + 12];
    float4 b0 = *(const float4*)&beta[d0],     b1 = *(const float4*)&beta[d0 + 4];
    float4 b2 = *(const float4*)&beta[d0 + 8], b3 = *(const float4*)&beta[d0 + 12];
    float gg[16] = {g0.x,g0.y,g0.z,g0.w, g1.x,g1.y,g1.z,g1.w, g2.x,g2.y,g2.z,g2.w, g3.x,g3.y,g3.z,g3.w};
    float bb[16] = {b0.x,b0.y,b0.z,b0.w, b1.x,b1.y,b1.z,b1.w, b2.x,b2.y,b2.z,b2.w, b3.x,b3.y,b3.z,b3.w};
    float y[16];
#pragma unroll
    for (int i = 0; i < 16; i++) y[i] = (v[i] - mean) * rstd * gg[i] + bb[i];
    uint4 oa, oc;
    oa.x = pk2(y[0], y[1]);  oa.y = pk2(y[2], y[3]);
    oa.z = pk2(y[4], y[5]);  oa.w = pk2(y[6], y[7]);
    oc.x = pk2(y[8], y[9]);  oc.y = pk2(y[10], y[11]);
    oc.z = pk2(y[12], y[13]); oc.w = pk2(y[14], y[15]);
    *(uint4*)&x[d0] = oa;
    *(uint4*)&x[d0 + 8] = oc;
}

// ---------------- xb = bf16(LN(xb + p0 + p1) * g + beta) -- f32 split-K partials ------
__global__ __launch_bounds__(256) void k_add_ln2(
    u16* __restrict__ xb, const float* __restrict__ p0, const float* __restrict__ p1,
    const float* __restrict__ g, const float* __restrict__ beta)
{
    int row = blockIdx.x * 4 + (threadIdx.x >> 6);   // b*512 + l
    int lane = threadIdx.x & 63;
    u16* x = xb + (long)row * 1024;
    const float* a0 = p0 + (long)row * 1024;
    const float* a1 = p1 + (long)row * 1024;
    int d0 = lane * 16;
    uint4 xa = *(const uint4*)&x[d0];
    uint4 xc = *(const uint4*)&x[d0 + 8];
    float v[16];
    unp8(xa, v); unp8(xc, v + 8);
#pragma unroll
    for (int i = 0; i < 16; i += 4) {
        float4 q0 = *(const float4*)&a0[d0 + i];
        float4 q1 = *(const float4*)&a1[d0 + i];
        v[i]     += q0.x + q1.x;
        v[i + 1] += q0.y + q1.y;
        v[i + 2] += q0.z + q1.z;
        v[i + 3] += q0.w + q1.w;
    }
    float sum = 0.f, sq = 0.f;
#pragma unroll
    for (int i = 0; i < 16; i++) { sum += v[i]; sq += v[i] * v[i]; }
#pragma unroll
    for (int off = 32; off; off >>= 1) {
        sum += __shfl_xor(sum, off);
        sq += __shfl_xor(sq, off);
    }
    float mean = sum * (1.f / 1024.f);
    float var = sq * (1.f / 1024.f) - mean * mean;
    float rstd = rsqrtf(var + LN_EPS);
    float4 g0 = *(const float4*)&g[d0],      g1 = *(const float4*)&g[d0 + 4];
    float4 g2 = *(const float4*)&g[d0 + 8],  g3 = *(const float4*)&g[d0 + 12];
    float4 b0 = *(const float4*)&beta[d0],     b1 = *(const float4*)&beta[d0 + 4];
    float4 b2 = *(const float4*)&beta[d0 + 8], b3 = *(const float4*)&beta[d0 + 12];
    float gg[16] = {g0.x,g0.y,g0.z,g0.w, g1.x,g1.y,g1.z,g1.w, g2.x,g2.y,g2.z,g2.w, g3.x,g3.y,g3.z,g3.w};
    float bb[16] = {b0.x,b0.y,b0.z,b0.w, b1.x,b1.y,b1.z,b1.w, b2.x,b2.y,b2.z,b2.w, b3.x,b3.y,b3.z,b3.w};
    float y[16];
#pragma unroll
    for (int i = 0; i < 16; i++) y[i] = (v[i] - mean) * rstd * gg[i] + bb[i];
    uint4 oa, oc;
    oa.x = pk2(y[0], y[1]);  oa.y = pk2(y[2], y[3]);
    oa.z = pk2(y[4], y[5]);  oa.w = pk2(y[6], y[7]);
    oc.x = pk2(y[8], y[9]);  oc.y = pk2(y[10], y[11]);
    oc.z = pk2(y[12], y[13]); oc.w = pk2(y[14], y[15]);
    *(uint4*)&x[d0] = oa;
    *(uint4*)&x[d0 + 8] = oc;
}

// ---------------- fused pool+head: out[b][c] = (mean_l x[b][l])·wf[:,c] + bf[c] -----
__global__ __launch_bounds__(256) void k_pool_head(
    const u16* __restrict__ xb, const float* __restrict__ wf,
    const float* __restrict__ bfin, float* __restrict__ out)
{
    int b = blockIdx.x;
    int tid = threadIdx.x;
    __shared__ float pl[1024];
    int d0 = tid * 4;
    const u16* x = xb + (long)b * 512 * 1024;
    float s0 = 0.f, s1 = 0.f, s2 = 0.f, s3 = 0.f;
    for (int l = 0; l < 512; l++) {
        ushort4 v = *(const ushort4*)&x[(long)l * 1024 + d0];
        s0 += bf2f(v.x); s1 += bf2f(v.y); s2 += bf2f(v.z); s3 += bf2f(v.w);
    }
    pl[d0] = s0 * (1.f / 512.f);
    pl[d0 + 1] = s1 * (1.f / 512.f);
    pl[d0 + 2] = s2 * (1.f / 512.f);
    pl[d0 + 3] = s3 * (1.f / 512.f);
    __syncthreads();
    __shared__ float red[4];
    for (int c = 0; c < 10; c++) {
        float t = 0.f;
        for (int d = tid; d < 1024; d += 256) t += pl[d] * wf[(long)d * 10 + c];
        for (int off = 32; off; off >>= 1) t += __shfl_down(t, off);
        if ((tid & 63) == 0) red[tid >> 6] = t;
        __syncthreads();
        if (tid == 0) out[b * 10 + c] = red[0] + red[1] + red[2] + red[3] + bfin[c];
        __syncthreads();
    }
}

// ---------------- host side ----------------
template <int TM, int TN, bool VT_EPI>
static void gemm(const u16* A, long lda, const u16* B, long ldb,
                 u16* C, long ldc,
                 int M, int N, int K, const float* bias,
                 hipStream_t st, u16* vTout = nullptr)
{
    dim3 g((N + TN - 1) / TN, (M + TM - 1) / TM);
    k_gemm_nt<TM, TN, VT_EPI><<<g, 256, 0, st>>>(A, lda, B, ldb, C, ldc, M, N, K, bias, vTout);
}

extern "C" void kernel_launch(void* const* d_in, const int* in_sizes, int n_in,
                              void* d_out, int out_size, void* d_ws, size_t ws_size,
                              hipStream_t stream)
{
    const int* ids   = (const int*)d_in[0];
    const float* emb = (const float*)d_in[1];
    const float* pe  = (const float*)d_in[2];
    const float* wq  = (const float*)d_in[3];
    const float* bq  = (const float*)d_in[4];
    const float* wk  = (const float*)d_in[5];
    const float* bk  = (const float*)d_in[6];
    const float* wv  = (const float*)d_in[7];
    const float* bv  = (const float*)d_in[8];
    const float* wo  = (const float*)d_in[9];
    const float* bo  = (const float*)d_in[10];
    const float* w1  = (const float*)d_in[11];
    const float* b1  = (const float*)d_in[12];
    const float* w2  = (const float*)d_in[13];
    const float* b2  = (const float*)d_in[14];
    const float* g1  = (const float*)d_in[15];
    const float* be1 = (const float*)d_in[16];
    const float* g2  = (const float*)d_in[17];
    const float* be2 = (const float*)d_in[18];
    const float* wf  = (const float*)d_in[19];
    const float* bfi = (const float*)d_in[20];
    float* out = (float*)d_out;

    char* base = (char*)d_ws;
    size_t off = 0;
    auto alloc = [&](size_t bytes) {
        char* p = base + off;
        off = (off + bytes + 255) & ~(size_t)255;
        return p;
    };
    u16*   xb    = (u16*)  alloc(16UL * 512 * 1024 * 2);   // bf16 residual stream [B,L,D]
    u16*   wqkvT = (u16*)  alloc(3072UL * 1024 * 2);       // [3072,1024] = wqT;wkT;wvT
    u16*   woT   = (u16*)  alloc(1024UL * 1024 * 2);
    u16*   w1b   = (u16*)  alloc(1024UL * 4096 * 2);       // bf16 cast of w1 [D,F]
    u16*   w2T   = (u16*)  alloc(1024UL * 4096 * 2);       // [D,F] = w2 transposed
    u16*   W12T  = (u16*)  alloc(1024UL * 1024 * 2);       // folded FFN weight, [e][d]
    float* b12f  = (float*)alloc(1024UL * 4);              // folded FFN bias
    float* qkvb  = (float*)alloc(3072UL * 4);              // concat(bq,bk,bv)
    u16*   qkv   = (u16*)  alloc(512UL * 3072 * 2);        // [L, 3*D]; v-part goes to vT
    u16*   vT    = (u16*)  alloc(1024UL * 512 * 2);        // v transposed [D,L]
    u16*   Ob    = (u16*)  alloc(512UL * 1024 * 2);        // attn context bf16 [L,D]
    u16*   src2  = (u16*)  alloc(512UL * 1024 * 2);        // bf16
    float* ffp   = (float*)alloc(2UL * 8192 * 1024 * 4);   // FFN split-K f32 partials

    k_prep<<<12300, 256, 0, stream>>>(wq, wk, wv, wo, w1, w2, bq, bk, bv, qkvb,
                                      wqkvT, woT, w1b, w2T);
    k_bias12<<<8, 512, 0, stream>>>(b1, w2, b2, b12f);
    k_embed<<<8192, 256, 0, stream>>>(ids, emb, pe, xb);
    // W12T[e][d] = sum_f w2T[e][f] * w1b[d][f]  (one-time folded FFN weight)
    gemm<64, 64, false>(w2T, 4096, w1b, 4096, W12T, 1024, 1024, 1024, 4096, nullptr, stream);

    for (int layer = 0; layer < 6; layer++) {
        // fused q|k|v for batch 0: [512,3072]; V cols written transposed into vT
        gemm<64, 64, true>(xb, 1024, wqkvT, 1024, qkv, 3072, 512, 3072, 1024, qkvb, stream, vT);
        // fused scores+softmax+PV
        k_attn<<<dim3(16, 16), 128, 0, stream>>>(qkv, vT, Ob);
        // src2 = O . wo + bo
        gemm<64, 64, false>(Ob, 1024, woT, 1024, src2, 1024, 512, 1024, 1024, bo, stream);
        k_add_ln<<<2048, 256, 0, stream>>>(xb, src2, 1, g1, be1);
        // folded FFN: ff = xb @ W12T^T + b12, split-K z=2 (K=512 each) -> f32 partials
        k_gemm8<true><<<dim3(4, 32, 2), 512, 0, stream>>>(xb, 1024, W12T, 1024,
                                                          (u16*)ffp, 1024, 512, b12f);
        k_add_ln2<<<2048, 256, 0, stream>>>(xb, ffp, ffp + 8192UL * 1024, g2, be2);
    }

    k_pool_head<<<16, 256, 0, stream>>>(xb, wf, bfi, out);
}

// Round 6
// 910.239 us; speedup vs baseline: 1.6834x; 1.2858x over previous
//
#include <hip/hip_runtime.h>

typedef unsigned short u16;
typedef unsigned int u32;
typedef __bf16 bf16x8 __attribute__((ext_vector_type(8)));
typedef float f32x4 __attribute__((ext_vector_type(4)));

#define LN_EPS 1e-5f
#define L2E 1.44269504f

__device__ __forceinline__ u16 f2bf(float f) {
    u32 u = __float_as_uint(f);
    u += 0x7fffu + ((u >> 16) & 1u);
    return (u16)(u >> 16);
}
__device__ __forceinline__ float bf2f(u32 v) {
    return __uint_as_float(v << 16);
}
__device__ __forceinline__ void unp8(uint4 u, float* v) {
    v[0] = bf2f(u.x & 0xffff); v[1] = bf2f(u.x >> 16);
    v[2] = bf2f(u.y & 0xffff); v[3] = bf2f(u.y >> 16);
    v[4] = bf2f(u.z & 0xffff); v[5] = bf2f(u.z >> 16);
    v[6] = bf2f(u.w & 0xffff); v[7] = bf2f(u.w >> 16);
}
__device__ __forceinline__ u32 pk2(float a, float b) {
    return (u32)f2bf(a) | ((u32)f2bf(b) << 16);
}

// async global->LDS, 16B per lane; lds base must be wave-uniform (HW: base + lane*16)
#define ASYNC_CP16(g, l)                                                      \
    __builtin_amdgcn_global_load_lds(                                         \
        (const __attribute__((address_space(1))) u32*)(g),                    \
        (__attribute__((address_space(3))) u32*)(l), 16, 0, 0)

// ---------------- one-shot prep: weight transposes (f32->bf16), w1 cast, bias concat --
__global__ __launch_bounds__(256) void k_prep(
    const float* __restrict__ wq, const float* __restrict__ wk,
    const float* __restrict__ wv, const float* __restrict__ wo,
    const float* __restrict__ w1, const float* __restrict__ w2,
    const float* __restrict__ bq, const float* __restrict__ bk,
    const float* __restrict__ bv, float* __restrict__ qkvb,
    u16* __restrict__ wqkvT, u16* __restrict__ woT,
    u16* __restrict__ w1b, u16* __restrict__ w2T)
{
    int b = blockIdx.x;
    if (b >= 12288) {
        int i = (b - 12288) * 256 + threadIdx.x;
        qkvb[i] = (i < 1024) ? bq[i] : (i < 2048 ? bk[i - 1024] : bv[i - 2048]);
        return;
    }
    if (b >= 4096 && b < 8192) {
        // straight f32->bf16 cast of w1 [1024][4096] (K-major already; no transpose)
        int i = (b - 4096) * 1024 + threadIdx.x * 4;
        float4 v = *(const float4*)&w1[i];
        ushort4 o;
        o.x = f2bf(v.x); o.y = f2bf(v.y); o.z = f2bf(v.z); o.w = f2bf(v.w);
        *(ushort4*)&w1b[i] = o;
        return;
    }
    const float* in; u16* out; int C; long ldo; int gx; int l;
    if (b < 4096) {
        int j = b >> 10; l = b & 1023;
        in = (j == 0) ? wq : (j == 1) ? wk : (j == 2) ? wv : wo;
        out = (j == 3) ? woT : wqkvT + (long)j * 1024 * 1024;
        C = 1024; ldo = 1024; gx = 32;
    } else {
        l = b - 8192; in = w2; out = w2T; C = 1024; ldo = 4096; gx = 32;
    }
    int bx = l % gx, by = l / gx;
    __shared__ float tile[32][33];
    int c0 = bx * 32, r0 = by * 32;
    int tx = threadIdx.x & 31, ty = threadIdx.x >> 5;
#pragma unroll
    for (int i = 0; i < 4; i++)
        tile[ty + 8 * i][tx] = in[(long)(r0 + ty + 8 * i) * C + c0 + tx];
    __syncthreads();
#pragma unroll
    for (int i = 0; i < 4; i++)
        out[(long)(c0 + ty + 8 * i) * ldo + r0 + tx] = f2bf(tile[tx][ty + 8 * i]);
}

// ---------------- folded FFN bias, stage A: partial[fc][e] = sum_{f in chunk} b1[f]*w2[f][e]
__global__ __launch_bounds__(256) void k_bias12a(
    const float* __restrict__ b1, const float* __restrict__ w2,
    float* __restrict__ partial)
{
    int eb = blockIdx.x & 7;       // e-chunk (128 e's)
    int fc = blockIdx.x >> 3;      // f-chunk 0..31 (128 f's)
    int t = threadIdx.x;
    int e = eb * 128 + (t & 127);
    int f0 = fc * 128 + (t >> 7) * 64;
    float s = 0.f;
    for (int f = f0; f < f0 + 64; f++)
        s += b1[f] * w2[(long)f * 1024 + e];
    __shared__ float sh[256];
    sh[t] = s;
    __syncthreads();
    if (t < 128) partial[(long)fc * 1024 + e] = sh[t] + sh[t + 128];
}

// ---------------- folded FFN bias, stage B: b12[e] = sum_fc partial[fc][e] + b2[e] ----
__global__ __launch_bounds__(128) void k_bias12b(
    const float* __restrict__ partial, const float* __restrict__ b2,
    float* __restrict__ b12)
{
    int e = blockIdx.x * 128 + threadIdx.x;
    float s = b2[e];
#pragma unroll 8
    for (int fc = 0; fc < 32; fc++) s += partial[(long)fc * 1024 + e];
    b12[e] = s;
}

// ---------------- embedding: xb = bf16(emb[id]*32 + pe) ----------------
__global__ __launch_bounds__(256) void k_embed(
    const int* __restrict__ ids, const float* __restrict__ emb,
    const float* __restrict__ pe, u16* __restrict__ xb)
{
    int row = blockIdx.x;          // b*512 + l
    int l = row & 511;
    long id = (long)ids[row];
    const float* e = emb + id * 1024;
    const float* p = pe + (long)l * 1024;
    u16* xbo = xb + (long)row * 1024;
    int d0 = threadIdx.x * 4;
    float4 ev = *(const float4*)&e[d0];
    float4 pv = *(const float4*)&p[d0];
    ushort4 o;
    o.x = f2bf(ev.x * 32.0f + pv.x);
    o.y = f2bf(ev.y * 32.0f + pv.y);
    o.z = f2bf(ev.z * 32.0f + pv.z);
    o.w = f2bf(ev.w * 32.0f + pv.w);
    *(ushort4*)&xbo[d0] = o;
}

// ---------------- bf16 MFMA GEMM, NT form (small shapes: QKV / WO / W12 build) -------
template <int TM, int TN, bool VT_EPI>
__global__ __launch_bounds__(256) void k_gemm_nt(
    const u16* __restrict__ A, long lda,
    const u16* __restrict__ B, long ldb,
    u16* __restrict__ Cm, long ldc,
    int M, int N, int K,
    const float* __restrict__ bias,
    u16* __restrict__ vTout)
{
    constexpr int FM = TM / 32;     // m-frags per wave
    constexpr int FN = TN / 32;     // n-frags per wave
    constexpr int CPA = TM / 64;    // A chunks per wave per K-plane
    constexpr int CPB = TN / 64;
    __shared__ u16 As[2 * TM * 32];
    __shared__ u16 Bs[2 * TN * 32];
    int m0 = blockIdx.y * TM, n0 = blockIdx.x * TN;
    int tid = threadIdx.x;
    int lane = tid & 63, wid = tid >> 6;
    int wr = wid >> 1, wc = wid & 1;
    int quad = lane >> 4, l16 = lane & 15;

    f32x4 acc[FM][FN];
#pragma unroll
    for (int i = 0; i < FM; i++)
#pragma unroll
        for (int j = 0; j < FN; j++) acc[i][j] = {0.f, 0.f, 0.f, 0.f};

    // staging: chunk = 16 rows x 32 k (1KB); lane l -> row c*16 + l/4, k-seg (l%4)*8
    int seg = (lane & 3) * 8;
    const u16* pA[CPA]; u16* lA[2][CPA];
    const u16* pB[CPB]; u16* lB[2][CPB];
#pragma unroll
    for (int i = 0; i < CPA; i++) {
        int c = wid * CPA + i;
        int gm = min(m0 + c * 16 + (lane >> 2), M - 1);
        pA[i] = A + (long)gm * lda + seg;
        lA[0][i] = &As[c * 512];
        lA[1][i] = &As[TM * 32 + c * 512];
    }
#pragma unroll
    for (int i = 0; i < CPB; i++) {
        int c = wid * CPB + i;
        int gn = min(n0 + c * 16 + (lane >> 2), N - 1);
        pB[i] = B + (long)gn * ldb + seg;
        lB[0][i] = &Bs[c * 512];
        lB[1][i] = &Bs[TN * 32 + c * 512];
    }

    for (int kb = 0; kb < K; kb += 64) {
#pragma unroll
        for (int kh = 0; kh < 2; kh++) {
#pragma unroll
            for (int i = 0; i < CPA; i++) ASYNC_CP16(pA[i] + kb + kh * 32, lA[kh][i]);
#pragma unroll
            for (int i = 0; i < CPB; i++) ASYNC_CP16(pB[i] + kb + kh * 32, lB[kh][i]);
        }
        __syncthreads();
        bf16x8 af[2][FM], bg[2][FN];
#pragma unroll
        for (int kh = 0; kh < 2; kh++)
#pragma unroll
            for (int t = 0; t < FM; t++)
                af[kh][t] = *(const bf16x8*)&As[kh * TM * 32 + (wr * (TM / 2) + t * 16 + l16) * 32 + quad * 8];
#pragma unroll
        for (int kh = 0; kh < 2; kh++)
#pragma unroll
            for (int t = 0; t < FN; t++)
                bg[kh][t] = *(const bf16x8*)&Bs[kh * TN * 32 + (wc * (TN / 2) + t * 16 + l16) * 32 + quad * 8];
#pragma unroll
        for (int kh = 0; kh < 2; kh++)
#pragma unroll
            for (int i = 0; i < FM; i++)
#pragma unroll
                for (int j = 0; j < FN; j++)
                    acc[i][j] = __builtin_amdgcn_mfma_f32_16x16x32_bf16(af[kh][i], bg[kh][j], acc[i][j], 0, 0, 0);
        __syncthreads();
    }

    // epilogue: C/D layout col=lane&15, row=quad*4+r (verified m89/m91)
#pragma unroll
    for (int i = 0; i < FM; i++) {
        int gm0 = m0 + wr * (TM / 2) + i * 16 + quad * 4;
#pragma unroll
        for (int j = 0; j < FN; j++) {
            int gn = n0 + wc * (TN / 2) + j * 16 + l16;
            if (gn >= N) continue;
            float bn = bias ? bias[gn] : 0.f;
            if (VT_EPI && gn >= 2048) {
                // V columns -> vT[d][l]: r maps to contiguous l -> ushort4 store
                ushort4 o;
                o.x = f2bf(acc[i][j][0] + bn);
                o.y = f2bf(acc[i][j][1] + bn);
                o.z = f2bf(acc[i][j][2] + bn);
                o.w = f2bf(acc[i][j][3] + bn);
                *(ushort4*)&vTout[(long)(gn - 2048) * 512 + gm0] = o;
                continue;
            }
#pragma unroll
            for (int r = 0; r < 4; r++) {
                int gm = gm0 + r;
                if (gm >= M) continue;
                Cm[(long)gm * ldc + gn] = f2bf(acc[i][j][r] + bn);
            }
        }
    }
}

// ---------------- full-prefetch counted-waitcnt MFMA GEMM, 256x256 (FFN) ------------
// 512 thr = 8 waves (2m x 4n); per-wave C = 128x64. K in 32-wide subtiles, 4 LDS slots.
// Per iter j: issue ALL 12 ds_reads for subtile j+1 (slot resident via prev vmcnt(4)),
// stage subtile j+3; lgkmcnt(12) waits only for LAST iter's reads (long done); then the
// FULL 32-MFMA burst runs from regs while this iter's 12 reads service underneath.
// vmcnt(4) end-of-iter gates slot j+2 residency; ONE barrier/iter. XCD-swizzled
// blockIdx; 2-way-free LDS bank swizzle via inverse-swizzled global src + swizzled
// ds_read addr. SPLITK: blockIdx.z selects K-slice; f32 partials at z*M*ldc; bias z==0.
// Requires M%256==0, N%256==0, K%64==0, K>=128, (gridDim.x*gridDim.y)%8==0.
template <bool SPLITK>
__global__ __launch_bounds__(512, 2) void k_gemm8(
    const u16* __restrict__ A, long lda,
    const u16* __restrict__ B, long ldb,
    u16* __restrict__ Cm, long ldc,
    int K, const float* __restrict__ bias)
{
    constexpr int BM = 256, BN = 256;
    constexpr int MF = 8;
    constexpr int ASLOT = BM * 32;
    constexpr int BSLOT = BN * 32;
    __shared__ u16 As[4 * ASLOT];
    __shared__ u16 Bs[4 * BSLOT];

    // XCD-aware chunked swizzle (bijective since nwg % 8 == 0)
    int lin = blockIdx.y * gridDim.x + blockIdx.x;
    int cpx = (gridDim.x * gridDim.y) >> 3;
    int sw = (lin & 7) * cpx + (lin >> 3);
    int bx = sw % gridDim.x, by = sw / gridDim.x;

    const int m0 = by * BM, n0 = bx * BN;
    const long kbase = SPLITK ? (long)blockIdx.z * K : 0;
    const int tid = threadIdx.x;
    const int lane = tid & 63, wid = tid >> 6;
    const int wm = wid >> 2, wn = wid & 3;
    const int wrow = wm * 128, wcol = wn * 64;
    const int quad = lane >> 4, l16 = lane & 15;

    f32x4 acc[MF][4];
#pragma unroll
    for (int f = 0; f < MF; f++)
#pragma unroll
        for (int g = 0; g < 4; g++) acc[f][g] = {0.f, 0.f, 0.f, 0.f};

    // staging source: lane covers row = i*128 + wid*16 + (lane>>2),
    // k-granule pre-inverse-swizzled: (lane&3) ^ ((lane>>3)&3)
    const int srow = wid * 16 + (lane >> 2);
    const int skoff = (((lane & 3) ^ ((lane >> 3) & 3)) << 3);
    const u16* aSrc = A + (long)(m0 + srow) * lda + kbase + skoff;
    const u16* bSrc = B + (long)(n0 + srow) * ldb + kbase + skoff;

    // swizzled ds_read offsets (u16 units): r*32 + ((quad ^ ((r>>1)&3)) * 8)
    int aoff[MF], boff[4];
#pragma unroll
    for (int f = 0; f < MF; f++) {
        int r = wrow + f * 16 + l16;
        aoff[f] = r * 32 + ((quad ^ ((r >> 1) & 3)) << 3);
    }
#pragma unroll
    for (int g = 0; g < 4; g++) {
        int r = wcol + g * 16 + l16;
        boff[g] = r * 32 + ((quad ^ ((r >> 1) & 3)) << 3);
    }

    auto stageA = [&](int j) {
        u16* d = &As[(j & 3) * ASLOT + wid * 512];
#pragma unroll
        for (int i = 0; i < 2; i++)
            ASYNC_CP16(aSrc + (long)i * 128 * lda + j * 32, d + i * 4096);
    };
    auto stageB = [&](int j) {
        u16* d = &Bs[(j & 3) * BSLOT + wid * 512];
#pragma unroll
        for (int i = 0; i < 2; i++)
            ASYNC_CP16(bSrc + (long)i * 128 * ldb + j * 32, d + i * 4096);
    };

    // prologue: 3 subtiles in flight; slots 0 AND 1 resident (iter 0 reads slot 1)
    stageA(0); stageB(0); stageA(1); stageB(1); stageA(2); stageB(2);
    asm volatile("s_waitcnt vmcnt(4)" ::: "memory");
    __builtin_amdgcn_s_barrier();

    bf16x8 ra[2][MF], rb[2][4];
#pragma unroll
    for (int f = 0; f < MF; f++) ra[0][f] = *(const bf16x8*)&As[aoff[f]];
#pragma unroll
    for (int g = 0; g < 4; g++)  rb[0][g] = *(const bf16x8*)&Bs[boff[g]];

    const int NK = K >> 5;   // NK even, >= 4
    for (int j0 = 0; j0 < NK - 2; j0 += 2) {
#pragma unroll
        for (int u = 0; u < 2; u++) {
            const int j = j0 + u;
            const u16* Abn = &As[((j + 1) & 3) * ASLOT];
            const u16* Bbn = &Bs[((j + 1) & 3) * BSLOT];
            // prefetch ALL of subtile j+1 into the alternate reg set (12 reads)
#pragma unroll
            for (int f = 0; f < MF; f++) ra[u ^ 1][f] = *(const bf16x8*)&Abn[aoff[f]];
#pragma unroll
            for (int g = 0; g < 4; g++)  rb[u ^ 1][g] = *(const bf16x8*)&Bbn[boff[g]];
            if (j + 3 < NK) { stageA(j + 3); stageB(j + 3); }
            __builtin_amdgcn_sched_barrier(0);
            // wait only for LAST iter's 12 reads (set u) -- long since serviced
            asm volatile("s_waitcnt lgkmcnt(12)" ::: "memory");
            __builtin_amdgcn_sched_barrier(0);
            __builtin_amdgcn_s_setprio(1);
#pragma unroll
            for (int f = 0; f < MF; f++)
#pragma unroll
                for (int g = 0; g < 4; g++)
                    acc[f][g] = __builtin_amdgcn_mfma_f32_16x16x32_bf16(ra[u][f], rb[u][g], acc[f][g], 0, 0, 0);
            __builtin_amdgcn_s_setprio(0);
            // residency gate for slot j+2 (read at iter j+1); drain once stages end
            if (j < NK - 3) asm volatile("s_waitcnt vmcnt(4)" ::: "memory");
            else            asm volatile("s_waitcnt vmcnt(0)" ::: "memory");
            __builtin_amdgcn_s_barrier();
        }
    }
    // peel j = NK-2 (set 0): prefetch subtile NK-1, no stage/gate
    {
        const u16* Abn = &As[((NK - 1) & 3) * ASLOT];
        const u16* Bbn = &Bs[((NK - 1) & 3) * BSLOT];
#pragma unroll
        for (int f = 0; f < MF; f++) ra[1][f] = *(const bf16x8*)&Abn[aoff[f]];
#pragma unroll
        for (int g = 0; g < 4; g++)  rb[1][g] = *(const bf16x8*)&Bbn[boff[g]];
        __builtin_amdgcn_sched_barrier(0);
        asm volatile("s_waitcnt lgkmcnt(12)" ::: "memory");
        __builtin_amdgcn_sched_barrier(0);
        __builtin_amdgcn_s_setprio(1);
#pragma unroll
        for (int f = 0; f < MF; f++)
#pragma unroll
            for (int g = 0; g < 4; g++)
                acc[f][g] = __builtin_amdgcn_mfma_f32_16x16x32_bf16(ra[0][f], rb[0][g], acc[f][g], 0, 0, 0);
        __builtin_amdgcn_s_setprio(0);
    }
    // peel j = NK-1 (set 1)
    {
        asm volatile("s_waitcnt lgkmcnt(0)" ::: "memory");
        __builtin_amdgcn_sched_barrier(0);
        __builtin_amdgcn_s_setprio(1);
#pragma unroll
        for (int f = 0; f < MF; f++)
#pragma unroll
            for (int g = 0; g < 4; g++)
                acc[f][g] = __builtin_amdgcn_mfma_f32_16x16x32_bf16(ra[1][f], rb[1][g], acc[f][g], 0, 0, 0);
        __builtin_amdgcn_s_setprio(0);
    }

    // epilogue: C/D layout col=lane&15, row=quad*4+r
    if (SPLITK) {
        float* Co = (float*)Cm + (long)blockIdx.z * (long)gridDim.y * BM * ldc;
        const bool zb = (blockIdx.z == 0);
#pragma unroll
        for (int f = 0; f < MF; f++) {
            int gm0 = m0 + wrow + f * 16 + quad * 4;
#pragma unroll
            for (int g = 0; g < 4; g++) {
                int gn = n0 + wcol + g * 16 + l16;
                float bn = zb ? bias[gn] : 0.f;
#pragma unroll
                for (int r = 0; r < 4; r++)
                    Co[(long)(gm0 + r) * ldc + gn] = acc[f][g][r] + bn;
            }
        }
    } else {
#pragma unroll
        for (int f = 0; f < MF; f++) {
            int gm0 = m0 + wrow + f * 16 + quad * 4;
#pragma unroll
            for (int g = 0; g < 4; g++) {
                int gn = n0 + wcol + g * 16 + l16;
                float bn = bias[gn];
#pragma unroll
                for (int r = 0; r < 4; r++)
                    Cm[(long)(gm0 + r) * ldc + gn] = f2bf(acc[f][g][r] + bn);
            }
        }
    }
}

// ---------------- fused attention: scores+softmax+PV for one (head, 32-q-row) block ---
__global__ __launch_bounds__(128) void k_attn(
    const u16* __restrict__ qkv, const u16* __restrict__ vT, u16* __restrict__ Ob)
{
    __shared__ u16 Ks[2][4096];   // plane layout: idx(key,d) = (d>>5)*2048 + key*32 + (d&31)
    __shared__ u16 Vs[2][4096];   // idx(d,key)   = (key>>5)*2048 + d*32 + (key&31)
    __shared__ u16 Pl[32 * 72];   // [q_local][72]; 144B rows -> 16B-aligned
    int qb = blockIdx.x, h = blockIdx.y;
    int tid = threadIdx.x;
    int w = tid >> 6, lane = tid & 63;
    int quad = lane >> 4, l16 = lane & 15;

    int qrow = qb * 32 + w * 16 + l16;
    bf16x8 aq[2];
#pragma unroll
    for (int c = 0; c < 2; c++)
        aq[c] = *(const bf16x8*)&qkv[(long)qrow * 3072 + h * 64 + c * 32 + quad * 8];

    f32x4 acc_o[4];
#pragma unroll
    for (int j = 0; j < 4; j++) acc_o[j] = {0.f, 0.f, 0.f, 0.f};
    float mrow[4], lrow[4];
#pragma unroll
    for (int r = 0; r < 4; r++) { mrow[r] = -1e30f; lrow[r] = 0.f; }

    {
        int kt = 0;
#pragma unroll
        for (int rr = 0; rr < 4; rr++) {
            int c = rr * 2 + w;
            int loc = (c & 3) * 16 + (lane >> 2);
            int off8 = ((c >> 2) << 5) + (lane & 3) * 8;
            ASYNC_CP16(&qkv[(long)(kt * 64 + loc) * 3072 + 1024 + h * 64 + off8], &Ks[0][c * 512]);
            ASYNC_CP16(&vT[(long)(h * 64 + loc) * 512 + kt * 64 + off8], &Vs[0][c * 512]);
        }
    }
    __syncthreads();

    for (int kt = 0; kt < 8; kt++) {
        int buf = kt & 1;
        if (kt < 7) {
            int nb = buf ^ 1, ktn = kt + 1;
#pragma unroll
            for (int rr = 0; rr < 4; rr++) {
                int c = rr * 2 + w;
                int loc = (c & 3) * 16 + (lane >> 2);
                int off8 = ((c >> 2) << 5) + (lane & 3) * 8;
                ASYNC_CP16(&qkv[(long)(ktn * 64 + loc) * 3072 + 1024 + h * 64 + off8], &Ks[nb][c * 512]);
                ASYNC_CP16(&vT[(long)(h * 64 + loc) * 512 + ktn * 64 + off8], &Vs[nb][c * 512]);
            }
        }
        f32x4 s[4];
#pragma unroll
        for (int ss = 0; ss < 4; ss++) {
            s[ss] = {0.f, 0.f, 0.f, 0.f};
#pragma unroll
            for (int c = 0; c < 2; c++) {
                bf16x8 bk = *(const bf16x8*)&Ks[buf][c * 2048 + (ss * 16 + l16) * 32 + quad * 8];
                s[ss] = __builtin_amdgcn_mfma_f32_16x16x32_bf16(aq[c], bk, s[ss], 0, 0, 0);
            }
        }
        float mt[4];
#pragma unroll
        for (int r = 0; r < 4; r++) {
#pragma unroll
            for (int ss = 0; ss < 4; ss++) s[ss][r] *= 0.125f;
            mt[r] = fmaxf(fmaxf(s[0][r], s[1][r]), fmaxf(s[2][r], s[3][r]));
        }
#pragma unroll
        for (int mask = 1; mask < 16; mask <<= 1)
#pragma unroll
            for (int r = 0; r < 4; r++) mt[r] = fmaxf(mt[r], __shfl_xor(mt[r], mask));
        float al[4], rsum[4];
#pragma unroll
        for (int r = 0; r < 4; r++) {
            float mn = fmaxf(mrow[r], mt[r]);
            al[r] = exp2f((mrow[r] - mn) * L2E);
            mrow[r] = mn;
            rsum[r] = 0.f;
#pragma unroll
            for (int ss = 0; ss < 4; ss++) {
                float p = exp2f((s[ss][r] - mn) * L2E);
                s[ss][r] = p;
                rsum[r] += p;
            }
        }
#pragma unroll
        for (int mask = 1; mask < 16; mask <<= 1)
#pragma unroll
            for (int r = 0; r < 4; r++) rsum[r] += __shfl_xor(rsum[r], mask);
#pragma unroll
        for (int r = 0; r < 4; r++) lrow[r] = lrow[r] * al[r] + rsum[r];
#pragma unroll
        for (int j = 0; j < 4; j++)
#pragma unroll
            for (int r = 0; r < 4; r++) acc_o[j][r] *= al[r];
#pragma unroll
        for (int ss = 0; ss < 4; ss++)
#pragma unroll
            for (int r = 0; r < 4; r++)
                Pl[(w * 16 + quad * 4 + r) * 72 + ss * 16 + l16] = f2bf(s[ss][r]);
#pragma unroll
        for (int kc = 0; kc < 2; kc++) {
            bf16x8 ap = *(const bf16x8*)&Pl[(w * 16 + l16) * 72 + kc * 32 + quad * 8];
#pragma unroll
            for (int j = 0; j < 4; j++) {
                bf16x8 bv = *(const bf16x8*)&Vs[buf][kc * 2048 + (j * 16 + l16) * 32 + quad * 8];
                acc_o[j] = __builtin_amdgcn_mfma_f32_16x16x32_bf16(ap, bv, acc_o[j], 0, 0, 0);
            }
        }
        __syncthreads();
    }

#pragma unroll
    for (int r = 0; r < 4; r++) {
        float inv = 1.0f / lrow[r];
        int gq = qb * 32 + w * 16 + quad * 4 + r;
#pragma unroll
        for (int j = 0; j < 4; j++)
            Ob[(long)gq * 1024 + h * 64 + j * 16 + l16] = f2bf(acc_o[j][r] * inv);
    }
}

// ---------------- xb = bf16(LN(xb + s) * g + beta), wave-per-row, no barrier -----------
__global__ __launch_bounds__(256) void k_add_ln(
    u16* __restrict__ xb, const u16* __restrict__ s, int sBroadcast,
    const float* __restrict__ g, const float* __restrict__ beta)
{
    int row = blockIdx.x * 4 + (threadIdx.x >> 6);   // b*512 + l
    int lane = threadIdx.x & 63;
    int srow = sBroadcast ? (row & 511) : row;
    u16* x = xb + (long)row * 1024;
    const u16* sp = s + (long)srow * 1024;
    int d0 = lane * 16;
    uint4 xa = *(const uint4*)&x[d0];
    uint4 xc = *(const uint4*)&x[d0 + 8];
    uint4 sa = *(const uint4*)&sp[d0];
    uint4 sc = *(const uint4*)&sp[d0 + 8];
    float v[16], t[8];
    unp8(xa, v); unp8(xc, v + 8);
    unp8(sa, t);
#pragma unroll
    for (int i = 0; i < 8; i++) v[i] += t[i];
    unp8(sc, t);
#pragma unroll
    for (int i = 0; i < 8; i++) v[8 + i] += t[i];
    float sum = 0.f, sq = 0.f;
#pragma unroll
    for (int i = 0; i < 16; i++) { sum += v[i]; sq += v[i] * v[i]; }
#pragma unroll
    for (int off = 32; off; off >>= 1) {
        sum += __shfl_xor(sum, off);
        sq += __shfl_xor(sq, off);
    }
    float mean = sum * (1.f / 1024.f);
    float var = sq * (1.f / 1024.f) - mean * mean;
    float rstd = rsqrtf(var + LN_EPS);
    float4 g0 = *(const float4*)&g[d0],      g1 = *(const float4*)&g[d0 + 4];
    float4 g2 = *(const float4*)&g[d0 + 8],  g3 = *(const float4*)&g[d0 + 12];
    float4 b0 = *(const float4*)&beta[d0],     b1 = *(const float4*)&beta[d0 + 4];
    float4 b2 = *(const float4*)&beta[d0 + 8], b3 = *(const float4*)&beta[d0 + 12];
    float gg[16] = {g0.x,g0.y,g0.z,g0.w, g1.x,g1.y,g1.z,g1.w, g2.x,g2.y,g2.z,g2.w, g3.x,g3.y,g3.z,g3.w};
    float bb[16] = {b0.x,b0.y,b0.z,b0.w, b1.x,b1.y,b1.z,b1.w, b2.x,b2.y,b2.z,b2.w, b3.x,b3.y,b3.z,b3.w};
    float y[16];
#pragma unroll
    for (int i = 0; i < 16; i++) y[i] = (v[i] - mean) * rstd * gg[i] + bb[i];
    uint4 oa, oc;
    oa.x = pk2(y[0], y[1]);  oa.y = pk2(y[2], y[3]);
    oa.z = pk2(y[4], y[5]);  oa.w = pk2(y[6], y[7]);
    oc.x = pk2(y[8], y[9]);  oc.y = pk2(y[10], y[11]);
    oc.z = pk2(y[12], y[13]); oc.w = pk2(y[14], y[15]);
    *(uint4*)&x[d0] = oa;
    *(uint4*)&x[d0 + 8] = oc;
}

// ---------------- xb = bf16(LN(xb + p0 + p1) * g + beta) -- f32 split-K partials ------
__global__ __launch_bounds__(256) void k_add_ln2(
    u16* __restrict__ xb, const float* __restrict__ p0, const float* __restrict__ p1,
    const float* __restrict__ g, const float* __restrict__ beta)
{
    int row = blockIdx.x * 4 + (threadIdx.x >> 6);   // b*512 + l
    int lane = threadIdx.x & 63;
    u16* x = xb + (long)row * 1024;
    const float* a0 = p0 + (long)row * 1024;
    const float* a1 = p1 + (long)row * 1024;
    int d0 = lane * 16;
    uint4 xa = *(const uint4*)&x[d0];
    uint4 xc = *(const uint4*)&x[d0 + 8];
    float v[16];
    unp8(xa, v); unp8(xc, v + 8);
#pragma unroll
    for (int i = 0; i < 16; i += 4) {
        float4 q0 = *(const float4*)&a0[d0 + i];
        float4 q1 = *(const float4*)&a1[d0 + i];
        v[i]     += q0.x + q1.x;
        v[i + 1] += q0.y + q1.y;
        v[i + 2] += q0.z + q1.z;
        v[i + 3] += q0.w + q1.w;
    }
    float sum = 0.f, sq = 0.f;
#pragma unroll
    for (int i = 0; i < 16; i++) { sum += v[i]; sq += v[i] * v[i]; }
#pragma unroll
    for (int off = 32; off; off >>= 1) {
        sum += __shfl_xor(sum, off);
        sq += __shfl_xor(sq, off);
    }
    float mean = sum * (1.f / 1024.f);
    float var = sq * (1.f / 1024.f) - mean * mean;
    float rstd = rsqrtf(var + LN_EPS);
    float4 g0 = *(const float4*)&g[d0],      g1 = *(const float4*)&g[d0 + 4];
    float4 g2 = *(const float4*)&g[d0 + 8],  g3 = *(const float4*)&g[d0 + 12];
    float4 b0 = *(const float4*)&beta[d0],     b1 = *(const float4*)&beta[d0 + 4];
    float4 b2 = *(const float4*)&beta[d0 + 8], b3 = *(const float4*)&beta[d0 + 12];
    float gg[16] = {g0.x,g0.y,g0.z,g0.w, g1.x,g1.y,g1.z,g1.w, g2.x,g2.y,g2.z,g2.w, g3.x,g3.y,g3.z,g3.w};
    float bb[16] = {b0.x,b0.y,b0.z,b0.w, b1.x,b1.y,b1.z,b1.w, b2.x,b2.y,b2.z,b2.w, b3.x,b3.y,b3.z,b3.w};
    float y[16];
#pragma unroll
    for (int i = 0; i < 16; i++) y[i] = (v[i] - mean) * rstd * gg[i] + bb[i];
    uint4 oa, oc;
    oa.x = pk2(y[0], y[1]);  oa.y = pk2(y[2], y[3]);
    oa.z = pk2(y[4], y[5]);  oa.w = pk2(y[6], y[7]);
    oc.x = pk2(y[8], y[9]);  oc.y = pk2(y[10], y[11]);
    oc.z = pk2(y[12], y[13]); oc.w = pk2(y[14], y[15]);
    *(uint4*)&x[d0] = oa;
    *(uint4*)&x[d0 + 8] = oc;
}

// ---------------- pool stage A: pp[b][ch][d] = sum_{l in 64-chunk} x[b][l][d] ---------
__global__ __launch_bounds__(256) void k_pool_a(
    const u16* __restrict__ xb, float* __restrict__ pp)
{
    int b = blockIdx.x >> 3, ch = blockIdx.x & 7;
    int d0 = threadIdx.x * 4;
    const u16* x = xb + ((long)b * 512 + ch * 64) * 1024;
    float s0 = 0.f, s1 = 0.f, s2 = 0.f, s3 = 0.f;
    for (int l = 0; l < 64; l++) {
        ushort4 v = *(const ushort4*)&x[(long)l * 1024 + d0];
        s0 += bf2f(v.x); s1 += bf2f(v.y); s2 += bf2f(v.z); s3 += bf2f(v.w);
    }
    float* o = pp + ((long)b * 8 + ch) * 1024 + d0;
    o[0] = s0; o[1] = s1; o[2] = s2; o[3] = s3;
}

// ---------------- pool stage B + head: out[b][c] = mean·wf[:,c] + bf[c] ---------------
__global__ __launch_bounds__(256) void k_pool_b(
    const float* __restrict__ pp, const float* __restrict__ wf,
    const float* __restrict__ bfin, float* __restrict__ out)
{
    int b = blockIdx.x;
    int tid = threadIdx.x;
    __shared__ float pl[1024];
    int d0 = tid * 4;
    float s0 = 0.f, s1 = 0.f, s2 = 0.f, s3 = 0.f;
#pragma unroll
    for (int ch = 0; ch < 8; ch++) {
        float4 q = *(const float4*)&pp[((long)b * 8 + ch) * 1024 + d0];
        s0 += q.x; s1 += q.y; s2 += q.z; s3 += q.w;
    }
    pl[d0] = s0 * (1.f / 512.f);
    pl[d0 + 1] = s1 * (1.f / 512.f);
    pl[d0 + 2] = s2 * (1.f / 512.f);
    pl[d0 + 3] = s3 * (1.f / 512.f);
    __syncthreads();
    __shared__ float red[4];
    for (int c = 0; c < 10; c++) {
        float t = 0.f;
        for (int d = tid; d < 1024; d += 256) t += pl[d] * wf[(long)d * 10 + c];
        for (int off = 32; off; off >>= 1) t += __shfl_down(t, off);
        if ((tid & 63) == 0) red[tid >> 6] = t;
        __syncthreads();
        if (tid == 0) out[b * 10 + c] = red[0] + red[1] + red[2] + red[3] + bfin[c];
        __syncthreads();
    }
}

// ---------------- host side ----------------
template <int TM, int TN, bool VT_EPI>
static void gemm(const u16* A, long lda, const u16* B, long ldb,
                 u16* C, long ldc,
                 int M, int N, int K, const float* bias,
                 hipStream_t st, u16* vTout = nullptr)
{
    dim3 g((N + TN - 1) / TN, (M + TM - 1) / TM);
    k_gemm_nt<TM, TN, VT_EPI><<<g, 256, 0, st>>>(A, lda, B, ldb, C, ldc, M, N, K, bias, vTout);
}

extern "C" void kernel_launch(void* const* d_in, const int* in_sizes, int n_in,
                              void* d_out, int out_size, void* d_ws, size_t ws_size,
                              hipStream_t stream)
{
    const int* ids   = (const int*)d_in[0];
    const float* emb = (const float*)d_in[1];
    const float* pe  = (const float*)d_in[2];
    const float* wq  = (const float*)d_in[3];
    const float* bq  = (const float*)d_in[4];
    const float* wk  = (const float*)d_in[5];
    const float* bk  = (const float*)d_in[6];
    const float* wv  = (const float*)d_in[7];
    const float* bv  = (const float*)d_in[8];
    const float* wo  = (const float*)d_in[9];
    const float* bo  = (const float*)d_in[10];
    const float* w1  = (const float*)d_in[11];
    const float* b1  = (const float*)d_in[12];
    const float* w2  = (const float*)d_in[13];
    const float* b2  = (const float*)d_in[14];
    const float* g1  = (const float*)d_in[15];
    const float* be1 = (const float*)d_in[16];
    const float* g2  = (const float*)d_in[17];
    const float* be2 = (const float*)d_in[18];
    const float* wf  = (const float*)d_in[19];
    const float* bfi = (const float*)d_in[20];
    float* out = (float*)d_out;

    char* base = (char*)d_ws;
    size_t off = 0;
    auto alloc = [&](size_t bytes) {
        char* p = base + off;
        off = (off + bytes + 255) & ~(size_t)255;
        return p;
    };
    u16*   xb    = (u16*)  alloc(16UL * 512 * 1024 * 2);   // bf16 residual stream [B,L,D]
    u16*   wqkvT = (u16*)  alloc(3072UL * 1024 * 2);       // [3072,1024] = wqT;wkT;wvT
    u16*   woT   = (u16*)  alloc(1024UL * 1024 * 2);
    u16*   w1b   = (u16*)  alloc(1024UL * 4096 * 2);       // bf16 cast of w1 [D,F]
    u16*   w2T   = (u16*)  alloc(1024UL * 4096 * 2);       // [D,F] = w2 transposed
    u16*   W12T  = (u16*)  alloc(1024UL * 1024 * 2);       // folded FFN weight, [e][d]
    float* b12f  = (float*)alloc(1024UL * 4);              // folded FFN bias
    float* b12p  = (float*)alloc(32UL * 1024 * 4);         // bias-fold partials
    float* qkvb  = (float*)alloc(3072UL * 4);              // concat(bq,bk,bv)
    u16*   qkv   = (u16*)  alloc(512UL * 3072 * 2);        // [L, 3*D]; v-part goes to vT
    u16*   vT    = (u16*)  alloc(1024UL * 512 * 2);        // v transposed [D,L]
    u16*   Ob    = (u16*)  alloc(512UL * 1024 * 2);        // attn context bf16 [L,D]
    u16*   src2  = (u16*)  alloc(512UL * 1024 * 2);        // bf16
    float* ppool = (float*)alloc(16UL * 8 * 1024 * 4);     // pool partials
    float* ffp   = (float*)alloc(2UL * 8192 * 1024 * 4);   // FFN split-K f32 partials

    k_prep<<<12300, 256, 0, stream>>>(wq, wk, wv, wo, w1, w2, bq, bk, bv, qkvb,
                                      wqkvT, woT, w1b, w2T);
    k_bias12a<<<256, 256, 0, stream>>>(b1, w2, b12p);
    k_bias12b<<<8, 128, 0, stream>>>(b12p, b2, b12f);
    k_embed<<<8192, 256, 0, stream>>>(ids, emb, pe, xb);
    // W12T[e][d] = sum_f w2T[e][f] * w1b[d][f]  (one-time folded FFN weight)
    gemm<64, 64, false>(w2T, 4096, w1b, 4096, W12T, 1024, 1024, 1024, 4096, nullptr, stream);

    for (int layer = 0; layer < 6; layer++) {
        // fused q|k|v for batch 0: [512,3072]; V cols written transposed into vT
        gemm<64, 64, true>(xb, 1024, wqkvT, 1024, qkv, 3072, 512, 3072, 1024, qkvb, stream, vT);
        // fused scores+softmax+PV
        k_attn<<<dim3(16, 16), 128, 0, stream>>>(qkv, vT, Ob);
        // src2 = O . wo + bo
        gemm<64, 64, false>(Ob, 1024, woT, 1024, src2, 1024, 512, 1024, 1024, bo, stream);
        k_add_ln<<<2048, 256, 0, stream>>>(xb, src2, 1, g1, be1);
        // folded FFN: ff = xb @ W12T^T + b12, split-K z=2 (K=512 each) -> f32 partials
        k_gemm8<true><<<dim3(4, 32, 2), 512, 0, stream>>>(xb, 1024, W12T, 1024,
                                                          (u16*)ffp, 1024, 512, b12f);
        k_add_ln2<<<2048, 256, 0, stream>>>(xb, ffp, ffp + 8192UL * 1024, g2, be2);
    }

    k_pool_a<<<128, 256, 0, stream>>>(xb, ppool);
    k_pool_b<<<16, 256, 0, stream>>>(ppool, wf, bfi, out);
}

// Round 7
// 897.178 us; speedup vs baseline: 1.7079x; 1.0146x over previous
//
#include <hip/hip_runtime.h>

typedef unsigned short u16;
typedef unsigned int u32;
typedef __bf16 bf16x8 __attribute__((ext_vector_type(8)));
typedef float f32x4 __attribute__((ext_vector_type(4)));

#define LN_EPS 1e-5f
#define L2E 1.44269504f

__device__ __forceinline__ u16 f2bf(float f) {
    u32 u = __float_as_uint(f);
    u += 0x7fffu + ((u >> 16) & 1u);
    return (u16)(u >> 16);
}
__device__ __forceinline__ float bf2f(u32 v) {
    return __uint_as_float(v << 16);
}
__device__ __forceinline__ void unp8(uint4 u, float* v) {
    v[0] = bf2f(u.x & 0xffff); v[1] = bf2f(u.x >> 16);
    v[2] = bf2f(u.y & 0xffff); v[3] = bf2f(u.y >> 16);
    v[4] = bf2f(u.z & 0xffff); v[5] = bf2f(u.z >> 16);
    v[6] = bf2f(u.w & 0xffff); v[7] = bf2f(u.w >> 16);
}
__device__ __forceinline__ u32 pk2(float a, float b) {
    return (u32)f2bf(a) | ((u32)f2bf(b) << 16);
}

// async global->LDS, 16B per lane; lds base must be wave-uniform (HW: base + lane*16)
#define ASYNC_CP16(g, l)                                                      \
    __builtin_amdgcn_global_load_lds(                                         \
        (const __attribute__((address_space(1))) u32*)(g),                    \
        (__attribute__((address_space(3))) u32*)(l), 16, 0, 0)

// ---------------- one-shot prep: weight transposes (f32->bf16), w1 cast, bias concat --
__global__ __launch_bounds__(256) void k_prep(
    const float* __restrict__ wq, const float* __restrict__ wk,
    const float* __restrict__ wv, const float* __restrict__ wo,
    const float* __restrict__ w1, const float* __restrict__ w2,
    const float* __restrict__ bq, const float* __restrict__ bk,
    const float* __restrict__ bv, float* __restrict__ qkvb,
    u16* __restrict__ wqkvT, u16* __restrict__ woT,
    u16* __restrict__ w1b, u16* __restrict__ w2T)
{
    int b = blockIdx.x;
    if (b >= 12288) {
        int i = (b - 12288) * 256 + threadIdx.x;
        qkvb[i] = (i < 1024) ? bq[i] : (i < 2048 ? bk[i - 1024] : bv[i - 2048]);
        return;
    }
    if (b >= 4096 && b < 8192) {
        // straight f32->bf16 cast of w1 [1024][4096] (K-major already; no transpose)
        int i = (b - 4096) * 1024 + threadIdx.x * 4;
        float4 v = *(const float4*)&w1[i];
        ushort4 o;
        o.x = f2bf(v.x); o.y = f2bf(v.y); o.z = f2bf(v.z); o.w = f2bf(v.w);
        *(ushort4*)&w1b[i] = o;
        return;
    }
    const float* in; u16* out; int C; long ldo; int gx; int l;
    if (b < 4096) {
        int j = b >> 10; l = b & 1023;
        in = (j == 0) ? wq : (j == 1) ? wk : (j == 2) ? wv : wo;
        out = (j == 3) ? woT : wqkvT + (long)j * 1024 * 1024;
        C = 1024; ldo = 1024; gx = 32;
    } else {
        l = b - 8192; in = w2; out = w2T; C = 1024; ldo = 4096; gx = 32;
    }
    int bx = l % gx, by = l / gx;
    __shared__ float tile[32][33];
    int c0 = bx * 32, r0 = by * 32;
    int tx = threadIdx.x & 31, ty = threadIdx.x >> 5;
#pragma unroll
    for (int i = 0; i < 4; i++)
        tile[ty + 8 * i][tx] = in[(long)(r0 + ty + 8 * i) * C + c0 + tx];
    __syncthreads();
#pragma unroll
    for (int i = 0; i < 4; i++)
        out[(long)(c0 + ty + 8 * i) * ldo + r0 + tx] = f2bf(tile[tx][ty + 8 * i]);
}

// ---------------- folded FFN bias, stage A: partial[fc][e] = sum_{f in chunk} b1[f]*w2[f][e]
__global__ __launch_bounds__(256) void k_bias12a(
    const float* __restrict__ b1, const float* __restrict__ w2,
    float* __restrict__ partial)
{
    int eb = blockIdx.x & 7;       // e-chunk (128 e's)
    int fc = blockIdx.x >> 3;      // f-chunk 0..31 (128 f's)
    int t = threadIdx.x;
    int e = eb * 128 + (t & 127);
    int f0 = fc * 128 + (t >> 7) * 64;
    float s = 0.f;
    for (int f = f0; f < f0 + 64; f++)
        s += b1[f] * w2[(long)f * 1024 + e];
    __shared__ float sh[256];
    sh[t] = s;
    __syncthreads();
    if (t < 128) partial[(long)fc * 1024 + e] = sh[t] + sh[t + 128];
}

// ---------------- folded FFN bias, stage B: b12[e] = sum_fc partial[fc][e] + b2[e] ----
__global__ __launch_bounds__(128) void k_bias12b(
    const float* __restrict__ partial, const float* __restrict__ b2,
    float* __restrict__ b12)
{
    int e = blockIdx.x * 128 + threadIdx.x;
    float s = b2[e];
#pragma unroll 8
    for (int fc = 0; fc < 32; fc++) s += partial[(long)fc * 1024 + e];
    b12[e] = s;
}

// ---------------- W12 split-K reduce: W12T[e][d] = bf16(sum_z p[z][e][d]) -------------
__global__ __launch_bounds__(256) void k_w12red(
    const float* __restrict__ p, u16* __restrict__ w12)
{
    int e = blockIdx.x;            // 0..1023
    int d0 = threadIdx.x * 4;
    float4 s = {0.f, 0.f, 0.f, 0.f};
#pragma unroll 4
    for (int z = 0; z < 16; z++) {
        float4 q = *(const float4*)&p[(long)z * 1024 * 1024 + (long)e * 1024 + d0];
        s.x += q.x; s.y += q.y; s.z += q.z; s.w += q.w;
    }
    ushort4 o;
    o.x = f2bf(s.x); o.y = f2bf(s.y); o.z = f2bf(s.z); o.w = f2bf(s.w);
    *(ushort4*)&w12[(long)e * 1024 + d0] = o;
}

// ---------------- embedding: xb = bf16(emb[id]*32 + pe) ----------------
__global__ __launch_bounds__(256) void k_embed(
    const int* __restrict__ ids, const float* __restrict__ emb,
    const float* __restrict__ pe, u16* __restrict__ xb)
{
    int row = blockIdx.x;          // b*512 + l
    int l = row & 511;
    long id = (long)ids[row];
    const float* e = emb + id * 1024;
    const float* p = pe + (long)l * 1024;
    u16* xbo = xb + (long)row * 1024;
    int d0 = threadIdx.x * 4;
    float4 ev = *(const float4*)&e[d0];
    float4 pv = *(const float4*)&p[d0];
    ushort4 o;
    o.x = f2bf(ev.x * 32.0f + pv.x);
    o.y = f2bf(ev.y * 32.0f + pv.y);
    o.z = f2bf(ev.z * 32.0f + pv.z);
    o.w = f2bf(ev.w * 32.0f + pv.w);
    *(ushort4*)&xbo[d0] = o;
}

// ---------------- bf16 MFMA GEMM, NT form (small shapes: QKV / WO) -------------------
template <int TM, int TN, bool VT_EPI>
__global__ __launch_bounds__(256) void k_gemm_nt(
    const u16* __restrict__ A, long lda,
    const u16* __restrict__ B, long ldb,
    u16* __restrict__ Cm, long ldc,
    int M, int N, int K,
    const float* __restrict__ bias,
    u16* __restrict__ vTout)
{
    constexpr int FM = TM / 32;     // m-frags per wave
    constexpr int FN = TN / 32;     // n-frags per wave
    constexpr int CPA = TM / 64;    // A chunks per wave per K-plane
    constexpr int CPB = TN / 64;
    __shared__ u16 As[2 * TM * 32];
    __shared__ u16 Bs[2 * TN * 32];
    int m0 = blockIdx.y * TM, n0 = blockIdx.x * TN;
    int tid = threadIdx.x;
    int lane = tid & 63, wid = tid >> 6;
    int wr = wid >> 1, wc = wid & 1;
    int quad = lane >> 4, l16 = lane & 15;

    f32x4 acc[FM][FN];
#pragma unroll
    for (int i = 0; i < FM; i++)
#pragma unroll
        for (int j = 0; j < FN; j++) acc[i][j] = {0.f, 0.f, 0.f, 0.f};

    // staging: chunk = 16 rows x 32 k (1KB); lane l -> row c*16 + l/4, k-seg (l%4)*8
    int seg = (lane & 3) * 8;
    const u16* pA[CPA]; u16* lA[2][CPA];
    const u16* pB[CPB]; u16* lB[2][CPB];
#pragma unroll
    for (int i = 0; i < CPA; i++) {
        int c = wid * CPA + i;
        int gm = min(m0 + c * 16 + (lane >> 2), M - 1);
        pA[i] = A + (long)gm * lda + seg;
        lA[0][i] = &As[c * 512];
        lA[1][i] = &As[TM * 32 + c * 512];
    }
#pragma unroll
    for (int i = 0; i < CPB; i++) {
        int c = wid * CPB + i;
        int gn = min(n0 + c * 16 + (lane >> 2), N - 1);
        pB[i] = B + (long)gn * ldb + seg;
        lB[0][i] = &Bs[c * 512];
        lB[1][i] = &Bs[TN * 32 + c * 512];
    }

    for (int kb = 0; kb < K; kb += 64) {
#pragma unroll
        for (int kh = 0; kh < 2; kh++) {
#pragma unroll
            for (int i = 0; i < CPA; i++) ASYNC_CP16(pA[i] + kb + kh * 32, lA[kh][i]);
#pragma unroll
            for (int i = 0; i < CPB; i++) ASYNC_CP16(pB[i] + kb + kh * 32, lB[kh][i]);
        }
        __syncthreads();
        bf16x8 af[2][FM], bg[2][FN];
#pragma unroll
        for (int kh = 0; kh < 2; kh++)
#pragma unroll
            for (int t = 0; t < FM; t++)
                af[kh][t] = *(const bf16x8*)&As[kh * TM * 32 + (wr * (TM / 2) + t * 16 + l16) * 32 + quad * 8];
#pragma unroll
        for (int kh = 0; kh < 2; kh++)
#pragma unroll
            for (int t = 0; t < FN; t++)
                bg[kh][t] = *(const bf16x8*)&Bs[kh * TN * 32 + (wc * (TN / 2) + t * 16 + l16) * 32 + quad * 8];
#pragma unroll
        for (int kh = 0; kh < 2; kh++)
#pragma unroll
            for (int i = 0; i < FM; i++)
#pragma unroll
                for (int j = 0; j < FN; j++)
                    acc[i][j] = __builtin_amdgcn_mfma_f32_16x16x32_bf16(af[kh][i], bg[kh][j], acc[i][j], 0, 0, 0);
        __syncthreads();
    }

    // epilogue: C/D layout col=lane&15, row=quad*4+r (verified m89/m91)
#pragma unroll
    for (int i = 0; i < FM; i++) {
        int gm0 = m0 + wr * (TM / 2) + i * 16 + quad * 4;
#pragma unroll
        for (int j = 0; j < FN; j++) {
            int gn = n0 + wc * (TN / 2) + j * 16 + l16;
            if (gn >= N) continue;
            float bn = bias ? bias[gn] : 0.f;
            if (VT_EPI && gn >= 2048) {
                // V columns -> vT[d][l]: r maps to contiguous l -> ushort4 store
                ushort4 o;
                o.x = f2bf(acc[i][j][0] + bn);
                o.y = f2bf(acc[i][j][1] + bn);
                o.z = f2bf(acc[i][j][2] + bn);
                o.w = f2bf(acc[i][j][3] + bn);
                *(ushort4*)&vTout[(long)(gn - 2048) * 512 + gm0] = o;
                continue;
            }
#pragma unroll
            for (int r = 0; r < 4; r++) {
                int gm = gm0 + r;
                if (gm >= M) continue;
                Cm[(long)gm * ldc + gn] = f2bf(acc[i][j][r] + bn);
            }
        }
    }
}

// ---------------- full-prefetch counted-waitcnt MFMA GEMM, 256x256 (FFN / W12) -------
// 512 thr = 8 waves (2m x 4n); per-wave C = 128x64. K in 32-wide subtiles, 4 LDS slots.
// Per iter j: issue ALL 12 ds_reads for subtile j+1 (slot resident via prev vmcnt(4)),
// stage subtile j+3; lgkmcnt(12) waits only for LAST iter's reads (long done); then the
// FULL 32-MFMA burst runs from regs while this iter's 12 reads service underneath.
// vmcnt(4) end-of-iter gates slot j+2 residency; ONE barrier/iter. XCD-swizzled
// blockIdx; 2-way-free LDS bank swizzle via inverse-swizzled global src + swizzled
// ds_read addr. SPLITK: blockIdx.z selects K-slice; f32 partials at z*M*ldc; bias z==0.
// Requires M%256==0, N%256==0, K%64==0, K>=128, (gridDim.x*gridDim.y)%8==0.
template <bool SPLITK>
__global__ __launch_bounds__(512, 2) void k_gemm8(
    const u16* __restrict__ A, long lda,
    const u16* __restrict__ B, long ldb,
    u16* __restrict__ Cm, long ldc,
    int K, const float* __restrict__ bias)
{
    constexpr int BM = 256, BN = 256;
    constexpr int MF = 8;
    constexpr int ASLOT = BM * 32;
    constexpr int BSLOT = BN * 32;
    __shared__ u16 As[4 * ASLOT];
    __shared__ u16 Bs[4 * BSLOT];

    // XCD-aware chunked swizzle (bijective since nwg % 8 == 0)
    int lin = blockIdx.y * gridDim.x + blockIdx.x;
    int cpx = (gridDim.x * gridDim.y) >> 3;
    int sw = (lin & 7) * cpx + (lin >> 3);
    int bx = sw % gridDim.x, by = sw / gridDim.x;

    const int m0 = by * BM, n0 = bx * BN;
    const long kbase = SPLITK ? (long)blockIdx.z * K : 0;
    const int tid = threadIdx.x;
    const int lane = tid & 63, wid = tid >> 6;
    const int wm = wid >> 2, wn = wid & 3;
    const int wrow = wm * 128, wcol = wn * 64;
    const int quad = lane >> 4, l16 = lane & 15;

    f32x4 acc[MF][4];
#pragma unroll
    for (int f = 0; f < MF; f++)
#pragma unroll
        for (int g = 0; g < 4; g++) acc[f][g] = {0.f, 0.f, 0.f, 0.f};

    // staging source: lane covers row = i*128 + wid*16 + (lane>>2),
    // k-granule pre-inverse-swizzled: (lane&3) ^ ((lane>>3)&3)
    const int srow = wid * 16 + (lane >> 2);
    const int skoff = (((lane & 3) ^ ((lane >> 3) & 3)) << 3);
    const u16* aSrc = A + (long)(m0 + srow) * lda + kbase + skoff;
    const u16* bSrc = B + (long)(n0 + srow) * ldb + kbase + skoff;

    // swizzled ds_read offsets (u16 units): r*32 + ((quad ^ ((r>>1)&3)) * 8)
    int aoff[MF], boff[4];
#pragma unroll
    for (int f = 0; f < MF; f++) {
        int r = wrow + f * 16 + l16;
        aoff[f] = r * 32 + ((quad ^ ((r >> 1) & 3)) << 3);
    }
#pragma unroll
    for (int g = 0; g < 4; g++) {
        int r = wcol + g * 16 + l16;
        boff[g] = r * 32 + ((quad ^ ((r >> 1) & 3)) << 3);
    }

    auto stageA = [&](int j) {
        u16* d = &As[(j & 3) * ASLOT + wid * 512];
#pragma unroll
        for (int i = 0; i < 2; i++)
            ASYNC_CP16(aSrc + (long)i * 128 * lda + j * 32, d + i * 4096);
    };
    auto stageB = [&](int j) {
        u16* d = &Bs[(j & 3) * BSLOT + wid * 512];
#pragma unroll
        for (int i = 0; i < 2; i++)
            ASYNC_CP16(bSrc + (long)i * 128 * ldb + j * 32, d + i * 4096);
    };

    // prologue: 3 subtiles in flight; slots 0 AND 1 resident (iter 0 reads slot 1)
    stageA(0); stageB(0); stageA(1); stageB(1); stageA(2); stageB(2);
    asm volatile("s_waitcnt vmcnt(4)" ::: "memory");
    __builtin_amdgcn_s_barrier();

    bf16x8 ra[2][MF], rb[2][4];
#pragma unroll
    for (int f = 0; f < MF; f++) ra[0][f] = *(const bf16x8*)&As[aoff[f]];
#pragma unroll
    for (int g = 0; g < 4; g++)  rb[0][g] = *(const bf16x8*)&Bs[boff[g]];

    const int NK = K >> 5;   // NK even, >= 4
    for (int j0 = 0; j0 < NK - 2; j0 += 2) {
#pragma unroll
        for (int u = 0; u < 2; u++) {
            const int j = j0 + u;
            const u16* Abn = &As[((j + 1) & 3) * ASLOT];
            const u16* Bbn = &Bs[((j + 1) & 3) * BSLOT];
            // prefetch ALL of subtile j+1 into the alternate reg set (12 reads)
#pragma unroll
            for (int f = 0; f < MF; f++) ra[u ^ 1][f] = *(const bf16x8*)&Abn[aoff[f]];
#pragma unroll
            for (int g = 0; g < 4; g++)  rb[u ^ 1][g] = *(const bf16x8*)&Bbn[boff[g]];
            if (j + 3 < NK) { stageA(j + 3); stageB(j + 3); }
            __builtin_amdgcn_sched_barrier(0);
            // wait only for LAST iter's 12 reads (set u) -- long since serviced
            asm volatile("s_waitcnt lgkmcnt(12)" ::: "memory");
            __builtin_amdgcn_sched_barrier(0);
            __builtin_amdgcn_s_setprio(1);
#pragma unroll
            for (int f = 0; f < MF; f++)
#pragma unroll
                for (int g = 0; g < 4; g++)
                    acc[f][g] = __builtin_amdgcn_mfma_f32_16x16x32_bf16(ra[u][f], rb[u][g], acc[f][g], 0, 0, 0);
            __builtin_amdgcn_s_setprio(0);
            // residency gate for slot j+2 (read at iter j+1); drain once stages end
            if (j < NK - 3) asm volatile("s_waitcnt vmcnt(4)" ::: "memory");
            else            asm volatile("s_waitcnt vmcnt(0)" ::: "memory");
            __builtin_amdgcn_s_barrier();
        }
    }
    // peel j = NK-2 (set 0): prefetch subtile NK-1, no stage/gate
    {
        const u16* Abn = &As[((NK - 1) & 3) * ASLOT];
        const u16* Bbn = &Bs[((NK - 1) & 3) * BSLOT];
#pragma unroll
        for (int f = 0; f < MF; f++) ra[1][f] = *(const bf16x8*)&Abn[aoff[f]];
#pragma unroll
        for (int g = 0; g < 4; g++)  rb[1][g] = *(const bf16x8*)&Bbn[boff[g]];
        __builtin_amdgcn_sched_barrier(0);
        asm volatile("s_waitcnt lgkmcnt(12)" ::: "memory");
        __builtin_amdgcn_sched_barrier(0);
        __builtin_amdgcn_s_setprio(1);
#pragma unroll
        for (int f = 0; f < MF; f++)
#pragma unroll
            for (int g = 0; g < 4; g++)
                acc[f][g] = __builtin_amdgcn_mfma_f32_16x16x32_bf16(ra[0][f], rb[0][g], acc[f][g], 0, 0, 0);
        __builtin_amdgcn_s_setprio(0);
    }
    // peel j = NK-1 (set 1)
    {
        asm volatile("s_waitcnt lgkmcnt(0)" ::: "memory");
        __builtin_amdgcn_sched_barrier(0);
        __builtin_amdgcn_s_setprio(1);
#pragma unroll
        for (int f = 0; f < MF; f++)
#pragma unroll
            for (int g = 0; g < 4; g++)
                acc[f][g] = __builtin_amdgcn_mfma_f32_16x16x32_bf16(ra[1][f], rb[1][g], acc[f][g], 0, 0, 0);
        __builtin_amdgcn_s_setprio(0);
    }

    // epilogue: C/D layout col=lane&15, row=quad*4+r
    if (SPLITK) {
        float* Co = (float*)Cm + (long)blockIdx.z * (long)gridDim.y * BM * ldc;
        const bool zb = (blockIdx.z == 0);
#pragma unroll
        for (int f = 0; f < MF; f++) {
            int gm0 = m0 + wrow + f * 16 + quad * 4;
#pragma unroll
            for (int g = 0; g < 4; g++) {
                int gn = n0 + wcol + g * 16 + l16;
                float bn = (zb && bias) ? bias[gn] : 0.f;
#pragma unroll
                for (int r = 0; r < 4; r++)
                    Co[(long)(gm0 + r) * ldc + gn] = acc[f][g][r] + bn;
            }
        }
    } else {
#pragma unroll
        for (int f = 0; f < MF; f++) {
            int gm0 = m0 + wrow + f * 16 + quad * 4;
#pragma unroll
            for (int g = 0; g < 4; g++) {
                int gn = n0 + wcol + g * 16 + l16;
                float bn = bias[gn];
#pragma unroll
                for (int r = 0; r < 4; r++)
                    Cm[(long)(gm0 + r) * ldc + gn] = f2bf(acc[f][g][r] + bn);
            }
        }
    }
}

// ---------------- fused attention: scores+softmax+PV for one (head, 32-q-row) block ---
__global__ __launch_bounds__(128) void k_attn(
    const u16* __restrict__ qkv, const u16* __restrict__ vT, u16* __restrict__ Ob)
{
    __shared__ u16 Ks[2][4096];   // plane layout: idx(key,d) = (d>>5)*2048 + key*32 + (d&31)
    __shared__ u16 Vs[2][4096];   // idx(d,key)   = (key>>5)*2048 + d*32 + (key&31)
    __shared__ u16 Pl[32 * 72];   // [q_local][72]; 144B rows -> 16B-aligned
    int qb = blockIdx.x, h = blockIdx.y;
    int tid = threadIdx.x;
    int w = tid >> 6, lane = tid & 63;
    int quad = lane >> 4, l16 = lane & 15;

    int qrow = qb * 32 + w * 16 + l16;
    bf16x8 aq[2];
#pragma unroll
    for (int c = 0; c < 2; c++)
        aq[c] = *(const bf16x8*)&qkv[(long)qrow * 3072 + h * 64 + c * 32 + quad * 8];

    f32x4 acc_o[4];
#pragma unroll
    for (int j = 0; j < 4; j++) acc_o[j] = {0.f, 0.f, 0.f, 0.f};
    float mrow[4], lrow[4];
#pragma unroll
    for (int r = 0; r < 4; r++) { mrow[r] = -1e30f; lrow[r] = 0.f; }

    {
        int kt = 0;
#pragma unroll
        for (int rr = 0; rr < 4; rr++) {
            int c = rr * 2 + w;
            int loc = (c & 3) * 16 + (lane >> 2);
            int off8 = ((c >> 2) << 5) + (lane & 3) * 8;
            ASYNC_CP16(&qkv[(long)(kt * 64 + loc) * 3072 + 1024 + h * 64 + off8], &Ks[0][c * 512]);
            ASYNC_CP16(&vT[(long)(h * 64 + loc) * 512 + kt * 64 + off8], &Vs[0][c * 512]);
        }
    }
    __syncthreads();

    for (int kt = 0; kt < 8; kt++) {
        int buf = kt & 1;
        if (kt < 7) {
            int nb = buf ^ 1, ktn = kt + 1;
#pragma unroll
            for (int rr = 0; rr < 4; rr++) {
                int c = rr * 2 + w;
                int loc = (c & 3) * 16 + (lane >> 2);
                int off8 = ((c >> 2) << 5) + (lane & 3) * 8;
                ASYNC_CP16(&qkv[(long)(ktn * 64 + loc) * 3072 + 1024 + h * 64 + off8], &Ks[nb][c * 512]);
                ASYNC_CP16(&vT[(long)(h * 64 + loc) * 512 + ktn * 64 + off8], &Vs[nb][c * 512]);
            }
        }
        f32x4 s[4];
#pragma unroll
        for (int ss = 0; ss < 4; ss++) {
            s[ss] = {0.f, 0.f, 0.f, 0.f};
#pragma unroll
            for (int c = 0; c < 2; c++) {
                bf16x8 bk = *(const bf16x8*)&Ks[buf][c * 2048 + (ss * 16 + l16) * 32 + quad * 8];
                s[ss] = __builtin_amdgcn_mfma_f32_16x16x32_bf16(aq[c], bk, s[ss], 0, 0, 0);
            }
        }
        float mt[4];
#pragma unroll
        for (int r = 0; r < 4; r++) {
#pragma unroll
            for (int ss = 0; ss < 4; ss++) s[ss][r] *= 0.125f;
            mt[r] = fmaxf(fmaxf(s[0][r], s[1][r]), fmaxf(s[2][r], s[3][r]));
        }
#pragma unroll
        for (int mask = 1; mask < 16; mask <<= 1)
#pragma unroll
            for (int r = 0; r < 4; r++) mt[r] = fmaxf(mt[r], __shfl_xor(mt[r], mask));
        float al[4], rsum[4];
#pragma unroll
        for (int r = 0; r < 4; r++) {
            float mn = fmaxf(mrow[r], mt[r]);
            al[r] = exp2f((mrow[r] - mn) * L2E);
            mrow[r] = mn;
            rsum[r] = 0.f;
#pragma unroll
            for (int ss = 0; ss < 4; ss++) {
                float p = exp2f((s[ss][r] - mn) * L2E);
                s[ss][r] = p;
                rsum[r] += p;
            }
        }
#pragma unroll
        for (int mask = 1; mask < 16; mask <<= 1)
#pragma unroll
            for (int r = 0; r < 4; r++) rsum[r] += __shfl_xor(rsum[r], mask);
#pragma unroll
        for (int r = 0; r < 4; r++) lrow[r] = lrow[r] * al[r] + rsum[r];
#pragma unroll
        for (int j = 0; j < 4; j++)
#pragma unroll
            for (int r = 0; r < 4; r++) acc_o[j][r] *= al[r];
#pragma unroll
        for (int ss = 0; ss < 4; ss++)
#pragma unroll
            for (int r = 0; r < 4; r++)
                Pl[(w * 16 + quad * 4 + r) * 72 + ss * 16 + l16] = f2bf(s[ss][r]);
#pragma unroll
        for (int kc = 0; kc < 2; kc++) {
            bf16x8 ap = *(const bf16x8*)&Pl[(w * 16 + l16) * 72 + kc * 32 + quad * 8];
#pragma unroll
            for (int j = 0; j < 4; j++) {
                bf16x8 bv = *(const bf16x8*)&Vs[buf][kc * 2048 + (j * 16 + l16) * 32 + quad * 8];
                acc_o[j] = __builtin_amdgcn_mfma_f32_16x16x32_bf16(ap, bv, acc_o[j], 0, 0, 0);
            }
        }
        __syncthreads();
    }

#pragma unroll
    for (int r = 0; r < 4; r++) {
        float inv = 1.0f / lrow[r];
        int gq = qb * 32 + w * 16 + quad * 4 + r;
#pragma unroll
        for (int j = 0; j < 4; j++)
            Ob[(long)gq * 1024 + h * 64 + j * 16 + l16] = f2bf(acc_o[j][r] * inv);
    }
}

// ---------------- xb = bf16(LN(xb + s) * g + beta), wave-per-row, no barrier -----------
__global__ __launch_bounds__(256) void k_add_ln(
    u16* __restrict__ xb, const u16* __restrict__ s, int sBroadcast,
    const float* __restrict__ g, const float* __restrict__ beta)
{
    int row = blockIdx.x * 4 + (threadIdx.x >> 6);   // b*512 + l
    int lane = threadIdx.x & 63;
    int srow = sBroadcast ? (row & 511) : row;
    u16* x = xb + (long)row * 1024;
    const u16* sp = s + (long)srow * 1024;
    int d0 = lane * 16;
    uint4 xa = *(const uint4*)&x[d0];
    uint4 xc = *(const uint4*)&x[d0 + 8];
    uint4 sa = *(const uint4*)&sp[d0];
    uint4 sc = *(const uint4*)&sp[d0 + 8];
    float v[16], t[8];
    unp8(xa, v); unp8(xc, v + 8);
    unp8(sa, t);
#pragma unroll
    for (int i = 0; i < 8; i++) v[i] += t[i];
    unp8(sc, t);
#pragma unroll
    for (int i = 0; i < 8; i++) v[8 + i] += t[i];
    float sum = 0.f, sq = 0.f;
#pragma unroll
    for (int i = 0; i < 16; i++) { sum += v[i]; sq += v[i] * v[i]; }
#pragma unroll
    for (int off = 32; off; off >>= 1) {
        sum += __shfl_xor(sum, off);
        sq += __shfl_xor(sq, off);
    }
    float mean = sum * (1.f / 1024.f);
    float var = sq * (1.f / 1024.f) - mean * mean;
    float rstd = rsqrtf(var + LN_EPS);
    float4 g0 = *(const float4*)&g[d0],      g1 = *(const float4*)&g[d0 + 4];
    float4 g2 = *(const float4*)&g[d0 + 8],  g3 = *(const float4*)&g[d0 + 12];
    float4 b0 = *(const float4*)&beta[d0],     b1 = *(const float4*)&beta[d0 + 4];
    float4 b2 = *(const float4*)&beta[d0 + 8], b3 = *(const float4*)&beta[d0 + 12];
    float gg[16] = {g0.x,g0.y,g0.z,g0.w, g1.x,g1.y,g1.z,g1.w, g2.x,g2.y,g2.z,g2.w, g3.x,g3.y,g3.z,g3.w};
    float bb[16] = {b0.x,b0.y,b0.z,b0.w, b1.x,b1.y,b1.z,b1.w, b2.x,b2.y,b2.z,b2.w, b3.x,b3.y,b3.z,b3.w};
    float y[16];
#pragma unroll
    for (int i = 0; i < 16; i++) y[i] = (v[i] - mean) * rstd * gg[i] + bb[i];
    uint4 oa, oc;
    oa.x = pk2(y[0], y[1]);  oa.y = pk2(y[2], y[3]);
    oa.z = pk2(y[4], y[5]);  oa.w = pk2(y[6], y[7]);
    oc.x = pk2(y[8], y[9]);  oc.y = pk2(y[10], y[11]);
    oc.z = pk2(y[12], y[13]); oc.w = pk2(y[14], y[15]);
    *(uint4*)&x[d0] = oa;
    *(uint4*)&x[d0 + 8] = oc;
}

// ---------------- xb = bf16(LN(xb + p0 + p1) * g + beta) -- f32 split-K partials ------
__global__ __launch_bounds__(256) void k_add_ln2(
    u16* __restrict__ xb, const float* __restrict__ p0, const float* __restrict__ p1,
    const float* __restrict__ g, const float* __restrict__ beta)
{
    int row = blockIdx.x * 4 + (threadIdx.x >> 6);   // b*512 + l
    int lane = threadIdx.x & 63;
    u16* x = xb + (long)row * 1024;
    const float* a0 = p0 + (long)row * 1024;
    const float* a1 = p1 + (long)row * 1024;
    int d0 = lane * 16;
    uint4 xa = *(const uint4*)&x[d0];
    uint4 xc = *(const uint4*)&x[d0 + 8];
    float v[16];
    unp8(xa, v); unp8(xc, v + 8);
#pragma unroll
    for (int i = 0; i < 16; i += 4) {
        float4 q0 = *(const float4*)&a0[d0 + i];
        float4 q1 = *(const float4*)&a1[d0 + i];
        v[i]     += q0.x + q1.x;
        v[i + 1] += q0.y + q1.y;
        v[i + 2] += q0.z + q1.z;
        v[i + 3] += q0.w + q1.w;
    }
    float sum = 0.f, sq = 0.f;
#pragma unroll
    for (int i = 0; i < 16; i++) { sum += v[i]; sq += v[i] * v[i]; }
#pragma unroll
    for (int off = 32; off; off >>= 1) {
        sum += __shfl_xor(sum, off);
        sq += __shfl_xor(sq, off);
    }
    float mean = sum * (1.f / 1024.f);
    float var = sq * (1.f / 1024.f) - mean * mean;
    float rstd = rsqrtf(var + LN_EPS);
    float4 g0 = *(const float4*)&g[d0],      g1 = *(const float4*)&g[d0 + 4];
    float4 g2 = *(const float4*)&g[d0 + 8],  g3 = *(const float4*)&g[d0 + 12];
    float4 b0 = *(const float4*)&beta[d0],     b1 = *(const float4*)&beta[d0 + 4];
    float4 b2 = *(const float4*)&beta[d0 + 8], b3 = *(const float4*)&beta[d0 + 12];
    float gg[16] = {g0.x,g0.y,g0.z,g0.w, g1.x,g1.y,g1.z,g1.w, g2.x,g2.y,g2.z,g2.w, g3.x,g3.y,g3.z,g3.w};
    float bb[16] = {b0.x,b0.y,b0.z,b0.w, b1.x,b1.y,b1.z,b1.w, b2.x,b2.y,b2.z,b2.w, b3.x,b3.y,b3.z,b3.w};
    float y[16];
#pragma unroll
    for (int i = 0; i < 16; i++) y[i] = (v[i] - mean) * rstd * gg[i] + bb[i];
    uint4 oa, oc;
    oa.x = pk2(y[0], y[1]);  oa.y = pk2(y[2], y[3]);
    oa.z = pk2(y[4], y[5]);  oa.w = pk2(y[6], y[7]);
    oc.x = pk2(y[8], y[9]);  oc.y = pk2(y[10], y[11]);
    oc.z = pk2(y[12], y[13]); oc.w = pk2(y[14], y[15]);
    *(uint4*)&x[d0] = oa;
    *(uint4*)&x[d0 + 8] = oc;
}

// ---------------- head rows only: xhead = bf16(LN(xb + p0 + p1; g,beta)), rows 0-511 --
__global__ __launch_bounds__(256) void k_ln_head(
    const u16* __restrict__ xb, const float* __restrict__ p0, const float* __restrict__ p1,
    const float* __restrict__ g, const float* __restrict__ beta, u16* __restrict__ xhead)
{
    int row = blockIdx.x * 4 + (threadIdx.x >> 6);   // 0..511
    int lane = threadIdx.x & 63;
    const u16* x = xb + (long)row * 1024;
    const float* a0 = p0 + (long)row * 1024;
    const float* a1 = p1 + (long)row * 1024;
    int d0 = lane * 16;
    uint4 xa = *(const uint4*)&x[d0];
    uint4 xc = *(const uint4*)&x[d0 + 8];
    float v[16];
    unp8(xa, v); unp8(xc, v + 8);
#pragma unroll
    for (int i = 0; i < 16; i += 4) {
        float4 q0 = *(const float4*)&a0[d0 + i];
        float4 q1 = *(const float4*)&a1[d0 + i];
        v[i]     += q0.x + q1.x;
        v[i + 1] += q0.y + q1.y;
        v[i + 2] += q0.z + q1.z;
        v[i + 3] += q0.w + q1.w;
    }
    float sum = 0.f, sq = 0.f;
#pragma unroll
    for (int i = 0; i < 16; i++) { sum += v[i]; sq += v[i] * v[i]; }
#pragma unroll
    for (int off = 32; off; off >>= 1) {
        sum += __shfl_xor(sum, off);
        sq += __shfl_xor(sq, off);
    }
    float mean = sum * (1.f / 1024.f);
    float var = sq * (1.f / 1024.f) - mean * mean;
    float rstd = rsqrtf(var + LN_EPS);
    float y[16];
#pragma unroll
    for (int i = 0; i < 16; i += 4) {
        float4 gv = *(const float4*)&g[d0 + i];
        float4 bv = *(const float4*)&beta[d0 + i];
        y[i]     = (v[i]     - mean) * rstd * gv.x + bv.x;
        y[i + 1] = (v[i + 1] - mean) * rstd * gv.y + bv.y;
        y[i + 2] = (v[i + 2] - mean) * rstd * gv.z + bv.z;
        y[i + 3] = (v[i + 3] - mean) * rstd * gv.w + bv.w;
    }
    uint4 oa, oc;
    oa.x = pk2(y[0], y[1]);  oa.y = pk2(y[2], y[3]);
    oa.z = pk2(y[4], y[5]);  oa.w = pk2(y[6], y[7]);
    oc.x = pk2(y[8], y[9]);  oc.y = pk2(y[10], y[11]);
    oc.z = pk2(y[12], y[13]); oc.w = pk2(y[14], y[15]);
    u16* o = xhead + (long)row * 1024;
    *(uint4*)&o[d0] = oa;
    *(uint4*)&o[d0 + 8] = oc;
}

// ---------------- fused ln2(prev layer) + ln1(this layer), all rows -------------------
// xb = LN( LN(xb + p0 + p1; g2,be2) + src2[row&511]; g1,be1 )
__global__ __launch_bounds__(256) void k_ln2ln1(
    u16* __restrict__ xb, const float* __restrict__ p0, const float* __restrict__ p1,
    const u16* __restrict__ s2,
    const float* __restrict__ g2, const float* __restrict__ be2,
    const float* __restrict__ g1, const float* __restrict__ be1)
{
    int row = blockIdx.x * 4 + (threadIdx.x >> 6);   // b*512 + l
    int lane = threadIdx.x & 63;
    u16* x = xb + (long)row * 1024;
    const float* a0 = p0 + (long)row * 1024;
    const float* a1 = p1 + (long)row * 1024;
    const u16* sp = s2 + (long)(row & 511) * 1024;
    int d0 = lane * 16;
    uint4 xa = *(const uint4*)&x[d0];
    uint4 xc = *(const uint4*)&x[d0 + 8];
    float v[16];
    unp8(xa, v); unp8(xc, v + 8);
#pragma unroll
    for (int i = 0; i < 16; i += 4) {
        float4 q0 = *(const float4*)&a0[d0 + i];
        float4 q1 = *(const float4*)&a1[d0 + i];
        v[i]     += q0.x + q1.x;
        v[i + 1] += q0.y + q1.y;
        v[i + 2] += q0.z + q1.z;
        v[i + 3] += q0.w + q1.w;
    }
    // ---- LN2 ----
    float sum = 0.f, sq = 0.f;
#pragma unroll
    for (int i = 0; i < 16; i++) { sum += v[i]; sq += v[i] * v[i]; }
#pragma unroll
    for (int off = 32; off; off >>= 1) {
        sum += __shfl_xor(sum, off);
        sq += __shfl_xor(sq, off);
    }
    float mean = sum * (1.f / 1024.f);
    float var = sq * (1.f / 1024.f) - mean * mean;
    float rstd = rsqrtf(var + LN_EPS);
#pragma unroll
    for (int i = 0; i < 16; i += 4) {
        float4 gv = *(const float4*)&g2[d0 + i];
        float4 bv = *(const float4*)&be2[d0 + i];
        v[i]     = (v[i]     - mean) * rstd * gv.x + bv.x;
        v[i + 1] = (v[i + 1] - mean) * rstd * gv.y + bv.y;
        v[i + 2] = (v[i + 2] - mean) * rstd * gv.z + bv.z;
        v[i + 3] = (v[i + 3] - mean) * rstd * gv.w + bv.w;
    }
    // ---- + src2 (broadcast) ----
    uint4 sa = *(const uint4*)&sp[d0];
    uint4 sc = *(const uint4*)&sp[d0 + 8];
    float t[8];
    unp8(sa, t);
#pragma unroll
    for (int i = 0; i < 8; i++) v[i] += t[i];
    unp8(sc, t);
#pragma unroll
    for (int i = 0; i < 8; i++) v[8 + i] += t[i];
    // ---- LN1 ----
    sum = 0.f; sq = 0.f;
#pragma unroll
    for (int i = 0; i < 16; i++) { sum += v[i]; sq += v[i] * v[i]; }
#pragma unroll
    for (int off = 32; off; off >>= 1) {
        sum += __shfl_xor(sum, off);
        sq += __shfl_xor(sq, off);
    }
    mean = sum * (1.f / 1024.f);
    var = sq * (1.f / 1024.f) - mean * mean;
    rstd = rsqrtf(var + LN_EPS);
    float y[16];
#pragma unroll
    for (int i = 0; i < 16; i += 4) {
        float4 gv = *(const float4*)&g1[d0 + i];
        float4 bv = *(const float4*)&be1[d0 + i];
        y[i]     = (v[i]     - mean) * rstd * gv.x + bv.x;
        y[i + 1] = (v[i + 1] - mean) * rstd * gv.y + bv.y;
        y[i + 2] = (v[i + 2] - mean) * rstd * gv.z + bv.z;
        y[i + 3] = (v[i + 3] - mean) * rstd * gv.w + bv.w;
    }
    uint4 oa, oc;
    oa.x = pk2(y[0], y[1]);  oa.y = pk2(y[2], y[3]);
    oa.z = pk2(y[4], y[5]);  oa.w = pk2(y[6], y[7]);
    oc.x = pk2(y[8], y[9]);  oc.y = pk2(y[10], y[11]);
    oc.z = pk2(y[12], y[13]); oc.w = pk2(y[14], y[15]);
    *(uint4*)&x[d0] = oa;
    *(uint4*)&x[d0 + 8] = oc;
}

// ---------------- pool stage A: pp[b][ch][d] = sum_{l in 64-chunk} x[b][l][d] ---------
__global__ __launch_bounds__(256) void k_pool_a(
    const u16* __restrict__ xb, float* __restrict__ pp)
{
    int b = blockIdx.x >> 3, ch = blockIdx.x & 7;
    int d0 = threadIdx.x * 4;
    const u16* x = xb + ((long)b * 512 + ch * 64) * 1024;
    float s0 = 0.f, s1 = 0.f, s2 = 0.f, s3 = 0.f;
    for (int l = 0; l < 64; l++) {
        ushort4 v = *(const ushort4*)&x[(long)l * 1024 + d0];
        s0 += bf2f(v.x); s1 += bf2f(v.y); s2 += bf2f(v.z); s3 += bf2f(v.w);
    }
    float* o = pp + ((long)b * 8 + ch) * 1024 + d0;
    o[0] = s0; o[1] = s1; o[2] = s2; o[3] = s3;
}

// ---------------- pool stage B + head: out[b][c] = mean·wf[:,c] + bf[c] ---------------
__global__ __launch_bounds__(256) void k_pool_b(
    const float* __restrict__ pp, const float* __restrict__ wf,
    const float* __restrict__ bfin, float* __restrict__ out)
{
    int b = blockIdx.x;
    int tid = threadIdx.x;
    __shared__ float pl[1024];
    int d0 = tid * 4;
    float s0 = 0.f, s1 = 0.f, s2 = 0.f, s3 = 0.f;
#pragma unroll
    for (int ch = 0; ch < 8; ch++) {
        float4 q = *(const float4*)&pp[((long)b * 8 + ch) * 1024 + d0];
        s0 += q.x; s1 += q.y; s2 += q.z; s3 += q.w;
    }
    pl[d0] = s0 * (1.f / 512.f);
    pl[d0 + 1] = s1 * (1.f / 512.f);
    pl[d0 + 2] = s2 * (1.f / 512.f);
    pl[d0 + 3] = s3 * (1.f / 512.f);
    __syncthreads();
    __shared__ float red[4];
    for (int c = 0; c < 10; c++) {
        float t = 0.f;
        for (int d = tid; d < 1024; d += 256) t += pl[d] * wf[(long)d * 10 + c];
        for (int off = 32; off; off >>= 1) t += __shfl_down(t, off);
        if ((tid & 63) == 0) red[tid >> 6] = t;
        __syncthreads();
        if (tid == 0) out[b * 10 + c] = red[0] + red[1] + red[2] + red[3] + bfin[c];
        __syncthreads();
    }
}

// ---------------- host side ----------------
template <int TM, int TN, bool VT_EPI>
static void gemm(const u16* A, long lda, const u16* B, long ldb,
                 u16* C, long ldc,
                 int M, int N, int K, const float* bias,
                 hipStream_t st, u16* vTout = nullptr)
{
    dim3 g((N + TN - 1) / TN, (M + TM - 1) / TM);
    k_gemm_nt<TM, TN, VT_EPI><<<g, 256, 0, st>>>(A, lda, B, ldb, C, ldc, M, N, K, bias, vTout);
}

extern "C" void kernel_launch(void* const* d_in, const int* in_sizes, int n_in,
                              void* d_out, int out_size, void* d_ws, size_t ws_size,
                              hipStream_t stream)
{
    const int* ids   = (const int*)d_in[0];
    const float* emb = (const float*)d_in[1];
    const float* pe  = (const float*)d_in[2];
    const float* wq  = (const float*)d_in[3];
    const float* bq  = (const float*)d_in[4];
    const float* wk  = (const float*)d_in[5];
    const float* bk  = (const float*)d_in[6];
    const float* wv  = (const float*)d_in[7];
    const float* bv  = (const float*)d_in[8];
    const float* wo  = (const float*)d_in[9];
    const float* bo  = (const float*)d_in[10];
    const float* w1  = (const float*)d_in[11];
    const float* b1  = (const float*)d_in[12];
    const float* w2  = (const float*)d_in[13];
    const float* b2  = (const float*)d_in[14];
    const float* g1  = (const float*)d_in[15];
    const float* be1 = (const float*)d_in[16];
    const float* g2  = (const float*)d_in[17];
    const float* be2 = (const float*)d_in[18];
    const float* wf  = (const float*)d_in[19];
    const float* bfi = (const float*)d_in[20];
    float* out = (float*)d_out;

    char* base = (char*)d_ws;
    size_t off = 0;
    auto alloc = [&](size_t bytes) {
        char* p = base + off;
        off = (off + bytes + 255) & ~(size_t)255;
        return p;
    };
    u16*   xb    = (u16*)  alloc(16UL * 512 * 1024 * 2);   // bf16 residual stream [B,L,D]
    u16*   wqkvT = (u16*)  alloc(3072UL * 1024 * 2);       // [3072,1024] = wqT;wkT;wvT
    u16*   woT   = (u16*)  alloc(1024UL * 1024 * 2);
    u16*   w1b   = (u16*)  alloc(1024UL * 4096 * 2);       // bf16 cast of w1 [D,F]
    u16*   w2T   = (u16*)  alloc(1024UL * 4096 * 2);       // [D,F] = w2 transposed
    u16*   W12T  = (u16*)  alloc(1024UL * 1024 * 2);       // folded FFN weight, [e][d]
    float* b12f  = (float*)alloc(1024UL * 4);              // folded FFN bias
    float* b12p  = (float*)alloc(32UL * 1024 * 4);         // bias-fold partials
    float* qkvb  = (float*)alloc(3072UL * 4);              // concat(bq,bk,bv)
    u16*   qkv   = (u16*)  alloc(512UL * 3072 * 2);        // [L, 3*D]; v-part goes to vT
    u16*   vT    = (u16*)  alloc(1024UL * 512 * 2);        // v transposed [D,L]
    u16*   Ob    = (u16*)  alloc(512UL * 1024 * 2);        // attn context bf16 [L,D]
    u16*   src2  = (u16*)  alloc(512UL * 1024 * 2);        // bf16
    u16*   xhead = (u16*)  alloc(512UL * 1024 * 2);        // ln2-ed head rows for qkv
    float* ppool = (float*)alloc(16UL * 8 * 1024 * 4);     // pool partials
    float* ffp   = (float*)alloc(2UL * 8192 * 1024 * 4);   // FFN split-K f32 partials

    k_prep<<<12300, 256, 0, stream>>>(wq, wk, wv, wo, w1, w2, bq, bk, bv, qkvb,
                                      wqkvT, woT, w1b, w2T);
    k_bias12a<<<256, 256, 0, stream>>>(b1, w2, b12p);
    k_bias12b<<<8, 128, 0, stream>>>(b12p, b2, b12f);
    k_embed<<<8192, 256, 0, stream>>>(ids, emb, pe, xb);
    // W12T[e][d] = sum_f w2T[e][f] * w1b[d][f] via split-K gemm8 (z=16, K=256 each)
    k_gemm8<true><<<dim3(4, 4, 16), 512, 0, stream>>>(w2T, 4096, w1b, 4096,
                                                      (u16*)ffp, 1024, 256, nullptr);
    k_w12red<<<1024, 256, 0, stream>>>(ffp, W12T);

    for (int layer = 0; layer < 6; layer++) {
        const u16* qsrc = xb;
        if (layer > 0) {
            // head rows of ln2(prev): feeds this layer's qkv; bulk ln2 deferred into F
            k_ln_head<<<128, 256, 0, stream>>>(xb, ffp, ffp + 8192UL * 1024, g2, be2, xhead);
            qsrc = xhead;
        }
        // fused q|k|v for batch 0: [512,3072]; V cols written transposed into vT
        gemm<64, 64, true>(qsrc, 1024, wqkvT, 1024, qkv, 3072, 512, 3072, 1024, qkvb, stream, vT);
        // fused scores+softmax+PV
        k_attn<<<dim3(16, 16), 128, 0, stream>>>(qkv, vT, Ob);
        // src2 = O . wo + bo
        gemm<64, 64, false>(Ob, 1024, woT, 1024, src2, 1024, 512, 1024, 1024, bo, stream);
        if (layer == 0)
            k_add_ln<<<2048, 256, 0, stream>>>(xb, src2, 1, g1, be1);
        else
            // xb = LN1( LN2(xb + ffp) + src2 )  -- fused bulk ln2(prev)+ln1(this)
            k_ln2ln1<<<2048, 256, 0, stream>>>(xb, ffp, ffp + 8192UL * 1024, src2,
                                               g2, be2, g1, be1);
        // folded FFN: ff = xb @ W12T^T + b12, split-K z=2 (K=512 each) -> f32 partials
        k_gemm8<true><<<dim3(4, 32, 2), 512, 0, stream>>>(xb, 1024, W12T, 1024,
                                                          (u16*)ffp, 1024, 512, b12f);
    }

    // final ln2 after last layer's FFN
    k_add_ln2<<<2048, 256, 0, stream>>>(xb, ffp, ffp + 8192UL * 1024, g2, be2);
    k_pool_a<<<128, 256, 0, stream>>>(xb, ppool);
    k_pool_b<<<16, 256, 0, stream>>>(ppool, wf, bfi, out);
}

// Round 8
// 861.260 us; speedup vs baseline: 1.7791x; 1.0417x over previous
//
#include <hip/hip_runtime.h>

typedef unsigned short u16;
typedef unsigned int u32;
typedef __bf16 bf16x8 __attribute__((ext_vector_type(8)));
typedef float f32x4 __attribute__((ext_vector_type(4)));

#define LN_EPS 1e-5f
#define L2E 1.44269504f

__device__ __forceinline__ u16 f2bf(float f) {
    u32 u = __float_as_uint(f);
    u += 0x7fffu + ((u >> 16) & 1u);
    return (u16)(u >> 16);
}
__device__ __forceinline__ float bf2f(u32 v) {
    return __uint_as_float(v << 16);
}
__device__ __forceinline__ void unp8(uint4 u, float* v) {
    v[0] = bf2f(u.x & 0xffff); v[1] = bf2f(u.x >> 16);
    v[2] = bf2f(u.y & 0xffff); v[3] = bf2f(u.y >> 16);
    v[4] = bf2f(u.z & 0xffff); v[5] = bf2f(u.z >> 16);
    v[6] = bf2f(u.w & 0xffff); v[7] = bf2f(u.w >> 16);
}
__device__ __forceinline__ u32 pk2(float a, float b) {
    return (u32)f2bf(a) | ((u32)f2bf(b) << 16);
}

// async global->LDS, 16B per lane; lds base must be wave-uniform (HW: base + lane*16)
#define ASYNC_CP16(g, l)                                                      \
    __builtin_amdgcn_global_load_lds(                                         \
        (const __attribute__((address_space(1))) u32*)(g),                    \
        (__attribute__((address_space(3))) u32*)(l), 16, 0, 0)

// ---------------- one-shot prep: weight transposes (f32->bf16), w1 cast, bias concat --
__global__ __launch_bounds__(256) void k_prep(
    const float* __restrict__ wq, const float* __restrict__ wk,
    const float* __restrict__ wv, const float* __restrict__ wo,
    const float* __restrict__ w1, const float* __restrict__ w2,
    const float* __restrict__ bq, const float* __restrict__ bk,
    const float* __restrict__ bv, float* __restrict__ qkvb,
    u16* __restrict__ wqkvT, u16* __restrict__ woT,
    u16* __restrict__ w1b, u16* __restrict__ w2T)
{
    int b = blockIdx.x;
    if (b >= 12288) {
        int i = (b - 12288) * 256 + threadIdx.x;
        qkvb[i] = (i < 1024) ? bq[i] : (i < 2048 ? bk[i - 1024] : bv[i - 2048]);
        return;
    }
    if (b >= 4096 && b < 8192) {
        // straight f32->bf16 cast of w1 [1024][4096] (K-major already; no transpose)
        int i = (b - 4096) * 1024 + threadIdx.x * 4;
        float4 v = *(const float4*)&w1[i];
        ushort4 o;
        o.x = f2bf(v.x); o.y = f2bf(v.y); o.z = f2bf(v.z); o.w = f2bf(v.w);
        *(ushort4*)&w1b[i] = o;
        return;
    }
    const float* in; u16* out; int C; long ldo; int gx; int l;
    if (b < 4096) {
        int j = b >> 10; l = b & 1023;
        in = (j == 0) ? wq : (j == 1) ? wk : (j == 2) ? wv : wo;
        out = (j == 3) ? woT : wqkvT + (long)j * 1024 * 1024;
        C = 1024; ldo = 1024; gx = 32;
    } else {
        l = b - 8192; in = w2; out = w2T; C = 1024; ldo = 4096; gx = 32;
    }
    int bx = l % gx, by = l / gx;
    __shared__ float tile[32][33];
    int c0 = bx * 32, r0 = by * 32;
    int tx = threadIdx.x & 31, ty = threadIdx.x >> 5;
#pragma unroll
    for (int i = 0; i < 4; i++)
        tile[ty + 8 * i][tx] = in[(long)(r0 + ty + 8 * i) * C + c0 + tx];
    __syncthreads();
#pragma unroll
    for (int i = 0; i < 4; i++)
        out[(long)(c0 + ty + 8 * i) * ldo + r0 + tx] = f2bf(tile[tx][ty + 8 * i]);
}

// ---------------- folded FFN bias, stage A: partial[fc][e] = sum_{f in chunk} b1[f]*w2[f][e]
__global__ __launch_bounds__(256) void k_bias12a(
    const float* __restrict__ b1, const float* __restrict__ w2,
    float* __restrict__ partial)
{
    int eb = blockIdx.x & 7;       // e-chunk (128 e's)
    int fc = blockIdx.x >> 3;      // f-chunk 0..31 (128 f's)
    int t = threadIdx.x;
    int e = eb * 128 + (t & 127);
    int f0 = fc * 128 + (t >> 7) * 64;
    float s = 0.f;
    for (int f = f0; f < f0 + 64; f++)
        s += b1[f] * w2[(long)f * 1024 + e];
    __shared__ float sh[256];
    sh[t] = s;
    __syncthreads();
    if (t < 128) partial[(long)fc * 1024 + e] = sh[t] + sh[t + 128];
}

// ---------------- folded FFN bias, stage B: b12[e] = sum_fc partial[fc][e] + b2[e] ----
__global__ __launch_bounds__(128) void k_bias12b(
    const float* __restrict__ partial, const float* __restrict__ b2,
    float* __restrict__ b12)
{
    int e = blockIdx.x * 128 + threadIdx.x;
    float s = b2[e];
#pragma unroll 8
    for (int fc = 0; fc < 32; fc++) s += partial[(long)fc * 1024 + e];
    b12[e] = s;
}

// ---------------- W12 split-K reduce: W12T[e][d] = bf16(sum_z bf16p[z][e][d]) ---------
__global__ __launch_bounds__(256) void k_w12red(
    const u16* __restrict__ p, u16* __restrict__ w12)
{
    int e = blockIdx.x;            // 0..1023
    int d0 = threadIdx.x * 4;
    float s0 = 0.f, s1 = 0.f, s2 = 0.f, s3 = 0.f;
#pragma unroll 4
    for (int z = 0; z < 16; z++) {
        ushort4 q = *(const ushort4*)&p[(long)z * 1024 * 1024 + (long)e * 1024 + d0];
        s0 += bf2f(q.x); s1 += bf2f(q.y); s2 += bf2f(q.z); s3 += bf2f(q.w);
    }
    ushort4 o;
    o.x = f2bf(s0); o.y = f2bf(s1); o.z = f2bf(s2); o.w = f2bf(s3);
    *(ushort4*)&w12[(long)e * 1024 + d0] = o;
}

// ---------------- embedding: xb = bf16(emb[id]*32 + pe) ----------------
__global__ __launch_bounds__(256) void k_embed(
    const int* __restrict__ ids, const float* __restrict__ emb,
    const float* __restrict__ pe, u16* __restrict__ xb)
{
    int row = blockIdx.x;          // b*512 + l
    int l = row & 511;
    long id = (long)ids[row];
    const float* e = emb + id * 1024;
    const float* p = pe + (long)l * 1024;
    u16* xbo = xb + (long)row * 1024;
    int d0 = threadIdx.x * 4;
    float4 ev = *(const float4*)&e[d0];
    float4 pv = *(const float4*)&p[d0];
    ushort4 o;
    o.x = f2bf(ev.x * 32.0f + pv.x);
    o.y = f2bf(ev.y * 32.0f + pv.y);
    o.z = f2bf(ev.z * 32.0f + pv.z);
    o.w = f2bf(ev.w * 32.0f + pv.w);
    *(ushort4*)&xbo[d0] = o;
}

// ---------------- bf16 MFMA GEMM, NT form (small shapes: QKV / WO) -------------------
template <int TM, int TN, bool VT_EPI>
__global__ __launch_bounds__(256) void k_gemm_nt(
    const u16* __restrict__ A, long lda,
    const u16* __restrict__ B, long ldb,
    u16* __restrict__ Cm, long ldc,
    int M, int N, int K,
    const float* __restrict__ bias,
    u16* __restrict__ vTout)
{
    constexpr int FM = TM / 32;     // m-frags per wave
    constexpr int FN = TN / 32;     // n-frags per wave
    constexpr int CPA = TM / 64;    // A chunks per wave per K-plane
    constexpr int CPB = TN / 64;
    __shared__ u16 As[2 * TM * 32];
    __shared__ u16 Bs[2 * TN * 32];
    int m0 = blockIdx.y * TM, n0 = blockIdx.x * TN;
    int tid = threadIdx.x;
    int lane = tid & 63, wid = tid >> 6;
    int wr = wid >> 1, wc = wid & 1;
    int quad = lane >> 4, l16 = lane & 15;

    f32x4 acc[FM][FN];
#pragma unroll
    for (int i = 0; i < FM; i++)
#pragma unroll
        for (int j = 0; j < FN; j++) acc[i][j] = {0.f, 0.f, 0.f, 0.f};

    // staging: chunk = 16 rows x 32 k (1KB); lane l -> row c*16 + l/4, k-seg (l%4)*8
    int seg = (lane & 3) * 8;
    const u16* pA[CPA]; u16* lA[2][CPA];
    const u16* pB[CPB]; u16* lB[2][CPB];
#pragma unroll
    for (int i = 0; i < CPA; i++) {
        int c = wid * CPA + i;
        int gm = min(m0 + c * 16 + (lane >> 2), M - 1);
        pA[i] = A + (long)gm * lda + seg;
        lA[0][i] = &As[c * 512];
        lA[1][i] = &As[TM * 32 + c * 512];
    }
#pragma unroll
    for (int i = 0; i < CPB; i++) {
        int c = wid * CPB + i;
        int gn = min(n0 + c * 16 + (lane >> 2), N - 1);
        pB[i] = B + (long)gn * ldb + seg;
        lB[0][i] = &Bs[c * 512];
        lB[1][i] = &Bs[TN * 32 + c * 512];
    }

    for (int kb = 0; kb < K; kb += 64) {
#pragma unroll
        for (int kh = 0; kh < 2; kh++) {
#pragma unroll
            for (int i = 0; i < CPA; i++) ASYNC_CP16(pA[i] + kb + kh * 32, lA[kh][i]);
#pragma unroll
            for (int i = 0; i < CPB; i++) ASYNC_CP16(pB[i] + kb + kh * 32, lB[kh][i]);
        }
        __syncthreads();
        bf16x8 af[2][FM], bg[2][FN];
#pragma unroll
        for (int kh = 0; kh < 2; kh++)
#pragma unroll
            for (int t = 0; t < FM; t++)
                af[kh][t] = *(const bf16x8*)&As[kh * TM * 32 + (wr * (TM / 2) + t * 16 + l16) * 32 + quad * 8];
#pragma unroll
        for (int kh = 0; kh < 2; kh++)
#pragma unroll
            for (int t = 0; t < FN; t++)
                bg[kh][t] = *(const bf16x8*)&Bs[kh * TN * 32 + (wc * (TN / 2) + t * 16 + l16) * 32 + quad * 8];
#pragma unroll
        for (int kh = 0; kh < 2; kh++)
#pragma unroll
            for (int i = 0; i < FM; i++)
#pragma unroll
                for (int j = 0; j < FN; j++)
                    acc[i][j] = __builtin_amdgcn_mfma_f32_16x16x32_bf16(af[kh][i], bg[kh][j], acc[i][j], 0, 0, 0);
        __syncthreads();
    }

    // epilogue: C/D layout col=lane&15, row=quad*4+r (verified m89/m91)
#pragma unroll
    for (int i = 0; i < FM; i++) {
        int gm0 = m0 + wr * (TM / 2) + i * 16 + quad * 4;
#pragma unroll
        for (int j = 0; j < FN; j++) {
            int gn = n0 + wc * (TN / 2) + j * 16 + l16;
            if (gn >= N) continue;
            float bn = bias ? bias[gn] : 0.f;
            if (VT_EPI && gn >= 2048) {
                // V columns -> vT[d][l]: r maps to contiguous l -> ushort4 store
                ushort4 o;
                o.x = f2bf(acc[i][j][0] + bn);
                o.y = f2bf(acc[i][j][1] + bn);
                o.z = f2bf(acc[i][j][2] + bn);
                o.w = f2bf(acc[i][j][3] + bn);
                *(ushort4*)&vTout[(long)(gn - 2048) * 512 + gm0] = o;
                continue;
            }
#pragma unroll
            for (int r = 0; r < 4; r++) {
                int gm = gm0 + r;
                if (gm >= M) continue;
                Cm[(long)gm * ldc + gn] = f2bf(acc[i][j][r] + bn);
            }
        }
    }
}

// ---------------- full-prefetch counted-waitcnt MFMA GEMM, 256x256 (FFN / W12) -------
// 512 thr = 8 waves (2m x 4n); per-wave C = 128x64. K in 32-wide subtiles, 4 LDS slots.
// Per iter j: issue ALL 12 ds_reads for subtile j+1 (slot resident via prev vmcnt(4)),
// stage subtile j+3; lgkmcnt(12) waits only for LAST iter's reads (long done); then the
// FULL 32-MFMA burst runs from regs while this iter's 12 reads service underneath.
// vmcnt(4) end-of-iter gates slot j+2 residency; ONE barrier/iter. XCD-swizzled
// blockIdx; 2-way-free LDS bank swizzle via inverse-swizzled global src + swizzled
// ds_read addr. SPLITK: blockIdx.z selects K-slice; BF16 partials at z*M*ldc; bias z==0
// (precision: partial sigma~0.6, bf16 rel 2^-9 -> abs ~1e-3, below bf16-input error).
// Requires M%256==0, N%256==0, K%64==0, K>=128, (gridDim.x*gridDim.y)%8==0.
template <bool SPLITK>
__global__ __launch_bounds__(512, 2) void k_gemm8(
    const u16* __restrict__ A, long lda,
    const u16* __restrict__ B, long ldb,
    u16* __restrict__ Cm, long ldc,
    int K, const float* __restrict__ bias)
{
    constexpr int BM = 256, BN = 256;
    constexpr int MF = 8;
    constexpr int ASLOT = BM * 32;
    constexpr int BSLOT = BN * 32;
    __shared__ u16 As[4 * ASLOT];
    __shared__ u16 Bs[4 * BSLOT];

    // XCD-aware chunked swizzle (bijective since nwg % 8 == 0)
    int lin = blockIdx.y * gridDim.x + blockIdx.x;
    int cpx = (gridDim.x * gridDim.y) >> 3;
    int sw = (lin & 7) * cpx + (lin >> 3);
    int bx = sw % gridDim.x, by = sw / gridDim.x;

    const int m0 = by * BM, n0 = bx * BN;
    const long kbase = SPLITK ? (long)blockIdx.z * K : 0;
    const int tid = threadIdx.x;
    const int lane = tid & 63, wid = tid >> 6;
    const int wm = wid >> 2, wn = wid & 3;
    const int wrow = wm * 128, wcol = wn * 64;
    const int quad = lane >> 4, l16 = lane & 15;

    f32x4 acc[MF][4];
#pragma unroll
    for (int f = 0; f < MF; f++)
#pragma unroll
        for (int g = 0; g < 4; g++) acc[f][g] = {0.f, 0.f, 0.f, 0.f};

    // staging source: lane covers row = i*128 + wid*16 + (lane>>2),
    // k-granule pre-inverse-swizzled: (lane&3) ^ ((lane>>3)&3)
    const int srow = wid * 16 + (lane >> 2);
    const int skoff = (((lane & 3) ^ ((lane >> 3) & 3)) << 3);
    const u16* aSrc = A + (long)(m0 + srow) * lda + kbase + skoff;
    const u16* bSrc = B + (long)(n0 + srow) * ldb + kbase + skoff;

    // swizzled ds_read offsets (u16 units): r*32 + ((quad ^ ((r>>1)&3)) * 8)
    int aoff[MF], boff[4];
#pragma unroll
    for (int f = 0; f < MF; f++) {
        int r = wrow + f * 16 + l16;
        aoff[f] = r * 32 + ((quad ^ ((r >> 1) & 3)) << 3);
    }
#pragma unroll
    for (int g = 0; g < 4; g++) {
        int r = wcol + g * 16 + l16;
        boff[g] = r * 32 + ((quad ^ ((r >> 1) & 3)) << 3);
    }

    auto stageA = [&](int j) {
        u16* d = &As[(j & 3) * ASLOT + wid * 512];
#pragma unroll
        for (int i = 0; i < 2; i++)
            ASYNC_CP16(aSrc + (long)i * 128 * lda + j * 32, d + i * 4096);
    };
    auto stageB = [&](int j) {
        u16* d = &Bs[(j & 3) * BSLOT + wid * 512];
#pragma unroll
        for (int i = 0; i < 2; i++)
            ASYNC_CP16(bSrc + (long)i * 128 * ldb + j * 32, d + i * 4096);
    };

    // prologue: 3 subtiles in flight; slots 0 AND 1 resident (iter 0 reads slot 1)
    stageA(0); stageB(0); stageA(1); stageB(1); stageA(2); stageB(2);
    asm volatile("s_waitcnt vmcnt(4)" ::: "memory");
    __builtin_amdgcn_s_barrier();

    bf16x8 ra[2][MF], rb[2][4];
#pragma unroll
    for (int f = 0; f < MF; f++) ra[0][f] = *(const bf16x8*)&As[aoff[f]];
#pragma unroll
    for (int g = 0; g < 4; g++)  rb[0][g] = *(const bf16x8*)&Bs[boff[g]];

    const int NK = K >> 5;   // NK even, >= 4
    for (int j0 = 0; j0 < NK - 2; j0 += 2) {
#pragma unroll
        for (int u = 0; u < 2; u++) {
            const int j = j0 + u;
            const u16* Abn = &As[((j + 1) & 3) * ASLOT];
            const u16* Bbn = &Bs[((j + 1) & 3) * BSLOT];
            // prefetch ALL of subtile j+1 into the alternate reg set (12 reads)
#pragma unroll
            for (int f = 0; f < MF; f++) ra[u ^ 1][f] = *(const bf16x8*)&Abn[aoff[f]];
#pragma unroll
            for (int g = 0; g < 4; g++)  rb[u ^ 1][g] = *(const bf16x8*)&Bbn[boff[g]];
            if (j + 3 < NK) { stageA(j + 3); stageB(j + 3); }
            __builtin_amdgcn_sched_barrier(0);
            // wait only for LAST iter's 12 reads (set u) -- long since serviced
            asm volatile("s_waitcnt lgkmcnt(12)" ::: "memory");
            __builtin_amdgcn_sched_barrier(0);
            __builtin_amdgcn_s_setprio(1);
#pragma unroll
            for (int f = 0; f < MF; f++)
#pragma unroll
                for (int g = 0; g < 4; g++)
                    acc[f][g] = __builtin_amdgcn_mfma_f32_16x16x32_bf16(ra[u][f], rb[u][g], acc[f][g], 0, 0, 0);
            __builtin_amdgcn_s_setprio(0);
            // residency gate for slot j+2 (read at iter j+1); drain once stages end
            if (j < NK - 3) asm volatile("s_waitcnt vmcnt(4)" ::: "memory");
            else            asm volatile("s_waitcnt vmcnt(0)" ::: "memory");
            __builtin_amdgcn_s_barrier();
        }
    }
    // peel j = NK-2 (set 0): prefetch subtile NK-1, no stage/gate
    {
        const u16* Abn = &As[((NK - 1) & 3) * ASLOT];
        const u16* Bbn = &Bs[((NK - 1) & 3) * BSLOT];
#pragma unroll
        for (int f = 0; f < MF; f++) ra[1][f] = *(const bf16x8*)&Abn[aoff[f]];
#pragma unroll
        for (int g = 0; g < 4; g++)  rb[1][g] = *(const bf16x8*)&Bbn[boff[g]];
        __builtin_amdgcn_sched_barrier(0);
        asm volatile("s_waitcnt lgkmcnt(12)" ::: "memory");
        __builtin_amdgcn_sched_barrier(0);
        __builtin_amdgcn_s_setprio(1);
#pragma unroll
        for (int f = 0; f < MF; f++)
#pragma unroll
            for (int g = 0; g < 4; g++)
                acc[f][g] = __builtin_amdgcn_mfma_f32_16x16x32_bf16(ra[0][f], rb[0][g], acc[f][g], 0, 0, 0);
        __builtin_amdgcn_s_setprio(0);
    }
    // peel j = NK-1 (set 1)
    {
        asm volatile("s_waitcnt lgkmcnt(0)" ::: "memory");
        __builtin_amdgcn_sched_barrier(0);
        __builtin_amdgcn_s_setprio(1);
#pragma unroll
        for (int f = 0; f < MF; f++)
#pragma unroll
            for (int g = 0; g < 4; g++)
                acc[f][g] = __builtin_amdgcn_mfma_f32_16x16x32_bf16(ra[1][f], rb[1][g], acc[f][g], 0, 0, 0);
        __builtin_amdgcn_s_setprio(0);
    }

    // epilogue: C/D layout col=lane&15, row=quad*4+r
    if (SPLITK) {
        u16* Co = Cm + (long)blockIdx.z * (long)gridDim.y * BM * ldc;
        const bool zb = (blockIdx.z == 0);
#pragma unroll
        for (int f = 0; f < MF; f++) {
            int gm0 = m0 + wrow + f * 16 + quad * 4;
#pragma unroll
            for (int g = 0; g < 4; g++) {
                int gn = n0 + wcol + g * 16 + l16;
                float bn = (zb && bias) ? bias[gn] : 0.f;
#pragma unroll
                for (int r = 0; r < 4; r++)
                    Co[(long)(gm0 + r) * ldc + gn] = f2bf(acc[f][g][r] + bn);
            }
        }
    } else {
#pragma unroll
        for (int f = 0; f < MF; f++) {
            int gm0 = m0 + wrow + f * 16 + quad * 4;
#pragma unroll
            for (int g = 0; g < 4; g++) {
                int gn = n0 + wcol + g * 16 + l16;
                float bn = bias[gn];
#pragma unroll
                for (int r = 0; r < 4; r++)
                    Cm[(long)(gm0 + r) * ldc + gn] = f2bf(acc[f][g][r] + bn);
            }
        }
    }
}

// ---------------- fused attention: scores+softmax+PV for one (head, 32-q-row) block ---
__global__ __launch_bounds__(128) void k_attn(
    const u16* __restrict__ qkv, const u16* __restrict__ vT, u16* __restrict__ Ob)
{
    __shared__ u16 Ks[2][4096];   // plane layout: idx(key,d) = (d>>5)*2048 + key*32 + (d&31)
    __shared__ u16 Vs[2][4096];   // idx(d,key)   = (key>>5)*2048 + d*32 + (key&31)
    __shared__ u16 Pl[32 * 72];   // [q_local][72]; 144B rows -> 16B-aligned
    int qb = blockIdx.x, h = blockIdx.y;
    int tid = threadIdx.x;
    int w = tid >> 6, lane = tid & 63;
    int quad = lane >> 4, l16 = lane & 15;

    int qrow = qb * 32 + w * 16 + l16;
    bf16x8 aq[2];
#pragma unroll
    for (int c = 0; c < 2; c++)
        aq[c] = *(const bf16x8*)&qkv[(long)qrow * 3072 + h * 64 + c * 32 + quad * 8];

    f32x4 acc_o[4];
#pragma unroll
    for (int j = 0; j < 4; j++) acc_o[j] = {0.f, 0.f, 0.f, 0.f};
    float mrow[4], lrow[4];
#pragma unroll
    for (int r = 0; r < 4; r++) { mrow[r] = -1e30f; lrow[r] = 0.f; }

    {
        int kt = 0;
#pragma unroll
        for (int rr = 0; rr < 4; rr++) {
            int c = rr * 2 + w;
            int loc = (c & 3) * 16 + (lane >> 2);
            int off8 = ((c >> 2) << 5) + (lane & 3) * 8;
            ASYNC_CP16(&qkv[(long)(kt * 64 + loc) * 3072 + 1024 + h * 64 + off8], &Ks[0][c * 512]);
            ASYNC_CP16(&vT[(long)(h * 64 + loc) * 512 + kt * 64 + off8], &Vs[0][c * 512]);
        }
    }
    __syncthreads();

    for (int kt = 0; kt < 8; kt++) {
        int buf = kt & 1;
        if (kt < 7) {
            int nb = buf ^ 1, ktn = kt + 1;
#pragma unroll
            for (int rr = 0; rr < 4; rr++) {
                int c = rr * 2 + w;
                int loc = (c & 3) * 16 + (lane >> 2);
                int off8 = ((c >> 2) << 5) + (lane & 3) * 8;
                ASYNC_CP16(&qkv[(long)(ktn * 64 + loc) * 3072 + 1024 + h * 64 + off8], &Ks[nb][c * 512]);
                ASYNC_CP16(&vT[(long)(h * 64 + loc) * 512 + ktn * 64 + off8], &Vs[nb][c * 512]);
            }
        }
        f32x4 s[4];
#pragma unroll
        for (int ss = 0; ss < 4; ss++) {
            s[ss] = {0.f, 0.f, 0.f, 0.f};
#pragma unroll
            for (int c = 0; c < 2; c++) {
                bf16x8 bk = *(const bf16x8*)&Ks[buf][c * 2048 + (ss * 16 + l16) * 32 + quad * 8];
                s[ss] = __builtin_amdgcn_mfma_f32_16x16x32_bf16(aq[c], bk, s[ss], 0, 0, 0);
            }
        }
        float mt[4];
#pragma unroll
        for (int r = 0; r < 4; r++) {
#pragma unroll
            for (int ss = 0; ss < 4; ss++) s[ss][r] *= 0.125f;
            mt[r] = fmaxf(fmaxf(s[0][r], s[1][r]), fmaxf(s[2][r], s[3][r]));
        }
#pragma unroll
        for (int mask = 1; mask < 16; mask <<= 1)
#pragma unroll
            for (int r = 0; r < 4; r++) mt[r] = fmaxf(mt[r], __shfl_xor(mt[r], mask));
        float al[4], rsum[4];
#pragma unroll
        for (int r = 0; r < 4; r++) {
            float mn = fmaxf(mrow[r], mt[r]);
            al[r] = exp2f((mrow[r] - mn) * L2E);
            mrow[r] = mn;
            rsum[r] = 0.f;
#pragma unroll
            for (int ss = 0; ss < 4; ss++) {
                float p = exp2f((s[ss][r] - mn) * L2E);
                s[ss][r] = p;
                rsum[r] += p;
            }
        }
#pragma unroll
        for (int mask = 1; mask < 16; mask <<= 1)
#pragma unroll
            for (int r = 0; r < 4; r++) rsum[r] += __shfl_xor(rsum[r], mask);
#pragma unroll
        for (int r = 0; r < 4; r++) lrow[r] = lrow[r] * al[r] + rsum[r];
#pragma unroll
        for (int j = 0; j < 4; j++)
#pragma unroll
            for (int r = 0; r < 4; r++) acc_o[j][r] *= al[r];
#pragma unroll
        for (int ss = 0; ss < 4; ss++)
#pragma unroll
            for (int r = 0; r < 4; r++)
                Pl[(w * 16 + quad * 4 + r) * 72 + ss * 16 + l16] = f2bf(s[ss][r]);
#pragma unroll
        for (int kc = 0; kc < 2; kc++) {
            bf16x8 ap = *(const bf16x8*)&Pl[(w * 16 + l16) * 72 + kc * 32 + quad * 8];
#pragma unroll
            for (int j = 0; j < 4; j++) {
                bf16x8 bv = *(const bf16x8*)&Vs[buf][kc * 2048 + (j * 16 + l16) * 32 + quad * 8];
                acc_o[j] = __builtin_amdgcn_mfma_f32_16x16x32_bf16(ap, bv, acc_o[j], 0, 0, 0);
            }
        }
        __syncthreads();
    }

#pragma unroll
    for (int r = 0; r < 4; r++) {
        float inv = 1.0f / lrow[r];
        int gq = qb * 32 + w * 16 + quad * 4 + r;
#pragma unroll
        for (int j = 0; j < 4; j++)
            Ob[(long)gq * 1024 + h * 64 + j * 16 + l16] = f2bf(acc_o[j][r] * inv);
    }
}

// ---------------- xb = bf16(LN(xb + s) * g + beta), wave-per-row, no barrier -----------
__global__ __launch_bounds__(256) void k_add_ln(
    u16* __restrict__ xb, const u16* __restrict__ s, int sBroadcast,
    const float* __restrict__ g, const float* __restrict__ beta)
{
    int row = blockIdx.x * 4 + (threadIdx.x >> 6);   // b*512 + l
    int lane = threadIdx.x & 63;
    int srow = sBroadcast ? (row & 511) : row;
    u16* x = xb + (long)row * 1024;
    const u16* sp = s + (long)srow * 1024;
    int d0 = lane * 16;
    uint4 xa = *(const uint4*)&x[d0];
    uint4 xc = *(const uint4*)&x[d0 + 8];
    uint4 sa = *(const uint4*)&sp[d0];
    uint4 sc = *(const uint4*)&sp[d0 + 8];
    float v[16], t[8];
    unp8(xa, v); unp8(xc, v + 8);
    unp8(sa, t);
#pragma unroll
    for (int i = 0; i < 8; i++) v[i] += t[i];
    unp8(sc, t);
#pragma unroll
    for (int i = 0; i < 8; i++) v[8 + i] += t[i];
    float sum = 0.f, sq = 0.f;
#pragma unroll
    for (int i = 0; i < 16; i++) { sum += v[i]; sq += v[i] * v[i]; }
#pragma unroll
    for (int off = 32; off; off >>= 1) {
        sum += __shfl_xor(sum, off);
        sq += __shfl_xor(sq, off);
    }
    float mean = sum * (1.f / 1024.f);
    float var = sq * (1.f / 1024.f) - mean * mean;
    float rstd = rsqrtf(var + LN_EPS);
    float4 g0 = *(const float4*)&g[d0],      g1 = *(const float4*)&g[d0 + 4];
    float4 g2 = *(const float4*)&g[d0 + 8],  g3 = *(const float4*)&g[d0 + 12];
    float4 b0 = *(const float4*)&beta[d0],     b1 = *(const float4*)&beta[d0 + 4];
    float4 b2 = *(const float4*)&beta[d0 + 8], b3 = *(const float4*)&beta[d0 + 12];
    float gg[16] = {g0.x,g0.y,g0.z,g0.w, g1.x,g1.y,g1.z,g1.w, g2.x,g2.y,g2.z,g2.w, g3.x,g3.y,g3.z,g3.w};
    float bb[16] = {b0.x,b0.y,b0.z,b0.w, b1.x,b1.y,b1.z,b1.w, b2.x,b2.y,b2.z,b2.w, b3.x,b3.y,b3.z,b3.w};
    float y[16];
#pragma unroll
    for (int i = 0; i < 16; i++) y[i] = (v[i] - mean) * rstd * gg[i] + bb[i];
    uint4 oa, oc;
    oa.x = pk2(y[0], y[1]);  oa.y = pk2(y[2], y[3]);
    oa.z = pk2(y[4], y[5]);  oa.w = pk2(y[6], y[7]);
    oc.x = pk2(y[8], y[9]);  oc.y = pk2(y[10], y[11]);
    oc.z = pk2(y[12], y[13]); oc.w = pk2(y[14], y[15]);
    *(uint4*)&x[d0] = oa;
    *(uint4*)&x[d0 + 8] = oc;
}

// ---------------- xb = bf16(LN(xb + p0 + p1) * g + beta) -- bf16 split-K partials -----
__global__ __launch_bounds__(256) void k_add_ln2(
    u16* __restrict__ xb, const u16* __restrict__ p0, const u16* __restrict__ p1,
    const float* __restrict__ g, const float* __restrict__ beta)
{
    int row = blockIdx.x * 4 + (threadIdx.x >> 6);   // b*512 + l
    int lane = threadIdx.x & 63;
    u16* x = xb + (long)row * 1024;
    const u16* a0 = p0 + (long)row * 1024;
    const u16* a1 = p1 + (long)row * 1024;
    int d0 = lane * 16;
    uint4 xa = *(const uint4*)&x[d0];
    uint4 xc = *(const uint4*)&x[d0 + 8];
    float v[16], t[8];
    unp8(xa, v); unp8(xc, v + 8);
    unp8(*(const uint4*)&a0[d0], t);
#pragma unroll
    for (int i = 0; i < 8; i++) v[i] += t[i];
    unp8(*(const uint4*)&a0[d0 + 8], t);
#pragma unroll
    for (int i = 0; i < 8; i++) v[8 + i] += t[i];
    unp8(*(const uint4*)&a1[d0], t);
#pragma unroll
    for (int i = 0; i < 8; i++) v[i] += t[i];
    unp8(*(const uint4*)&a1[d0 + 8], t);
#pragma unroll
    for (int i = 0; i < 8; i++) v[8 + i] += t[i];
    float sum = 0.f, sq = 0.f;
#pragma unroll
    for (int i = 0; i < 16; i++) { sum += v[i]; sq += v[i] * v[i]; }
#pragma unroll
    for (int off = 32; off; off >>= 1) {
        sum += __shfl_xor(sum, off);
        sq += __shfl_xor(sq, off);
    }
    float mean = sum * (1.f / 1024.f);
    float var = sq * (1.f / 1024.f) - mean * mean;
    float rstd = rsqrtf(var + LN_EPS);
    float y[16];
#pragma unroll
    for (int i = 0; i < 16; i += 4) {
        float4 gv = *(const float4*)&g[d0 + i];
        float4 bv = *(const float4*)&beta[d0 + i];
        y[i]     = (v[i]     - mean) * rstd * gv.x + bv.x;
        y[i + 1] = (v[i + 1] - mean) * rstd * gv.y + bv.y;
        y[i + 2] = (v[i + 2] - mean) * rstd * gv.z + bv.z;
        y[i + 3] = (v[i + 3] - mean) * rstd * gv.w + bv.w;
    }
    uint4 oa, oc;
    oa.x = pk2(y[0], y[1]);  oa.y = pk2(y[2], y[3]);
    oa.z = pk2(y[4], y[5]);  oa.w = pk2(y[6], y[7]);
    oc.x = pk2(y[8], y[9]);  oc.y = pk2(y[10], y[11]);
    oc.z = pk2(y[12], y[13]); oc.w = pk2(y[14], y[15]);
    *(uint4*)&x[d0] = oa;
    *(uint4*)&x[d0 + 8] = oc;
}

// ---------------- head rows only: xhead = bf16(LN(xb + p0 + p1; g,beta)), rows 0-511 --
__global__ __launch_bounds__(256) void k_ln_head(
    const u16* __restrict__ xb, const u16* __restrict__ p0, const u16* __restrict__ p1,
    const float* __restrict__ g, const float* __restrict__ beta, u16* __restrict__ xhead)
{
    int row = blockIdx.x * 4 + (threadIdx.x >> 6);   // 0..511
    int lane = threadIdx.x & 63;
    const u16* x = xb + (long)row * 1024;
    const u16* a0 = p0 + (long)row * 1024;
    const u16* a1 = p1 + (long)row * 1024;
    int d0 = lane * 16;
    uint4 xa = *(const uint4*)&x[d0];
    uint4 xc = *(const uint4*)&x[d0 + 8];
    float v[16], t[8];
    unp8(xa, v); unp8(xc, v + 8);
    unp8(*(const uint4*)&a0[d0], t);
#pragma unroll
    for (int i = 0; i < 8; i++) v[i] += t[i];
    unp8(*(const uint4*)&a0[d0 + 8], t);
#pragma unroll
    for (int i = 0; i < 8; i++) v[8 + i] += t[i];
    unp8(*(const uint4*)&a1[d0], t);
#pragma unroll
    for (int i = 0; i < 8; i++) v[i] += t[i];
    unp8(*(const uint4*)&a1[d0 + 8], t);
#pragma unroll
    for (int i = 0; i < 8; i++) v[8 + i] += t[i];
    float sum = 0.f, sq = 0.f;
#pragma unroll
    for (int i = 0; i < 16; i++) { sum += v[i]; sq += v[i] * v[i]; }
#pragma unroll
    for (int off = 32; off; off >>= 1) {
        sum += __shfl_xor(sum, off);
        sq += __shfl_xor(sq, off);
    }
    float mean = sum * (1.f / 1024.f);
    float var = sq * (1.f / 1024.f) - mean * mean;
    float rstd = rsqrtf(var + LN_EPS);
    float y[16];
#pragma unroll
    for (int i = 0; i < 16; i += 4) {
        float4 gv = *(const float4*)&g[d0 + i];
        float4 bv = *(const float4*)&beta[d0 + i];
        y[i]     = (v[i]     - mean) * rstd * gv.x + bv.x;
        y[i + 1] = (v[i + 1] - mean) * rstd * gv.y + bv.y;
        y[i + 2] = (v[i + 2] - mean) * rstd * gv.z + bv.z;
        y[i + 3] = (v[i + 3] - mean) * rstd * gv.w + bv.w;
    }
    uint4 oa, oc;
    oa.x = pk2(y[0], y[1]);  oa.y = pk2(y[2], y[3]);
    oa.z = pk2(y[4], y[5]);  oa.w = pk2(y[6], y[7]);
    oc.x = pk2(y[8], y[9]);  oc.y = pk2(y[10], y[11]);
    oc.z = pk2(y[12], y[13]); oc.w = pk2(y[14], y[15]);
    u16* o = xhead + (long)row * 1024;
    *(uint4*)&o[d0] = oa;
    *(uint4*)&o[d0 + 8] = oc;
}

// ---------------- fused ln2(prev layer) + ln1(this layer), all rows -------------------
// xb = LN( LN(xb + p0 + p1; g2,be2) + src2[row&511]; g1,be1 )
__global__ __launch_bounds__(256) void k_ln2ln1(
    u16* __restrict__ xb, const u16* __restrict__ p0, const u16* __restrict__ p1,
    const u16* __restrict__ s2,
    const float* __restrict__ g2, const float* __restrict__ be2,
    const float* __restrict__ g1, const float* __restrict__ be1)
{
    int row = blockIdx.x * 4 + (threadIdx.x >> 6);   // b*512 + l
    int lane = threadIdx.x & 63;
    u16* x = xb + (long)row * 1024;
    const u16* a0 = p0 + (long)row * 1024;
    const u16* a1 = p1 + (long)row * 1024;
    const u16* sp = s2 + (long)(row & 511) * 1024;
    int d0 = lane * 16;
    uint4 xa = *(const uint4*)&x[d0];
    uint4 xc = *(const uint4*)&x[d0 + 8];
    float v[16], t[8];
    unp8(xa, v); unp8(xc, v + 8);
    unp8(*(const uint4*)&a0[d0], t);
#pragma unroll
    for (int i = 0; i < 8; i++) v[i] += t[i];
    unp8(*(const uint4*)&a0[d0 + 8], t);
#pragma unroll
    for (int i = 0; i < 8; i++) v[8 + i] += t[i];
    unp8(*(const uint4*)&a1[d0], t);
#pragma unroll
    for (int i = 0; i < 8; i++) v[i] += t[i];
    unp8(*(const uint4*)&a1[d0 + 8], t);
#pragma unroll
    for (int i = 0; i < 8; i++) v[8 + i] += t[i];
    // ---- LN2 ----
    float sum = 0.f, sq = 0.f;
#pragma unroll
    for (int i = 0; i < 16; i++) { sum += v[i]; sq += v[i] * v[i]; }
#pragma unroll
    for (int off = 32; off; off >>= 1) {
        sum += __shfl_xor(sum, off);
        sq += __shfl_xor(sq, off);
    }
    float mean = sum * (1.f / 1024.f);
    float var = sq * (1.f / 1024.f) - mean * mean;
    float rstd = rsqrtf(var + LN_EPS);
#pragma unroll
    for (int i = 0; i < 16; i += 4) {
        float4 gv = *(const float4*)&g2[d0 + i];
        float4 bv = *(const float4*)&be2[d0 + i];
        v[i]     = (v[i]     - mean) * rstd * gv.x + bv.x;
        v[i + 1] = (v[i + 1] - mean) * rstd * gv.y + bv.y;
        v[i + 2] = (v[i + 2] - mean) * rstd * gv.z + bv.z;
        v[i + 3] = (v[i + 3] - mean) * rstd * gv.w + bv.w;
    }
    // ---- + src2 (broadcast) ----
    uint4 sa = *(const uint4*)&sp[d0];
    uint4 sc = *(const uint4*)&sp[d0 + 8];
    unp8(sa, t);
#pragma unroll
    for (int i = 0; i < 8; i++) v[i] += t[i];
    unp8(sc, t);
#pragma unroll
    for (int i = 0; i < 8; i++) v[8 + i] += t[i];
    // ---- LN1 ----
    sum = 0.f; sq = 0.f;
#pragma unroll
    for (int i = 0; i < 16; i++) { sum += v[i]; sq += v[i] * v[i]; }
#pragma unroll
    for (int off = 32; off; off >>= 1) {
        sum += __shfl_xor(sum, off);
        sq += __shfl_xor(sq, off);
    }
    mean = sum * (1.f / 1024.f);
    var = sq * (1.f / 1024.f) - mean * mean;
    rstd = rsqrtf(var + LN_EPS);
    float y[16];
#pragma unroll
    for (int i = 0; i < 16; i += 4) {
        float4 gv = *(const float4*)&g1[d0 + i];
        float4 bv = *(const float4*)&be1[d0 + i];
        y[i]     = (v[i]     - mean) * rstd * gv.x + bv.x;
        y[i + 1] = (v[i + 1] - mean) * rstd * gv.y + bv.y;
        y[i + 2] = (v[i + 2] - mean) * rstd * gv.z + bv.z;
        y[i + 3] = (v[i + 3] - mean) * rstd * gv.w + bv.w;
    }
    uint4 oa, oc;
    oa.x = pk2(y[0], y[1]);  oa.y = pk2(y[2], y[3]);
    oa.z = pk2(y[4], y[5]);  oa.w = pk2(y[6], y[7]);
    oc.x = pk2(y[8], y[9]);  oc.y = pk2(y[10], y[11]);
    oc.z = pk2(y[12], y[13]); oc.w = pk2(y[14], y[15]);
    *(uint4*)&x[d0] = oa;
    *(uint4*)&x[d0 + 8] = oc;
}

// ---------------- pool stage A: pp[b][ch][d] = sum_{l in 64-chunk} x[b][l][d] ---------
__global__ __launch_bounds__(256) void k_pool_a(
    const u16* __restrict__ xb, float* __restrict__ pp)
{
    int b = blockIdx.x >> 3, ch = blockIdx.x & 7;
    int d0 = threadIdx.x * 4;
    const u16* x = xb + ((long)b * 512 + ch * 64) * 1024;
    float s0 = 0.f, s1 = 0.f, s2 = 0.f, s3 = 0.f;
    for (int l = 0; l < 64; l++) {
        ushort4 v = *(const ushort4*)&x[(long)l * 1024 + d0];
        s0 += bf2f(v.x); s1 += bf2f(v.y); s2 += bf2f(v.z); s3 += bf2f(v.w);
    }
    float* o = pp + ((long)b * 8 + ch) * 1024 + d0;
    o[0] = s0; o[1] = s1; o[2] = s2; o[3] = s3;
}

// ---------------- pool stage B + head: out[b][c] = mean·wf[:,c] + bf[c] ---------------
__global__ __launch_bounds__(256) void k_pool_b(
    const float* __restrict__ pp, const float* __restrict__ wf,
    const float* __restrict__ bfin, float* __restrict__ out)
{
    int b = blockIdx.x;
    int tid = threadIdx.x;
    __shared__ float pl[1024];
    int d0 = tid * 4;
    float s0 = 0.f, s1 = 0.f, s2 = 0.f, s3 = 0.f;
#pragma unroll
    for (int ch = 0; ch < 8; ch++) {
        float4 q = *(const float4*)&pp[((long)b * 8 + ch) * 1024 + d0];
        s0 += q.x; s1 += q.y; s2 += q.z; s3 += q.w;
    }
    pl[d0] = s0 * (1.f / 512.f);
    pl[d0 + 1] = s1 * (1.f / 512.f);
    pl[d0 + 2] = s2 * (1.f / 512.f);
    pl[d0 + 3] = s3 * (1.f / 512.f);
    __syncthreads();
    __shared__ float red[4];
    for (int c = 0; c < 10; c++) {
        float t = 0.f;
        for (int d = tid; d < 1024; d += 256) t += pl[d] * wf[(long)d * 10 + c];
        for (int off = 32; off; off >>= 1) t += __shfl_down(t, off);
        if ((tid & 63) == 0) red[tid >> 6] = t;
        __syncthreads();
        if (tid == 0) out[b * 10 + c] = red[0] + red[1] + red[2] + red[3] + bfin[c];
        __syncthreads();
    }
}

// ---------------- host side ----------------
template <int TM, int TN, bool VT_EPI>
static void gemm(const u16* A, long lda, const u16* B, long ldb,
                 u16* C, long ldc,
                 int M, int N, int K, const float* bias,
                 hipStream_t st, u16* vTout = nullptr)
{
    dim3 g((N + TN - 1) / TN, (M + TM - 1) / TM);
    k_gemm_nt<TM, TN, VT_EPI><<<g, 256, 0, st>>>(A, lda, B, ldb, C, ldc, M, N, K, bias, vTout);
}

extern "C" void kernel_launch(void* const* d_in, const int* in_sizes, int n_in,
                              void* d_out, int out_size, void* d_ws, size_t ws_size,
                              hipStream_t stream)
{
    const int* ids   = (const int*)d_in[0];
    const float* emb = (const float*)d_in[1];
    const float* pe  = (const float*)d_in[2];
    const float* wq  = (const float*)d_in[3];
    const float* bq  = (const float*)d_in[4];
    const float* wk  = (const float*)d_in[5];
    const float* bk  = (const float*)d_in[6];
    const float* wv  = (const float*)d_in[7];
    const float* bv  = (const float*)d_in[8];
    const float* wo  = (const float*)d_in[9];
    const float* bo  = (const float*)d_in[10];
    const float* w1  = (const float*)d_in[11];
    const float* b1  = (const float*)d_in[12];
    const float* w2  = (const float*)d_in[13];
    const float* b2  = (const float*)d_in[14];
    const float* g1  = (const float*)d_in[15];
    const float* be1 = (const float*)d_in[16];
    const float* g2  = (const float*)d_in[17];
    const float* be2 = (const float*)d_in[18];
    const float* wf  = (const float*)d_in[19];
    const float* bfi = (const float*)d_in[20];
    float* out = (float*)d_out;

    char* base = (char*)d_ws;
    size_t off = 0;
    auto alloc = [&](size_t bytes) {
        char* p = base + off;
        off = (off + bytes + 255) & ~(size_t)255;
        return p;
    };
    u16*   xb    = (u16*)  alloc(16UL * 512 * 1024 * 2);   // bf16 residual stream [B,L,D]
    u16*   wqkvT = (u16*)  alloc(3072UL * 1024 * 2);       // [3072,1024] = wqT;wkT;wvT
    u16*   woT   = (u16*)  alloc(1024UL * 1024 * 2);
    u16*   w1b   = (u16*)  alloc(1024UL * 4096 * 2);       // bf16 cast of w1 [D,F]
    u16*   w2T   = (u16*)  alloc(1024UL * 4096 * 2);       // [D,F] = w2 transposed
    u16*   W12T  = (u16*)  alloc(1024UL * 1024 * 2);       // folded FFN weight, [e][d]
    float* b12f  = (float*)alloc(1024UL * 4);              // folded FFN bias
    float* b12p  = (float*)alloc(32UL * 1024 * 4);         // bias-fold partials
    float* qkvb  = (float*)alloc(3072UL * 4);              // concat(bq,bk,bv)
    u16*   qkv   = (u16*)  alloc(512UL * 3072 * 2);        // [L, 3*D]; v-part goes to vT
    u16*   vT    = (u16*)  alloc(1024UL * 512 * 2);        // v transposed [D,L]
    u16*   Ob    = (u16*)  alloc(512UL * 1024 * 2);        // attn context bf16 [L,D]
    u16*   src2  = (u16*)  alloc(512UL * 1024 * 2);        // bf16
    u16*   xhead = (u16*)  alloc(512UL * 1024 * 2);        // ln2-ed head rows for qkv
    float* ppool = (float*)alloc(16UL * 8 * 1024 * 4);     // pool partials
    u16*   ffp   = (u16*)  alloc(16UL * 1024 * 1024 * 2);  // bf16 split-K partials
                                                           // (FFN: 2x[8192,1024]; W12: 16x[1024,1024])

    k_prep<<<12300, 256, 0, stream>>>(wq, wk, wv, wo, w1, w2, bq, bk, bv, qkvb,
                                      wqkvT, woT, w1b, w2T);
    k_bias12a<<<256, 256, 0, stream>>>(b1, w2, b12p);
    k_bias12b<<<8, 128, 0, stream>>>(b12p, b2, b12f);
    k_embed<<<8192, 256, 0, stream>>>(ids, emb, pe, xb);
    // W12T[e][d] = sum_f w2T[e][f] * w1b[d][f] via split-K gemm8 (z=16, K=256 each)
    k_gemm8<true><<<dim3(4, 4, 16), 512, 0, stream>>>(w2T, 4096, w1b, 4096,
                                                      ffp, 1024, 256, nullptr);
    k_w12red<<<1024, 256, 0, stream>>>(ffp, W12T);

    u16* fp0 = ffp;
    u16* fp1 = ffp + 8192UL * 1024;
    for (int layer = 0; layer < 6; layer++) {
        const u16* qsrc = xb;
        if (layer > 0) {
            // head rows of ln2(prev): feeds this layer's qkv; bulk ln2 deferred
            k_ln_head<<<128, 256, 0, stream>>>(xb, fp0, fp1, g2, be2, xhead);
            qsrc = xhead;
        }
        // fused q|k|v for batch 0: [512,3072]; V cols written transposed into vT
        gemm<64, 64, true>(qsrc, 1024, wqkvT, 1024, qkv, 3072, 512, 3072, 1024, qkvb, stream, vT);
        // fused scores+softmax+PV
        k_attn<<<dim3(16, 16), 128, 0, stream>>>(qkv, vT, Ob);
        // src2 = O . wo + bo
        gemm<64, 64, false>(Ob, 1024, woT, 1024, src2, 1024, 512, 1024, 1024, bo, stream);
        if (layer == 0)
            k_add_ln<<<2048, 256, 0, stream>>>(xb, src2, 1, g1, be1);
        else
            // xb = LN1( LN2(xb + ffp) + src2 )  -- fused bulk ln2(prev)+ln1(this)
            k_ln2ln1<<<2048, 256, 0, stream>>>(xb, fp0, fp1, src2, g2, be2, g1, be1);
        // folded FFN: ff = xb @ W12T^T + b12, split-K z=2 (K=512 each) -> bf16 partials
        k_gemm8<true><<<dim3(4, 32, 2), 512, 0, stream>>>(xb, 1024, W12T, 1024,
                                                          ffp, 1024, 512, b12f);
    }

    // final ln2 after last layer's FFN
    k_add_ln2<<<2048, 256, 0, stream>>>(xb, fp0, fp1, g2, be2);
    k_pool_a<<<128, 256, 0, stream>>>(xb, ppool);
    k_pool_b<<<16, 256, 0, stream>>>(ppool, wf, bfi, out);
}